// Round 14
// baseline (343.558 us; speedup 1.0000x reference)
//
#include <hip/hip_runtime.h>
#include <math.h>
#include <stdint.h>

namespace {

constexpr int B_ = 2, S_ = 1024, E_ = 1024, H_ = 8, HD_ = 128;
constexpr int M_ = 128, W_ = 32, GH_ = 128, R_ = 8, MR_ = 8, FFNH_ = 4096;
constexpr int SCH = 32;            // s-chunks for pooling
constexpr int SPC = S_ / SCH;      // 32 rows per chunk

typedef __bf16 bf16;
typedef _Float16 f16;
typedef __attribute__((ext_vector_type(8))) __bf16 bf16x8;
typedef __attribute__((ext_vector_type(4))) __bf16 bf16x4;
typedef __attribute__((ext_vector_type(4))) _Float16 f16x4;
typedef __attribute__((ext_vector_type(4))) float f32x4;

__device__ inline float gelu_tanh(float u) {
  float u3 = u * u * u;
  return 0.5f * u * (1.f + tanhf(0.7978845608028654f * (u + 0.044715f * u3)));
}

// ---------------- fp32 -> bf16 elementwise ---------------------------------
__global__ __launch_bounds__(256) void k_cvt_bf16(const float* __restrict__ in,
                                                  bf16* __restrict__ out) {
  int i = blockIdx.x * 256 + threadIdx.x;
  float4 v = *(const float4*)(in + (size_t)i * 4);
  bf16x4 o;
  o.x = (bf16)v.x; o.y = (bf16)v.y; o.z = (bf16)v.z; o.w = (bf16)v.w;
  *(bf16x4*)(out + (size_t)i * 4) = o;
}

// ---------------- weight (K,N) fp32 -> (N,K) bf16 transpose ----------------
__global__ __launch_bounds__(256) void k_wt(const float* __restrict__ w,
                                            bf16* __restrict__ wT, int K, int N) {
  __shared__ float tile[32][33];
  int n0 = blockIdx.x * 32, k0 = blockIdx.y * 32;
  int tx = threadIdx.x & 31, ty = threadIdx.x >> 5;
  for (int r = ty; r < 32; r += 8) tile[r][tx] = w[(size_t)(k0 + r) * N + n0 + tx];
  __syncthreads();
  for (int r = ty; r < 32; r += 8) wT[(size_t)(n0 + r) * K + k0 + tx] = (bf16)tile[tx][r];
}

// ---------------- Wcat^T (256 x 1024) bf16: [qmod|kmod|diag(cwq)|diag(cwk)] -
__global__ __launch_bounds__(256) void k_wcat(const float* __restrict__ qmw,
                                              const float* __restrict__ kmw,
                                              const float* __restrict__ cwq,
                                              const float* __restrict__ cwk,
                                              bf16* __restrict__ wcat) {
  int idx = blockIdx.x * 256 + threadIdx.x;   // over 256*1024
  int n = idx >> 10, k = idx & 1023;
  float v = 0.f;
  if (n < 8) {
    v = qmw[k * 8 + n];
  } else if (n < 16) {
    v = kmw[k * 8 + (n - 8)];
  } else if (n < 80) {
    int u = n - 16, h = u >> 3, r = u & 7;
    int kk = k - h * 128;
    if (kk >= 0 && kk < 128) v = cwq[((size_t)h * 128 + kk) * 8 + r];
  } else if (n < 144) {
    int u = n - 80, h = u >> 3, r = u & 7;
    int kk = k - h * 128;
    if (kk >= 0 && kk < 128) v = cwk[((size_t)h * 128 + kk) * 8 + r];
  }
  wcat[idx] = (bf16)v;
}

// ---------------- finish qk GEMM: sum fp16 partials, scatter -----------------
__global__ __launch_bounds__(256) void k_fin_qk(
    const f16* __restrict__ P, const float* __restrict__ qmb,
    const float* __restrict__ kmb, float* __restrict__ qsT,
    float* __restrict__ kmT, float* __restrict__ qc, float* __restrict__ kc) {
  int row = blockIdx.x;            // 0..2047
  int t = threadIdx.x;
  if (t >= 144) return;
  int b = row >> 10, s = row & 1023;
  const size_t mn = (size_t)2048 * 256;
  float sum = 0.f;
#pragma unroll
  for (int z = 0; z < 8; ++z) sum += (float)P[(size_t)z * mn + (size_t)row * 256 + t];
  if (t < 8) {
    qsT[((size_t)(b * 8 + t)) * 1024 + s] = sum + qmb[t];
  } else if (t < 16) {
    kmT[((size_t)(b * 8 + t - 8)) * 1024 + s] = sum + kmb[t - 8];
  } else if (t < 80) {
    int u = t - 16, h = u >> 3, r = u & 7;
    qc[(((size_t)(b * 8 + h)) * 1024 + s) * 8 + r] = sum;
  } else {
    int u = t - 80, h = u >> 3, r = u & 7;
    kc[(((size_t)(b * 8 + h)) * 1024 + s) * 8 + r] = sum;
  }
}

// ---------------- pooled = mean_s x[b,s,:] ---------------------------------
__global__ __launch_bounds__(256) void k_pool_partial(const float* __restrict__ x,
                                                      float* __restrict__ part) {
  int blk = blockIdx.x;
  int b = blk / SCH, c = blk % SCH;
  int t = threadIdx.x;
  const float* xp = x + (size_t)b * S_ * E_ + (size_t)c * SPC * E_;
  float acc[4] = {0.f, 0.f, 0.f, 0.f};
  for (int s = 0; s < SPC; ++s) {
    const float* row = xp + (size_t)s * E_;
#pragma unroll
    for (int q = 0; q < 4; ++q) acc[q] += row[t + q * 256];
  }
  float* pp = part + (size_t)blk * E_;
#pragma unroll
  for (int q = 0; q < 4; ++q) pp[t + q * 256] = acc[q];
}

__global__ __launch_bounds__(256) void k_pool_reduce(const float* __restrict__ part,
                                                     float* __restrict__ pooled) {
  int b = blockIdx.x;
  int t = threadIdx.x;
#pragma unroll
  for (int q = 0; q < 4; ++q) {
    int e = t + q * 256;
    float s = 0.f;
    for (int c = 0; c < SCH; ++c) s += part[(size_t)(b * SCH + c) * E_ + e];
    pooled[b * E_ + e] = s * (1.0f / S_);
  }
}

// ---------------- gate first layer: coalesced split-E partials --------------
__global__ __launch_bounds__(256) void k_gate1(
    const float* __restrict__ pooled,
    const float* __restrict__ gw1, const float* __restrict__ mw1,
    float2* __restrict__ part) {
  int chunk = blockIdx.x;          // 0..15
  int h = blockIdx.y;              // 0..7
  int mat = blockIdx.z;            // 0: gate, 1: mod
  const float* w = mat ? mw1 : gw1;
  int t = threadIdx.x;
  int g = t & 127, half = t >> 7;
  int e0 = chunk * 64 + half * 32;
  const float* wp = w + (size_t)h * E_ * GH_ + (size_t)e0 * GH_ + g;
  const float* p0 = pooled + e0;
  const float* p1 = pooled + E_ + e0;
  float a0 = 0.f, a1 = 0.f;
#pragma unroll 8
  for (int r = 0; r < 32; ++r) {
    float wv = wp[(size_t)r * GH_];
    a0 += p0[r] * wv;
    a1 += p1[r] * wv;
  }
  __shared__ float red[2][2][128];
  red[half][0][g] = a0;
  red[half][1][g] = a1;
  __syncthreads();
  if (half == 0) {
    float2 o;
    o.x = red[0][0][g] + red[1][0][g];
    o.y = red[0][1][g] + red[1][1][g];
    part[(((size_t)mat * H_ + h) * 16 + chunk) * 128 + g] = o;
  }
}

// ---------------- gate finish ------------------------------------------------
__global__ __launch_bounds__(256) void k_gate2(
    const float2* __restrict__ part,
    const float* __restrict__ gb1, const float* __restrict__ gw2, const float* __restrict__ gb2,
    const float* __restrict__ mb1, const float* __restrict__ mw2, const float* __restrict__ mb2,
    const float* __restrict__ mbasis, float* __restrict__ wmod) {
  int bh = blockIdx.x;
  int b = bh >> 3, h = bh & 7;
  int t = threadIdx.x;
  __shared__ float ghs[GH_], mhs[GH_], glog[M_], mrs[MR_];
  __shared__ float red2[2][128];
  __shared__ float rbuf[128];
  {
    int g = t & 127, mat = t >> 7;
    const float2* pp = part + ((size_t)mat * H_ + h) * 16 * 128 + g;
    float acc = 0.f;
#pragma unroll
    for (int c = 0; c < 16; ++c) {
      float2 v = pp[(size_t)c * 128];
      acc += b ? v.y : v.x;
    }
    acc += (mat ? mb1 : gb1)[h * GH_ + g];
    acc = fmaxf(acc, 0.f);
    if (mat == 0) ghs[g] = acc; else mhs[g] = acc;
  }
  __syncthreads();
  {
    int m = t & 127, half = t >> 7;
    float acc = 0.f;
    const float* wp = gw2 + (size_t)h * GH_ * M_ + m;
#pragma unroll 4
    for (int g = half * 64; g < half * 64 + 64; ++g)
      acc += ghs[g] * wp[(size_t)g * M_];
    red2[half][m] = acc;
  }
  __syncthreads();
  if (t < 128) glog[t] = red2[0][t] + red2[1][t] + gb2[h * M_ + t];
  if (t < 64) {
    int r = t & 7, seg = t >> 3;
    float acc = 0.f;
    const float* wp = mw2 + (size_t)h * GH_ * MR_ + r;
    for (int g = seg * 16; g < seg * 16 + 16; ++g) acc += mhs[g] * wp[(size_t)g * MR_];
    acc += __shfl_xor(acc, 8);
    acc += __shfl_xor(acc, 16);
    acc += __shfl_xor(acc, 32);
    if (t < 8) mrs[t] = acc + mb2[h * MR_ + t];
  }
  __syncthreads();
  if (t < 128) rbuf[t] = glog[t];
  __syncthreads();
  for (int off = 64; off >= 1; off >>= 1) {
    if (t < off) rbuf[t] = fmaxf(rbuf[t], rbuf[t + off]);
    __syncthreads();
  }
  float mx = rbuf[0];
  __syncthreads();
  float ev = 0.f;
  if (t < 128) ev = expf(glog[t] - mx);
  __syncthreads();
  if (t < 128) rbuf[t] = ev;
  __syncthreads();
  for (int off = 64; off >= 1; off >>= 1) {
    if (t < off) rbuf[t] += rbuf[t + off];
    __syncthreads();
  }
  float inv = 1.f / rbuf[0];
  if (t < 128) {
    float wsel = ev * inv;
    float md = 0.f;
#pragma unroll
    for (int r = 0; r < MR_; ++r) md += mrs[r] * mbasis[((size_t)h * MR_ + r) * M_ + t];
    wmod[bh * M_ + t] = wsel * (1.f + md);
  }
}

// ---------------- wave kernels ---------------------------------------------
__global__ __launch_bounds__(256) void k_waves(const float* __restrict__ freqs,
                                               const float* __restrict__ amps,
                                               const float* __restrict__ phases,
                                               float* __restrict__ kerns) {
  int blk = blockIdx.x;
  int lt = blk & 3;
  int hm = blk >> 2;
  int t = threadIdx.x;
  __shared__ float f0[W_], f1[W_], am[W_], ph[W_];
  if (t < W_) {
    f0[t] = freqs[((size_t)hm * W_ + t) * 2 + 0];
    f1[t] = freqs[((size_t)hm * W_ + t) * 2 + 1];
    am[t] = amps[(size_t)hm * W_ + t];
    ph[t] = phases[(size_t)hm * W_ + t];
  }
  __syncthreads();
  int l = lt * 256 + t;
  float rel = (float)(l - (S_ - 1));
  float p1 = rel * (1.0f / S_);
  float p2 = (rel < 0.f) ? (-sqrtf(-rel + 1e-6f) * (1.0f / 32.0f)) : 0.f;
  const float TWO_PI = 6.28318530717958647692f;
  float acc = 0.f;
#pragma unroll
  for (int w = 0; w < W_; ++w)
    acc += am[w] * __sinf(TWO_PI * (f0[w] * p1 + f1[w] * p2) + ph[w]);
  kerns[(size_t)hm * S_ + l] = acc;
}

// ---------------- swin ------------------------------------------------------
__global__ __launch_bounds__(256) void k_swin(const float* __restrict__ wmod,
                                              const float* __restrict__ kerns,
                                              float* __restrict__ swin) {
  int blk = blockIdx.x;
  int dt = blk & 3;
  int bh = blk >> 2;
  int h = bh & 7;
  int t = threadIdx.x;
  __shared__ float wm[M_];
  if (t < M_) wm[t] = wmod[bh * M_ + t];
  __syncthreads();
  int d = dt * 256 + t;
  int l = (S_ - 1) - d;
  float acc = 0.f;
  for (int m = 0; m < M_; ++m) acc += wm[m] * kerns[((size_t)h * M_ + m) * S_ + l];
  float dd = (float)d;
  float win = expf(-dd * dd * (1.0f / 131072.0f));
  swin[(size_t)bh * S_ + d] = 3.0f * win * acc;
}

// ---------------- cont[bh][i][j] = qc_i . kc_j  (bf16, lower-tri 128-tiles) -
__global__ __launch_bounds__(256) void k_cont(const float* __restrict__ qc,
                                              const float* __restrict__ kc,
                                              bf16* __restrict__ cont) {
  int jt = blockIdx.x, it = blockIdx.y;
  if (jt > it) return;
  int bh = blockIdx.z;
  int t = threadIdx.x;
  int w = t >> 6, lane = t & 63;
  int ln = lane & 15, ko = lane >> 4;
  int i0 = it * 128 + w * 32;
  int j0 = jt * 128;

  bf16x8 av[2];
#pragma unroll
  for (int mi = 0; mi < 2; ++mi) {
    bf16x8 a;
#pragma unroll
    for (int k = 0; k < 8; ++k) a[k] = (bf16)0.f;
    if (ko == 0) {
      const float* qp = &qc[((size_t)bh * S_ + i0 + mi * 16 + ln) * 8];
      float4 q0 = *(const float4*)qp;
      float4 q1 = *(const float4*)(qp + 4);
      a[0] = (bf16)q0.x; a[1] = (bf16)q0.y; a[2] = (bf16)q0.z; a[3] = (bf16)q0.w;
      a[4] = (bf16)q1.x; a[5] = (bf16)q1.y; a[6] = (bf16)q1.z; a[7] = (bf16)q1.w;
    }
    av[mi] = a;
  }
  bf16x8 bv[8];
#pragma unroll
  for (int nb = 0; nb < 8; ++nb) {
    bf16x8 bb;
#pragma unroll
    for (int k = 0; k < 8; ++k) bb[k] = (bf16)0.f;
    if (ko == 0) {
      const float* kp = &kc[((size_t)bh * S_ + j0 + nb * 16 + ln) * 8];
      float4 k0 = *(const float4*)kp;
      float4 k1 = *(const float4*)(kp + 4);
      bb[0] = (bf16)k0.x; bb[1] = (bf16)k0.y; bb[2] = (bf16)k0.z; bb[3] = (bf16)k0.w;
      bb[4] = (bf16)k1.x; bb[5] = (bf16)k1.y; bb[6] = (bf16)k1.z; bb[7] = (bf16)k1.w;
    }
    bv[nb] = bb;
  }
  f32x4 acc[2][8];
#pragma unroll
  for (int mi = 0; mi < 2; ++mi)
#pragma unroll
    for (int nb = 0; nb < 8; ++nb) {
      acc[mi][nb] = (f32x4){0.f, 0.f, 0.f, 0.f};
      acc[mi][nb] = __builtin_amdgcn_mfma_f32_16x16x32_bf16(av[mi], bv[nb], acc[mi][nb], 0, 0, 0);
    }
  bf16* cb = cont + ((size_t)bh << 20);
#pragma unroll
  for (int mi = 0; mi < 2; ++mi)
#pragma unroll
    for (int nb = 0; nb < 8; ++nb) {
      int col = j0 + nb * 16 + ln;
#pragma unroll
      for (int reg = 0; reg < 4; ++reg) {
        int row = i0 + mi * 16 + ko * 4 + reg;
        cb[(size_t)row * S_ + col] = (bf16)acc[mi][nb][reg];
      }
    }
}

// ---------------- barrier-free TLP GEMM: 1 wave / 64x64 tile ----------------
// Fragments loaded DIRECTLY global->reg (no LDS, no barriers, no gl_lds):
// lane l reads row (l&15), k-octet (l>>4) -> 16x64B segments per load instr.
// Register double-buffer with named sets (static indices). fp16 partial out,
// identical P layout / accumulation order to the old k_gemm_sk.
template <int NB>
__global__ __launch_bounds__(64) void k_gemm_tlp(
    const bf16* __restrict__ A, const bf16* __restrict__ BT,
    f16* __restrict__ P, int N, int K, int Kslice, size_t strideB, size_t mn) {
  int l = threadIdx.x;
  // XCD-aware bijective remap, row-tile (by) fastest for L2 locality
  int gx = gridDim.x, gy = gridDim.y;
  int nwg = gx * gy * gridDim.z;
  int lin = (blockIdx.z * gy + blockIdx.y) * gx + blockIdx.x;
  if (!(nwg & 7)) {
    int cpx = nwg >> 3;
    lin = (lin & 7) * cpx + (lin >> 3);
  }
  int by = lin % gy;
  int rem = lin / gy;
  int bx = rem % gx;
  int z = rem / gx;

  int bb = z % NB;
  int k0 = (z / NB) * Kslice;
  const bf16* Ab = A + (size_t)(by * 64 + (l & 15)) * K + k0 + (l >> 4) * 8;
  const bf16* Bb = BT + (size_t)bb * strideB +
                   (size_t)(bx * 64 + (l & 15)) * K + k0 + (l >> 4) * 8;

  f32x4 acc[4][4];
#pragma unroll
  for (int m = 0; m < 4; ++m)
#pragma unroll
    for (int n = 0; n < 4; ++n) acc[m][n] = (f32x4){0.f, 0.f, 0.f, 0.f};

  const int niter = Kslice >> 5;   // BK=32 per iter; niter even for all uses
  bf16x8 aA[4], bA[4], aB[4], bB[4];
#pragma unroll
  for (int m = 0; m < 4; ++m) {
    aA[m] = *(const bf16x8*)(Ab + (size_t)m * 16 * K);
    bA[m] = *(const bf16x8*)(Bb + (size_t)m * 16 * K);
  }
  for (int it = 0; it < niter; it += 2) {
    // prefetch it+1 into B-set
#pragma unroll
    for (int m = 0; m < 4; ++m) {
      aB[m] = *(const bf16x8*)(Ab + (size_t)m * 16 * K + (it + 1) * 32);
      bB[m] = *(const bf16x8*)(Bb + (size_t)m * 16 * K + (it + 1) * 32);
    }
#pragma unroll
    for (int m = 0; m < 4; ++m)
#pragma unroll
      for (int n = 0; n < 4; ++n)
        acc[m][n] = __builtin_amdgcn_mfma_f32_16x16x32_bf16(aA[m], bA[n], acc[m][n], 0, 0, 0);
    if (it + 2 < niter) {          // prefetch it+2 into A-set
#pragma unroll
      for (int m = 0; m < 4; ++m) {
        aA[m] = *(const bf16x8*)(Ab + (size_t)m * 16 * K + (it + 2) * 32);
        bA[m] = *(const bf16x8*)(Bb + (size_t)m * 16 * K + (it + 2) * 32);
      }
    }
#pragma unroll
    for (int m = 0; m < 4; ++m)
#pragma unroll
      for (int n = 0; n < 4; ++n)
        acc[m][n] = __builtin_amdgcn_mfma_f32_16x16x32_bf16(aB[m], bB[n], acc[m][n], 0, 0, 0);
  }

  f16* Pz = P + (size_t)z * mn;
  int r0 = by * 64, c0 = bx * 64;
#pragma unroll
  for (int m = 0; m < 4; ++m)
#pragma unroll
    for (int n = 0; n < 4; ++n) {
      int col = c0 + n * 16 + (l & 15);
#pragma unroll
      for (int reg = 0; reg < 4; ++reg) {
        int row = r0 + m * 16 + ((l >> 4) << 2) + reg;
        Pz[(size_t)row * N + col] = (f16)acc[m][n][reg];
      }
    }
}

// ---------------- combine: vT = sum_sk P + v_b (bf16 out, [b][hd][s]) -------
__global__ __launch_bounds__(256) void k_fin_vT(const f16* __restrict__ P,
                                                const float* __restrict__ bias,
                                                bf16* __restrict__ vT) {
  size_t i = ((size_t)blockIdx.x * 256 + threadIdx.x) * 4;
  const size_t mn = (size_t)1024 * 1024;
  float sx = 0.f, sy = 0.f, sz = 0.f, sw2 = 0.f;
#pragma unroll
  for (int sk = 0; sk < 4; ++sk) {
    f16x4 v = *(const f16x4*)&P[(size_t)sk * 2 * mn + i];
    sx += (float)v.x; sy += (float)v.y; sz += (float)v.z; sw2 += (float)v.w;
  }
  float bcol = bias[(i >> 10) & 1023];
  bf16x4 o;
  o.x = (bf16)(sx + bcol); o.y = (bf16)(sy + bcol);
  o.z = (bf16)(sz + bcol); o.w = (bf16)(sw2 + bcol);
  *(bf16x4*)&vT[i] = o;
}

// ---------------- combine: hb = gelu(sum_sk P + bias) (bf16) ----------------
__global__ __launch_bounds__(256) void k_fin_gelu(const f16* __restrict__ P,
                                                  const float* __restrict__ bias,
                                                  bf16* __restrict__ hb) {
  size_t i = ((size_t)blockIdx.x * 256 + threadIdx.x) * 4;
  const size_t mn = (size_t)2048 * 4096;
  float s[4] = {0.f, 0.f, 0.f, 0.f};
#pragma unroll
  for (int sk = 0; sk < 2; ++sk) {
    f16x4 v = *(const f16x4*)&P[(size_t)sk * mn + i];
    s[0] += (float)v.x; s[1] += (float)v.y; s[2] += (float)v.z; s[3] += (float)v.w;
  }
  float4 bv = *(const float4*)&bias[i & 4095];
  bf16x4 o;
  o.x = (bf16)gelu_tanh(s[0] + bv.x);
  o.y = (bf16)gelu_tanh(s[1] + bv.y);
  o.z = (bf16)gelu_tanh(s[2] + bv.z);
  o.w = (bf16)gelu_tanh(s[3] + bv.w);
  *(bf16x4*)&hb[i] = o;
}

// ---------------- fused fin+LayerNorm: u = sumP + bias + res; LN(u) ---------
template <int SK, bool OUTBF16>
__global__ __launch_bounds__(256) void k_fin_ln(
    const f16* __restrict__ P, const float* __restrict__ bias,
    const float* __restrict__ res, const float* __restrict__ g,
    const float* __restrict__ bb, float* __restrict__ outF,
    bf16* __restrict__ outB) {
  int row = blockIdx.x, t = threadIdx.x;
  size_t base = (size_t)row * E_ + t * 4;
  const size_t mn = (size_t)2048 * 1024;
  float u0 = 0.f, u1 = 0.f, u2 = 0.f, u3 = 0.f;
#pragma unroll
  for (int sk = 0; sk < SK; ++sk) {
    f16x4 v = *(const f16x4*)&P[(size_t)sk * mn + base];
    u0 += (float)v.x; u1 += (float)v.y; u2 += (float)v.z; u3 += (float)v.w;
  }
  float4 bv = *(const float4*)&bias[t * 4];
  float4 rv = *(const float4*)&res[base];
  u0 += bv.x + rv.x; u1 += bv.y + rv.y; u2 += bv.z + rv.z; u3 += bv.w + rv.w;
  float s = u0 + u1 + u2 + u3;
  float s2 = u0 * u0 + u1 * u1 + u2 * u2 + u3 * u3;
#pragma unroll
  for (int off = 32; off >= 1; off >>= 1) {
    s += __shfl_xor(s, off);
    s2 += __shfl_xor(s2, off);
  }
  __shared__ float rs[4], rs2[4];
  int wid = t >> 6;
  if ((t & 63) == 0) { rs[wid] = s; rs2[wid] = s2; }
  __syncthreads();
  float S1 = rs[0] + rs[1] + rs[2] + rs[3];
  float S2 = rs2[0] + rs2[1] + rs2[2] + rs2[3];
  float mu = S1 * (1.f / E_);
  float var = S2 * (1.f / E_) - mu * mu;
  float inv = rsqrtf(var + 1e-5f);
  float4 gv = *(const float4*)&g[t * 4];
  float4 bbv = *(const float4*)&bb[t * 4];
  float4 ov;
  ov.x = (u0 - mu) * inv * gv.x + bbv.x;
  ov.y = (u1 - mu) * inv * gv.y + bbv.y;
  ov.z = (u2 - mu) * inv * gv.z + bbv.z;
  ov.w = (u3 - mu) * inv * gv.w + bbv.w;
  *(float4*)&outF[base] = ov;
  if (OUTBF16) {
    bf16x4 obv;
    obv.x = (bf16)ov.x; obv.y = (bf16)ov.y; obv.z = (bf16)ov.z; obv.w = (bf16)ov.w;
    *(bf16x4*)&outB[base] = obv;
  }
}

// ---------------- MFMA flash attention (cont-based scores) ------------------
__global__ __launch_bounds__(256) void k_attn2(
    const float* __restrict__ qsT, const float* __restrict__ kmT,
    const bf16* __restrict__ cont, const float* __restrict__ swin,
    const bf16* __restrict__ vT,
    bf16* __restrict__ o, bf16* __restrict__ opart, float* __restrict__ mlpart) {
  int q = blockIdx.x & 3;
  int iwg = blockIdx.x >> 2;       // 0..15
  if (q > iwg) return;             // ntile = iwg+1; quarter q needs q < ntile
  int bh = blockIdx.y;
  int b = bh >> 3, h = bh & 7;
  int t = threadIdx.x;
  int wid = t >> 6, lane = t & 63;
  int iw = iwg * 4 + wid;          // 0..63
  int m = lane & 15, ko = lane >> 4;
  int ntile = iwg + 1;

  __shared__ float sw[S_];
  *(float4*)&sw[t * 4] = *(const float4*)&swin[(size_t)bh * S_ + t * 4];
  __syncthreads();

  int i_row = iw * 16 + m;
  float qs_i = qsT[(size_t)bh * S_ + i_row];
  const bf16* cr = cont + ((size_t)bh << 20) + (size_t)i_row * S_;

  f32x4 acc[8];
#pragma unroll
  for (int nf = 0; nf < 8; ++nf) acc[nf] = (f32x4){0.f, 0.f, 0.f, 0.f};
  float m_run = -INFINITY, l_run = 0.f;

  for (int jt = q; jt < ntile; jt += 4) {
    int j0 = jt * 64;
    float pv[2][8];
    float mx = -INFINITY;
    bf16x8 cv[2];
    cv[0] = *(const bf16x8*)&cr[j0 + ko * 8];
    cv[1] = *(const bf16x8*)&cr[j0 + 32 + ko * 8];
#pragma unroll
    for (int s = 0; s < 2; ++s) {
      int bj = j0 + s * 32 + ko * 8;
      float4 km0 = *(const float4*)&kmT[(size_t)bh * S_ + bj];
      float4 km1 = *(const float4*)&kmT[(size_t)bh * S_ + bj + 4];
      float kmv[8] = {km0.x, km0.y, km0.z, km0.w, km1.x, km1.y, km1.z, km1.w};
#pragma unroll
      for (int e = 0; e < 8; ++e) {
        int j = bj + e;
        int dd = i_row - j;
        float val = sw[dd >= 0 ? dd : 0] + qs_i + kmv[e] + 0.25f * (float)cv[s][e];
        val = (dd >= 0) ? val : -INFINITY;   // cndmask, branch-free
        pv[s][e] = val;
        mx = fmaxf(mx, val);
      }
    }
    mx = fmaxf(mx, __shfl_xor(mx, 16));
    mx = fmaxf(mx, __shfl_xor(mx, 32));
    float mnew = fmaxf(m_run, mx);
    float scale = __expf(m_run - mnew);
    float lsum = 0.f;
    bf16x8 pa[2];
#pragma unroll
    for (int s = 0; s < 2; ++s)
#pragma unroll
      for (int e = 0; e < 8; ++e) {
        float p = __expf(pv[s][e] - mnew);
        lsum += p;
        pa[s][e] = (bf16)p;
      }
    lsum += __shfl_xor(lsum, 16);
    lsum += __shfl_xor(lsum, 32);
    l_run = l_run * scale + lsum;
    m_run = mnew;
    float sc[4];
#pragma unroll
    for (int r = 0; r < 4; ++r) sc[r] = __shfl(scale, ko * 4 + r);
#pragma unroll
    for (int nf = 0; nf < 8; ++nf)
#pragma unroll
      for (int r = 0; r < 4; ++r) acc[nf][r] *= sc[r];
#pragma unroll
    for (int s = 0; s < 2; ++s) {
      int bj = j0 + s * 32 + ko * 8;
#pragma unroll
      for (int nf = 0; nf < 8; ++nf) {
        int d = nf * 16 + m;
        bf16x8 bv = *(const bf16x8*)&vT[((size_t)bh * HD_ + d) * S_ + bj];
        acc[nf] = __builtin_amdgcn_mfma_f32_16x16x32_bf16(pa[s], bv, acc[nf], 0, 0, 0);
      }
    }
  }

  if (ntile == 1) {                // iw<4 (only q==0): finalize directly
    float lr[4];
#pragma unroll
    for (int r = 0; r < 4; ++r) lr[r] = __shfl(l_run, ko * 4 + r);
#pragma unroll
    for (int nf = 0; nf < 8; ++nf) {
      int d = nf * 16 + m;
#pragma unroll
      for (int r = 0; r < 4; ++r) {
        int row = iw * 16 + ko * 4 + r;
        o[(((size_t)b * S_ + row) * H_ + h) * HD_ + d] = (bf16)(acc[nf][r] / lr[r]);
      }
    }
  } else {
    bf16* op = opart + ((size_t)(q * 16 + bh) * 64 + iw) * 2048;
#pragma unroll
    for (int nf = 0; nf < 8; ++nf) {
      int d = nf * 16 + m;
#pragma unroll
      for (int r = 0; r < 4; ++r) op[(ko * 4 + r) * 128 + d] = (bf16)acc[nf][r];
    }
    if (lane < 16) {
      float* mlp = mlpart + ((size_t)(q * 16 + bh) * 64 + iw) * 32;
      mlp[m * 2 + 0] = m_run;
      mlp[m * 2 + 1] = l_run;
    }
  }
}

// ---------------- combine up to 4 attention quarters (rows iw>=4) -----------
__global__ __launch_bounds__(256) void k_comb(const bf16* __restrict__ opart,
                                              const float* __restrict__ mlpart,
                                              bf16* __restrict__ o) {
  int blk = blockIdx.x;
  int bh = blk / 60, iw = blk % 60 + 4;
  int b = bh >> 3, h = bh & 7;
  int t = threadIdx.x;
  int r = t >> 4, d0 = (t & 15) * 8;
  int nq = iw / 4 + 1;
  if (nq > 4) nq = 4;
  float mq[4], lq[4];
  float mm = -INFINITY;
#pragma unroll
  for (int q = 0; q < 4; ++q) {
    if (q < nq) {
      size_t idx = (size_t)(q * 16 + bh) * 64 + iw;
      mq[q] = mlpart[idx * 32 + r * 2];
      lq[q] = mlpart[idx * 32 + r * 2 + 1];
      mm = fmaxf(mm, mq[q]);
    }
  }
  float L = 0.f;
  float acc[8] = {0.f, 0.f, 0.f, 0.f, 0.f, 0.f, 0.f, 0.f};
#pragma unroll
  for (int q = 0; q < 4; ++q) {
    if (q < nq) {
      float e = __expf(mq[q] - mm);
      L += lq[q] * e;
      size_t idx = (size_t)(q * 16 + bh) * 64 + iw;
      bf16x8 v = *(const bf16x8*)&opart[(idx * 16 + r) * 128 + d0];
#pragma unroll
      for (int k = 0; k < 8; ++k) acc[k] += (float)v[k] * e;
    }
  }
  float inv = 1.f / L;
  bf16x8 ov;
#pragma unroll
  for (int k = 0; k < 8; ++k) ov[k] = (bf16)(acc[k] * inv);
  int row = iw * 16 + r;
  *(bf16x8*)&o[(((size_t)b * S_ + row) * H_ + h) * HD_ + d0] = ov;
}

}  // namespace

extern "C" void kernel_launch(void* const* d_in, const int* in_sizes, int n_in,
                              void* d_out, int out_size, void* d_ws, size_t ws_size,
                              hipStream_t stream) {
  (void)in_sizes; (void)n_in; (void)out_size; (void)ws_size;
  const float* x       = (const float*)d_in[0];
  const float* v_w     = (const float*)d_in[1];
  const float* v_b     = (const float*)d_in[2];
  const float* out_w   = (const float*)d_in[3];
  const float* out_b   = (const float*)d_in[4];
  const float* qmod_w  = (const float*)d_in[5];
  const float* qmod_b  = (const float*)d_in[6];
  const float* kmod_w  = (const float*)d_in[7];
  const float* kmod_b  = (const float*)d_in[8];
  const float* gate_w1 = (const float*)d_in[9];
  const float* gate_b1 = (const float*)d_in[10];
  const float* gate_w2 = (const float*)d_in[11];
  const float* gate_b2 = (const float*)d_in[12];
  const float* mod_w1  = (const float*)d_in[13];
  const float* mod_b1  = (const float*)d_in[14];
  const float* mod_w2  = (const float*)d_in[15];
  const float* mod_b2  = (const float*)d_in[16];
  const float* mod_basis = (const float*)d_in[17];
  const float* freqs   = (const float*)d_in[18];
  const float* amps    = (const float*)d_in[19];
  const float* phases  = (const float*)d_in[20];
  const float* cwq     = (const float*)d_in[21];
  const float* cwk     = (const float*)d_in[22];
  const float* ffn_w1  = (const float*)d_in[23];
  const float* ffn_b1  = (const float*)d_in[24];
  const float* ffn_w2  = (const float*)d_in[25];
  const float* ffn_b2  = (const float*)d_in[26];
  const float* ln_ag   = (const float*)d_in[27];
  const float* ln_ab   = (const float*)d_in[28];
  const float* ln_fg   = (const float*)d_in[29];
  const float* ln_fb   = (const float*)d_in[30];

  char* wsc = (char*)d_ws;
  size_t off = 0;
  auto alloc = [&](size_t bytes) -> void* {
    void* p = wsc + off;
    off += (bytes + 255) & ~(size_t)255;
    return p;
  };
  float* pooled = (float*)alloc(2048 * 4);
  float* part   = (float*)alloc(65536 * 4);
  float2* gpart = (float2*)alloc((size_t)2 * H_ * 16 * 128 * 8);
  float* wmod   = (float*)alloc(2048 * 4);
  float* kerns  = (float*)alloc((size_t)H_ * M_ * S_ * 4);
  float* swin   = (float*)alloc((size_t)B_ * H_ * S_ * 4);
  float* qsT    = (float*)alloc((size_t)B_ * H_ * S_ * 4);
  float* kmT    = (float*)alloc((size_t)B_ * H_ * S_ * 4);
  float* qcb    = (float*)alloc((size_t)B_ * H_ * S_ * R_ * 4);
  float* kcb    = (float*)alloc((size_t)B_ * H_ * S_ * R_ * 4);
  float* ybuf   = (float*)alloc((size_t)B_ * S_ * E_ * 4);       // 8MB (post-LN y)
  bf16* xb      = (bf16*)alloc((size_t)B_ * S_ * E_ * 2);
  bf16* yb      = (bf16*)alloc((size_t)B_ * S_ * E_ * 2);
  bf16* vwT     = (bf16*)alloc((size_t)E_ * E_ * 2);
  bf16* outwT   = (bf16*)alloc((size_t)E_ * E_ * 2);
  bf16* ffn1T   = (bf16*)alloc((size_t)E_ * FFNH_ * 2);
  bf16* ffn2T   = (bf16*)alloc((size_t)FFNH_ * E_ * 2);
  bf16* wcatT   = (bf16*)alloc((size_t)256 * E_ * 2);            // 0.5MB
  bf16* vT      = (bf16*)alloc((size_t)B_ * S_ * E_ * 2);        // v [b,hd,s]
  bf16* ob      = (bf16*)alloc((size_t)B_ * S_ * E_ * 2);        // attn out
  float* mlpart = (float*)alloc((size_t)4 * 16 * 64 * 16 * 2 * 4);
  char* poolU2  = (char*)alloc((size_t)B_ * S_ * FFNH_ * 2);     // 16MB union
  bf16* opart = (bf16*)poolU2;     // 16MB (attn phase)
  bf16* hb    = (bf16*)poolU2;     // 16MB (FFN phase)
  // P1: 64MB union. fp16 partials: qk [0,8MB); v [0,16MB); out [0,16MB);
  // ffn1 [0,32MB); ffn2 [0,16MB). cont (32MB bf16) at [16MB,48MB) until attn2.
  char* P1c = (char*)alloc((size_t)64 * 1024 * 1024);
  f16*  P1  = (f16*)P1c;
  bf16* cont = (bf16*)(P1c + (size_t)16 * 1024 * 1024);

  float* outp = (float*)d_out;
  const int BS = B_ * S_;

  // prep
  k_cvt_bf16<<<(BS * E_) / 1024, 256, 0, stream>>>(x, xb);
  k_wt<<<dim3(E_ / 32, E_ / 32), 256, 0, stream>>>(v_w, vwT, E_, E_);
  k_wt<<<dim3(E_ / 32, E_ / 32), 256, 0, stream>>>(out_w, outwT, E_, E_);
  k_wt<<<dim3(FFNH_ / 32, E_ / 32), 256, 0, stream>>>(ffn_w1, ffn1T, E_, FFNH_);
  k_wt<<<dim3(E_ / 32, FFNH_ / 32), 256, 0, stream>>>(ffn_w2, ffn2T, FFNH_, E_);
  k_wcat<<<(256 * E_) / 256, 256, 0, stream>>>(qmod_w, kmod_w, cwq, cwk, wcatT);

  // scores pipeline
  k_pool_partial<<<B_ * SCH, 256, 0, stream>>>(x, part);
  k_pool_reduce<<<B_, 256, 0, stream>>>(part, pooled);
  k_gate1<<<dim3(16, H_, 2), 256, 0, stream>>>(pooled, gate_w1, mod_w1, gpart);
  k_gate2<<<B_ * H_, 256, 0, stream>>>(gpart, gate_b1, gate_w2, gate_b2,
                                       mod_b1, mod_w2, mod_b2, mod_basis, wmod);
  k_waves<<<H_ * M_ * (S_ / 256), 256, 0, stream>>>(freqs, amps, phases, kerns);
  k_swin<<<B_ * H_ * (S_ / 256), 256, 0, stream>>>(wmod, kerns, swin);

  // qs/km/qc/kc via one MFMA GEMM: [xb (2048x1024)] @ WcatT^T -> 2048x256
  k_gemm_tlp<1><<<dim3(4, 32, 8), 64, 0, stream>>>(
      xb, wcatT, P1, 256, E_, 128, 0, (size_t)2048 * 256);
  k_fin_qk<<<2048, 256, 0, stream>>>(P1, qmod_b, kmod_b, qsT, kmT, qcb, kcb);

  // content logits precompute (lower-tri 128-tiles), bf16
  k_cont<<<dim3(8, 8, 16), 256, 0, stream>>>(qcb, kcb, cont);

  // vT[b][hd][s] = vwT x xb^T, split-K=4 x batch2, fp16 partials
  k_gemm_tlp<2><<<dim3(16, 16, 8), 64, 0, stream>>>(
      vwT, xb, P1, S_, E_, 256, (size_t)S_ * E_, (size_t)1024 * 1024);
  k_fin_vT<<<2048, 256, 0, stream>>>(P1, v_b, vT);

  k_attn2<<<dim3(64, 16), 256, 0, stream>>>(qsT, kmT, cont, swin, vT, ob, opart, mlpart);
  k_comb<<<16 * 60, 256, 0, stream>>>(opart, mlpart, ob);

  // y = LN(o @ out_w + out_b + x)  (split-K=4, fused fin+LN)
  k_gemm_tlp<1><<<dim3(16, 32, 4), 64, 0, stream>>>(
      ob, outwT, P1, E_, E_, 256, 0, (size_t)2048 * 1024);
  k_fin_ln<4, true><<<2048, 256, 0, stream>>>(P1, out_b, x, ln_ag, ln_ab, ybuf, yb);

  // h = gelu(y @ ffn_w1 + b1)  (split-K=2)
  k_gemm_tlp<1><<<dim3(64, 32, 2), 64, 0, stream>>>(
      yb, ffn1T, P1, FFNH_, E_, 512, 0, (size_t)2048 * 4096);
  k_fin_gelu<<<8192, 256, 0, stream>>>(P1, ffn_b1, hb);

  // out = LN(h @ ffn_w2 + b2 + y)  (split-K=4)
  k_gemm_tlp<1><<<dim3(16, 32, 4), 64, 0, stream>>>(
      hb, ffn2T, P1, E_, FFNH_, 1024, 0, (size_t)2048 * 1024);
  k_fin_ln<4, false><<<2048, 256, 0, stream>>>(P1, ffn_b2, ybuf, ln_fg, ln_fb, outp, nullptr);
}

// Round 15
// 271.143 us; speedup vs baseline: 1.2671x; 1.2671x over previous
//
#include <hip/hip_runtime.h>
#include <math.h>
#include <stdint.h>

namespace {

constexpr int B_ = 2, S_ = 1024, E_ = 1024, H_ = 8, HD_ = 128;
constexpr int M_ = 128, W_ = 32, GH_ = 128, R_ = 8, MR_ = 8, FFNH_ = 4096;
constexpr int SCH = 32;            // s-chunks for pooling
constexpr int SPC = S_ / SCH;      // 32 rows per chunk

typedef __bf16 bf16;
typedef _Float16 f16;
typedef __attribute__((ext_vector_type(8))) __bf16 bf16x8;
typedef __attribute__((ext_vector_type(4))) __bf16 bf16x4;
typedef __attribute__((ext_vector_type(4))) _Float16 f16x4;
typedef __attribute__((ext_vector_type(4))) float f32x4;

__device__ inline float gelu_tanh(float u) {
  float u3 = u * u * u;
  return 0.5f * u * (1.f + tanhf(0.7978845608028654f * (u + 0.044715f * u3)));
}

__device__ __forceinline__ void gl_lds16(const void* g, void* l) {
  __builtin_amdgcn_global_load_lds((const __attribute__((address_space(1))) void*)g,
                                   (__attribute__((address_space(3))) void*)l, 16, 0, 0);
}

// ---------------- fp32 -> bf16 elementwise ---------------------------------
__global__ __launch_bounds__(256) void k_cvt_bf16(const float* __restrict__ in,
                                                  bf16* __restrict__ out) {
  int i = blockIdx.x * 256 + threadIdx.x;
  float4 v = *(const float4*)(in + (size_t)i * 4);
  bf16x4 o;
  o.x = (bf16)v.x; o.y = (bf16)v.y; o.z = (bf16)v.z; o.w = (bf16)v.w;
  *(bf16x4*)(out + (size_t)i * 4) = o;
}

// ---------------- weight (K,N) fp32 -> (N,K) bf16 transpose ----------------
__global__ __launch_bounds__(256) void k_wt(const float* __restrict__ w,
                                            bf16* __restrict__ wT, int K, int N) {
  __shared__ float tile[32][33];
  int n0 = blockIdx.x * 32, k0 = blockIdx.y * 32;
  int tx = threadIdx.x & 31, ty = threadIdx.x >> 5;
  for (int r = ty; r < 32; r += 8) tile[r][tx] = w[(size_t)(k0 + r) * N + n0 + tx];
  __syncthreads();
  for (int r = ty; r < 32; r += 8) wT[(size_t)(n0 + r) * K + k0 + tx] = (bf16)tile[tx][r];
}

// ---------------- Wcat^T (256 x 1024) bf16: [qmod|kmod|diag(cwq)|diag(cwk)] -
__global__ __launch_bounds__(256) void k_wcat(const float* __restrict__ qmw,
                                              const float* __restrict__ kmw,
                                              const float* __restrict__ cwq,
                                              const float* __restrict__ cwk,
                                              bf16* __restrict__ wcat) {
  int idx = blockIdx.x * 256 + threadIdx.x;   // over 256*1024
  int n = idx >> 10, k = idx & 1023;
  float v = 0.f;
  if (n < 8) {
    v = qmw[k * 8 + n];
  } else if (n < 16) {
    v = kmw[k * 8 + (n - 8)];
  } else if (n < 80) {
    int u = n - 16, h = u >> 3, r = u & 7;
    int kk = k - h * 128;
    if (kk >= 0 && kk < 128) v = cwq[((size_t)h * 128 + kk) * 8 + r];
  } else if (n < 144) {
    int u = n - 80, h = u >> 3, r = u & 7;
    int kk = k - h * 128;
    if (kk >= 0 && kk < 128) v = cwk[((size_t)h * 128 + kk) * 8 + r];
  }
  wcat[idx] = (bf16)v;
}

// ---------------- finish qk GEMM: sum fp16 partials, scatter -----------------
__global__ __launch_bounds__(256) void k_fin_qk(
    const f16* __restrict__ P, const float* __restrict__ qmb,
    const float* __restrict__ kmb, float* __restrict__ qsT,
    float* __restrict__ kmT, float* __restrict__ qc, float* __restrict__ kc) {
  int row = blockIdx.x;            // 0..2047
  int t = threadIdx.x;
  if (t >= 144) return;
  int b = row >> 10, s = row & 1023;
  const size_t mn = (size_t)2048 * 256;
  float sum = 0.f;
#pragma unroll
  for (int z = 0; z < 8; ++z) sum += (float)P[(size_t)z * mn + (size_t)row * 256 + t];
  if (t < 8) {
    qsT[((size_t)(b * 8 + t)) * 1024 + s] = sum + qmb[t];
  } else if (t < 16) {
    kmT[((size_t)(b * 8 + t - 8)) * 1024 + s] = sum + kmb[t - 8];
  } else if (t < 80) {
    int u = t - 16, h = u >> 3, r = u & 7;
    qc[(((size_t)(b * 8 + h)) * 1024 + s) * 8 + r] = sum;
  } else {
    int u = t - 80, h = u >> 3, r = u & 7;
    kc[(((size_t)(b * 8 + h)) * 1024 + s) * 8 + r] = sum;
  }
}

// ---------------- pooled = mean_s x[b,s,:] ---------------------------------
__global__ __launch_bounds__(256) void k_pool_partial(const float* __restrict__ x,
                                                      float* __restrict__ part) {
  int blk = blockIdx.x;
  int b = blk / SCH, c = blk % SCH;
  int t = threadIdx.x;
  const float* xp = x + (size_t)b * S_ * E_ + (size_t)c * SPC * E_;
  float acc[4] = {0.f, 0.f, 0.f, 0.f};
  for (int s = 0; s < SPC; ++s) {
    const float* row = xp + (size_t)s * E_;
#pragma unroll
    for (int q = 0; q < 4; ++q) acc[q] += row[t + q * 256];
  }
  float* pp = part + (size_t)blk * E_;
#pragma unroll
  for (int q = 0; q < 4; ++q) pp[t + q * 256] = acc[q];
}

__global__ __launch_bounds__(256) void k_pool_reduce(const float* __restrict__ part,
                                                     float* __restrict__ pooled) {
  int b = blockIdx.x;
  int t = threadIdx.x;
#pragma unroll
  for (int q = 0; q < 4; ++q) {
    int e = t + q * 256;
    float s = 0.f;
    for (int c = 0; c < SCH; ++c) s += part[(size_t)(b * SCH + c) * E_ + e];
    pooled[b * E_ + e] = s * (1.0f / S_);
  }
}

// ---------------- gate first layer: coalesced split-E partials --------------
__global__ __launch_bounds__(256) void k_gate1(
    const float* __restrict__ pooled,
    const float* __restrict__ gw1, const float* __restrict__ mw1,
    float2* __restrict__ part) {
  int chunk = blockIdx.x;          // 0..15
  int h = blockIdx.y;              // 0..7
  int mat = blockIdx.z;            // 0: gate, 1: mod
  const float* w = mat ? mw1 : gw1;
  int t = threadIdx.x;
  int g = t & 127, half = t >> 7;
  int e0 = chunk * 64 + half * 32;
  const float* wp = w + (size_t)h * E_ * GH_ + (size_t)e0 * GH_ + g;
  const float* p0 = pooled + e0;
  const float* p1 = pooled + E_ + e0;
  float a0 = 0.f, a1 = 0.f;
#pragma unroll 8
  for (int r = 0; r < 32; ++r) {
    float wv = wp[(size_t)r * GH_];
    a0 += p0[r] * wv;
    a1 += p1[r] * wv;
  }
  __shared__ float red[2][2][128];
  red[half][0][g] = a0;
  red[half][1][g] = a1;
  __syncthreads();
  if (half == 0) {
    float2 o;
    o.x = red[0][0][g] + red[1][0][g];
    o.y = red[0][1][g] + red[1][1][g];
    part[(((size_t)mat * H_ + h) * 16 + chunk) * 128 + g] = o;
  }
}

// ---------------- gate finish ------------------------------------------------
__global__ __launch_bounds__(256) void k_gate2(
    const float2* __restrict__ part,
    const float* __restrict__ gb1, const float* __restrict__ gw2, const float* __restrict__ gb2,
    const float* __restrict__ mb1, const float* __restrict__ mw2, const float* __restrict__ mb2,
    const float* __restrict__ mbasis, float* __restrict__ wmod) {
  int bh = blockIdx.x;
  int b = bh >> 3, h = bh & 7;
  int t = threadIdx.x;
  __shared__ float ghs[GH_], mhs[GH_], glog[M_], mrs[MR_];
  __shared__ float red2[2][128];
  __shared__ float rbuf[128];
  {
    int g = t & 127, mat = t >> 7;
    const float2* pp = part + ((size_t)mat * H_ + h) * 16 * 128 + g;
    float acc = 0.f;
#pragma unroll
    for (int c = 0; c < 16; ++c) {
      float2 v = pp[(size_t)c * 128];
      acc += b ? v.y : v.x;
    }
    acc += (mat ? mb1 : gb1)[h * GH_ + g];
    acc = fmaxf(acc, 0.f);
    if (mat == 0) ghs[g] = acc; else mhs[g] = acc;
  }
  __syncthreads();
  {
    int m = t & 127, half = t >> 7;
    float acc = 0.f;
    const float* wp = gw2 + (size_t)h * GH_ * M_ + m;
#pragma unroll 4
    for (int g = half * 64; g < half * 64 + 64; ++g)
      acc += ghs[g] * wp[(size_t)g * M_];
    red2[half][m] = acc;
  }
  __syncthreads();
  if (t < 128) glog[t] = red2[0][t] + red2[1][t] + gb2[h * M_ + t];
  if (t < 64) {
    int r = t & 7, seg = t >> 3;
    float acc = 0.f;
    const float* wp = mw2 + (size_t)h * GH_ * MR_ + r;
    for (int g = seg * 16; g < seg * 16 + 16; ++g) acc += mhs[g] * wp[(size_t)g * MR_];
    acc += __shfl_xor(acc, 8);
    acc += __shfl_xor(acc, 16);
    acc += __shfl_xor(acc, 32);
    if (t < 8) mrs[t] = acc + mb2[h * MR_ + t];
  }
  __syncthreads();
  if (t < 128) rbuf[t] = glog[t];
  __syncthreads();
  for (int off = 64; off >= 1; off >>= 1) {
    if (t < off) rbuf[t] = fmaxf(rbuf[t], rbuf[t + off]);
    __syncthreads();
  }
  float mx = rbuf[0];
  __syncthreads();
  float ev = 0.f;
  if (t < 128) ev = expf(glog[t] - mx);
  __syncthreads();
  if (t < 128) rbuf[t] = ev;
  __syncthreads();
  for (int off = 64; off >= 1; off >>= 1) {
    if (t < off) rbuf[t] += rbuf[t + off];
    __syncthreads();
  }
  float inv = 1.f / rbuf[0];
  if (t < 128) {
    float wsel = ev * inv;
    float md = 0.f;
#pragma unroll
    for (int r = 0; r < MR_; ++r) md += mrs[r] * mbasis[((size_t)h * MR_ + r) * M_ + t];
    wmod[bh * M_ + t] = wsel * (1.f + md);
  }
}

// ---------------- wave kernels ---------------------------------------------
__global__ __launch_bounds__(256) void k_waves(const float* __restrict__ freqs,
                                               const float* __restrict__ amps,
                                               const float* __restrict__ phases,
                                               float* __restrict__ kerns) {
  int blk = blockIdx.x;
  int lt = blk & 3;
  int hm = blk >> 2;
  int t = threadIdx.x;
  __shared__ float f0[W_], f1[W_], am[W_], ph[W_];
  if (t < W_) {
    f0[t] = freqs[((size_t)hm * W_ + t) * 2 + 0];
    f1[t] = freqs[((size_t)hm * W_ + t) * 2 + 1];
    am[t] = amps[(size_t)hm * W_ + t];
    ph[t] = phases[(size_t)hm * W_ + t];
  }
  __syncthreads();
  int l = lt * 256 + t;
  float rel = (float)(l - (S_ - 1));
  float p1 = rel * (1.0f / S_);
  float p2 = (rel < 0.f) ? (-sqrtf(-rel + 1e-6f) * (1.0f / 32.0f)) : 0.f;
  const float TWO_PI = 6.28318530717958647692f;
  float acc = 0.f;
#pragma unroll
  for (int w = 0; w < W_; ++w)
    acc += am[w] * __sinf(TWO_PI * (f0[w] * p1 + f1[w] * p2) + ph[w]);
  kerns[(size_t)hm * S_ + l] = acc;
}

// ---------------- swin ------------------------------------------------------
__global__ __launch_bounds__(256) void k_swin(const float* __restrict__ wmod,
                                              const float* __restrict__ kerns,
                                              float* __restrict__ swin) {
  int blk = blockIdx.x;
  int dt = blk & 3;
  int bh = blk >> 2;
  int h = bh & 7;
  int t = threadIdx.x;
  __shared__ float wm[M_];
  if (t < M_) wm[t] = wmod[bh * M_ + t];
  __syncthreads();
  int d = dt * 256 + t;
  int l = (S_ - 1) - d;
  float acc = 0.f;
  for (int m = 0; m < M_; ++m) acc += wm[m] * kerns[((size_t)h * M_ + m) * S_ + l];
  float dd = (float)d;
  float win = expf(-dd * dd * (1.0f / 131072.0f));
  swin[(size_t)bh * S_ + d] = 3.0f * win * acc;
}

// ---------------- cont[bh][i][j] = qc_i . kc_j  (bf16, lower-tri 128-tiles) -
__global__ __launch_bounds__(256) void k_cont(const float* __restrict__ qc,
                                              const float* __restrict__ kc,
                                              bf16* __restrict__ cont) {
  int jt = blockIdx.x, it = blockIdx.y;
  if (jt > it) return;
  int bh = blockIdx.z;
  int t = threadIdx.x;
  int w = t >> 6, lane = t & 63;
  int ln = lane & 15, ko = lane >> 4;
  int i0 = it * 128 + w * 32;
  int j0 = jt * 128;

  bf16x8 av[2];
#pragma unroll
  for (int mi = 0; mi < 2; ++mi) {
    bf16x8 a;
#pragma unroll
    for (int k = 0; k < 8; ++k) a[k] = (bf16)0.f;
    if (ko == 0) {
      const float* qp = &qc[((size_t)bh * S_ + i0 + mi * 16 + ln) * 8];
      float4 q0 = *(const float4*)qp;
      float4 q1 = *(const float4*)(qp + 4);
      a[0] = (bf16)q0.x; a[1] = (bf16)q0.y; a[2] = (bf16)q0.z; a[3] = (bf16)q0.w;
      a[4] = (bf16)q1.x; a[5] = (bf16)q1.y; a[6] = (bf16)q1.z; a[7] = (bf16)q1.w;
    }
    av[mi] = a;
  }
  bf16x8 bv[8];
#pragma unroll
  for (int nb = 0; nb < 8; ++nb) {
    bf16x8 bb;
#pragma unroll
    for (int k = 0; k < 8; ++k) bb[k] = (bf16)0.f;
    if (ko == 0) {
      const float* kp = &kc[((size_t)bh * S_ + j0 + nb * 16 + ln) * 8];
      float4 k0 = *(const float4*)kp;
      float4 k1 = *(const float4*)(kp + 4);
      bb[0] = (bf16)k0.x; bb[1] = (bf16)k0.y; bb[2] = (bf16)k0.z; bb[3] = (bf16)k0.w;
      bb[4] = (bf16)k1.x; bb[5] = (bf16)k1.y; bb[6] = (bf16)k1.z; bb[7] = (bf16)k1.w;
    }
    bv[nb] = bb;
  }
  f32x4 acc[2][8];
#pragma unroll
  for (int mi = 0; mi < 2; ++mi)
#pragma unroll
    for (int nb = 0; nb < 8; ++nb) {
      acc[mi][nb] = (f32x4){0.f, 0.f, 0.f, 0.f};
      acc[mi][nb] = __builtin_amdgcn_mfma_f32_16x16x32_bf16(av[mi], bv[nb], acc[mi][nb], 0, 0, 0);
    }
  bf16* cb = cont + ((size_t)bh << 20);
#pragma unroll
  for (int mi = 0; mi < 2; ++mi)
#pragma unroll
    for (int nb = 0; nb < 8; ++nb) {
      int col = j0 + nb * 16 + ln;
#pragma unroll
      for (int reg = 0; reg < 4; ++reg) {
        int row = i0 + mi * 16 + ko * 4 + reg;
        cb[(size_t)row * S_ + col] = (bf16)acc[mi][nb][reg];
      }
    }
}

// ---------------- bf16 MFMA GEMM, BK=64, fused epilogue (FFN1), swizzled ----
template <bool GELU, bool RES, bool OUTF32, bool OUTBF16>
__global__ __launch_bounds__(256) void k_gemm_mfma(
    const bf16* __restrict__ A, const bf16* __restrict__ BT,
    const float* __restrict__ bias, const float* __restrict__ res,
    float* __restrict__ C, bf16* __restrict__ Cb, int N, int K) {
  __shared__ bf16 Asb[2][8192];
  __shared__ bf16 Bsb[2][8192];
  int t = threadIdx.x;
  // XCD-aware bijective remap, row-tile fastest (L2 locality)
  int gx = gridDim.x, gy = gridDim.y;
  int nwg = gx * gy;
  int lin = blockIdx.y * gx + blockIdx.x;
  if (!(nwg & 7)) {
    int cpx = nwg >> 3;
    lin = (lin & 7) * cpx + (lin >> 3);
  }
  int by = lin % gy;
  int bx = lin / gy;
  int row0 = by * 128, col0 = bx * 128;
  int lane = t & 63, wid = t >> 6;
  int wr = wid >> 1, wc = wid & 1;

  const bf16* AgP[4];
  const bf16* BgP[4];
  int ldo[4];
#pragma unroll
  for (int j = 0; j < 4; ++j) {
    int p = t + j * 256;           // 0..1023
    int sub = p >> 9;
    int pp = p & 511;
    int rt = ((pp >> 6) << 4) | (pp & 15);
    int kb = (pp >> 4) & 3;
    AgP[j] = A + (size_t)(row0 + rt) * K + sub * 32 + kb * 8;
    BgP[j] = BT + (size_t)(col0 + rt) * K + sub * 32 + kb * 8;
    ldo[j] = sub * 4096 + pp * 8;
  }

  f32x4 acc[4][4];
#pragma unroll
  for (int m = 0; m < 4; ++m)
#pragma unroll
    for (int n = 0; n < 4; ++n) acc[m][n] = (f32x4){0.f, 0.f, 0.f, 0.f};

#pragma unroll
  for (int j = 0; j < 4; ++j) {
    gl_lds16(AgP[j], &Asb[0][ldo[j]]);
    gl_lds16(BgP[j], &Bsb[0][ldo[j]]);
  }

  const int nt = K >> 6;
  for (int kt = 0; kt < nt; ++kt) {
    int cur = kt & 1;
    __syncthreads();
    if (kt + 1 < nt) {
      size_t go = (size_t)(kt + 1) * 64;
      int nb = cur ^ 1;
#pragma unroll
      for (int j = 0; j < 4; ++j) {
        gl_lds16(AgP[j] + go, &Asb[nb][ldo[j]]);
        gl_lds16(BgP[j] + go, &Bsb[nb][ldo[j]]);
      }
    }
#pragma unroll
    for (int kk = 0; kk < 2; ++kk) {
      bf16x8 af[4], bfr[4];
#pragma unroll
      for (int m = 0; m < 4; ++m)
        af[m] = *(const bf16x8*)&Asb[cur][kk * 4096 + ((wr * 4 + m) * 64 + lane) * 8];
#pragma unroll
      for (int n = 0; n < 4; ++n)
        bfr[n] = *(const bf16x8*)&Bsb[cur][kk * 4096 + ((wc * 4 + n) * 64 + lane) * 8];
#pragma unroll
      for (int m = 0; m < 4; ++m)
#pragma unroll
        for (int n = 0; n < 4; ++n)
          acc[m][n] = __builtin_amdgcn_mfma_f32_16x16x32_bf16(af[m], bfr[n], acc[m][n], 0, 0, 0);
    }
  }

  int r0 = row0 + wr * 64, c0 = col0 + wc * 64;
#pragma unroll
  for (int m = 0; m < 4; ++m) {
#pragma unroll
    for (int n = 0; n < 4; ++n) {
      int col = c0 + n * 16 + (lane & 15);
      float bcol = bias[col];
#pragma unroll
      for (int reg = 0; reg < 4; ++reg) {
        int row = r0 + m * 16 + ((lane >> 4) << 2) + reg;
        float u = acc[m][n][reg] + bcol;
        if (GELU) u = gelu_tanh(u);
        if (RES) u += res[(size_t)row * N + col];
        if (OUTF32) C[(size_t)row * N + col] = u;
        if (OUTBF16) Cb[(size_t)row * N + col] = (bf16)u;
      }
    }
  }
}

// ---------------- split-K bf16 MFMA GEMM, BK=64, swizzled (by-fastest) ------
template <int NB>
__global__ __launch_bounds__(256) void k_gemm_sk(
    const bf16* __restrict__ A, const bf16* __restrict__ BT,
    f16* __restrict__ P, int N, int K, int Kslice, size_t strideB, size_t mn) {
  __shared__ bf16 Asb[2][8192];
  __shared__ bf16 Bsb[2][8192];
  int t = threadIdx.x;
  // XCD-aware bijective remap, row-tile (by) fastest for L2 locality
  int gx = gridDim.x, gy = gridDim.y;
  int nwg = gx * gy * gridDim.z;
  int lin = (blockIdx.z * gy + blockIdx.y) * gx + blockIdx.x;
  if (!(nwg & 7)) {
    int cpx = nwg >> 3;
    lin = (lin & 7) * cpx + (lin >> 3);
  }
  int by = lin % gy;
  int rem = lin / gy;
  int bx = rem % gx;
  int z = rem / gx;

  int bb = z % NB;
  int k0 = (z / NB) * Kslice;
  const bf16* Bbase = BT + (size_t)bb * strideB;
  int row0 = by * 128, col0 = bx * 128;
  int lane = t & 63, wid = t >> 6;
  int wr = wid >> 1, wc = wid & 1;

  const bf16* AgP[4];
  const bf16* BgP[4];
  int ldo[4];
#pragma unroll
  for (int j = 0; j < 4; ++j) {
    int p = t + j * 256;
    int sub = p >> 9;
    int pp = p & 511;
    int rt = ((pp >> 6) << 4) | (pp & 15);
    int kb = (pp >> 4) & 3;
    AgP[j] = A + (size_t)(row0 + rt) * K + k0 + sub * 32 + kb * 8;
    BgP[j] = Bbase + (size_t)(col0 + rt) * K + k0 + sub * 32 + kb * 8;
    ldo[j] = sub * 4096 + pp * 8;
  }

  f32x4 acc[4][4];
#pragma unroll
  for (int m = 0; m < 4; ++m)
#pragma unroll
    for (int n = 0; n < 4; ++n) acc[m][n] = (f32x4){0.f, 0.f, 0.f, 0.f};

#pragma unroll
  for (int j = 0; j < 4; ++j) {
    gl_lds16(AgP[j], &Asb[0][ldo[j]]);
    gl_lds16(BgP[j], &Bsb[0][ldo[j]]);
  }

  const int nt = Kslice >> 6;
  for (int kt = 0; kt < nt; ++kt) {
    int cur = kt & 1;
    __syncthreads();
    if (kt + 1 < nt) {
      size_t go = (size_t)(kt + 1) * 64;
      int nb = cur ^ 1;
#pragma unroll
      for (int j = 0; j < 4; ++j) {
        gl_lds16(AgP[j] + go, &Asb[nb][ldo[j]]);
        gl_lds16(BgP[j] + go, &Bsb[nb][ldo[j]]);
      }
    }
#pragma unroll
    for (int kk = 0; kk < 2; ++kk) {
      bf16x8 af[4], bfr[4];
#pragma unroll
      for (int m = 0; m < 4; ++m)
        af[m] = *(const bf16x8*)&Asb[cur][kk * 4096 + ((wr * 4 + m) * 64 + lane) * 8];
#pragma unroll
      for (int n = 0; n < 4; ++n)
        bfr[n] = *(const bf16x8*)&Bsb[cur][kk * 4096 + ((wc * 4 + n) * 64 + lane) * 8];
#pragma unroll
      for (int m = 0; m < 4; ++m)
#pragma unroll
        for (int n = 0; n < 4; ++n)
          acc[m][n] = __builtin_amdgcn_mfma_f32_16x16x32_bf16(af[m], bfr[n], acc[m][n], 0, 0, 0);
    }
  }

  f16* Pz = P + (size_t)z * mn;
  int r0 = row0 + wr * 64, c0 = col0 + wc * 64;
#pragma unroll
  for (int m = 0; m < 4; ++m)
#pragma unroll
    for (int n = 0; n < 4; ++n) {
      int col = c0 + n * 16 + (lane & 15);
#pragma unroll
      for (int reg = 0; reg < 4; ++reg) {
        int row = r0 + m * 16 + ((lane >> 4) << 2) + reg;
        Pz[(size_t)row * N + col] = (f16)acc[m][n][reg];
      }
    }
}

// ---------------- combine: vT = sum_sk P + v_b (bf16 out, [b][hd][s]) -------
__global__ __launch_bounds__(256) void k_fin_vT(const f16* __restrict__ P,
                                                const float* __restrict__ bias,
                                                bf16* __restrict__ vT) {
  size_t i = ((size_t)blockIdx.x * 256 + threadIdx.x) * 4;
  const size_t mn = (size_t)1024 * 1024;
  float sx = 0.f, sy = 0.f, sz = 0.f, sw2 = 0.f;
#pragma unroll
  for (int sk = 0; sk < 4; ++sk) {
    f16x4 v = *(const f16x4*)&P[(size_t)sk * 2 * mn + i];
    sx += (float)v.x; sy += (float)v.y; sz += (float)v.z; sw2 += (float)v.w;
  }
  float bcol = bias[(i >> 10) & 1023];
  bf16x4 o;
  o.x = (bf16)(sx + bcol); o.y = (bf16)(sy + bcol);
  o.z = (bf16)(sz + bcol); o.w = (bf16)(sw2 + bcol);
  *(bf16x4*)&vT[i] = o;
}

// ---------------- fused fin+LayerNorm: u = sumP + bias + res; LN(u) ---------
template <int SK, bool OUTBF16>
__global__ __launch_bounds__(256) void k_fin_ln(
    const f16* __restrict__ P, const float* __restrict__ bias,
    const float* __restrict__ res, const float* __restrict__ g,
    const float* __restrict__ bb, float* __restrict__ outF,
    bf16* __restrict__ outB) {
  int row = blockIdx.x, t = threadIdx.x;
  size_t base = (size_t)row * E_ + t * 4;
  const size_t mn = (size_t)2048 * 1024;
  float u0 = 0.f, u1 = 0.f, u2 = 0.f, u3 = 0.f;
#pragma unroll
  for (int sk = 0; sk < SK; ++sk) {
    f16x4 v = *(const f16x4*)&P[(size_t)sk * mn + base];
    u0 += (float)v.x; u1 += (float)v.y; u2 += (float)v.z; u3 += (float)v.w;
  }
  float4 bv = *(const float4*)&bias[t * 4];
  float4 rv = *(const float4*)&res[base];
  u0 += bv.x + rv.x; u1 += bv.y + rv.y; u2 += bv.z + rv.z; u3 += bv.w + rv.w;
  float s = u0 + u1 + u2 + u3;
  float s2 = u0 * u0 + u1 * u1 + u2 * u2 + u3 * u3;
#pragma unroll
  for (int off = 32; off >= 1; off >>= 1) {
    s += __shfl_xor(s, off);
    s2 += __shfl_xor(s2, off);
  }
  __shared__ float rs[4], rs2[4];
  int wid = t >> 6;
  if ((t & 63) == 0) { rs[wid] = s; rs2[wid] = s2; }
  __syncthreads();
  float S1 = rs[0] + rs[1] + rs[2] + rs[3];
  float S2 = rs2[0] + rs2[1] + rs2[2] + rs2[3];
  float mu = S1 * (1.f / E_);
  float var = S2 * (1.f / E_) - mu * mu;
  float inv = rsqrtf(var + 1e-5f);
  float4 gv = *(const float4*)&g[t * 4];
  float4 bbv = *(const float4*)&bb[t * 4];
  float4 ov;
  ov.x = (u0 - mu) * inv * gv.x + bbv.x;
  ov.y = (u1 - mu) * inv * gv.y + bbv.y;
  ov.z = (u2 - mu) * inv * gv.z + bbv.z;
  ov.w = (u3 - mu) * inv * gv.w + bbv.w;
  *(float4*)&outF[base] = ov;
  if (OUTBF16) {
    bf16x4 obv;
    obv.x = (bf16)ov.x; obv.y = (bf16)ov.y; obv.z = (bf16)ov.z; obv.w = (bf16)ov.w;
    *(bf16x4*)&outB[base] = obv;
  }
}

// ---------------- MFMA flash attention (cont-based scores) ------------------
__global__ __launch_bounds__(256) void k_attn2(
    const float* __restrict__ qsT, const float* __restrict__ kmT,
    const bf16* __restrict__ cont, const float* __restrict__ swin,
    const bf16* __restrict__ vT,
    bf16* __restrict__ o, bf16* __restrict__ opart, float* __restrict__ mlpart) {
  int q = blockIdx.x & 3;
  int iwg = blockIdx.x >> 2;       // 0..15
  if (q > iwg) return;             // ntile = iwg+1; quarter q needs q < ntile
  int bh = blockIdx.y;
  int b = bh >> 3, h = bh & 7;
  int t = threadIdx.x;
  int wid = t >> 6, lane = t & 63;
  int iw = iwg * 4 + wid;          // 0..63
  int m = lane & 15, ko = lane >> 4;
  int ntile = iwg + 1;

  __shared__ float sw[S_];
  *(float4*)&sw[t * 4] = *(const float4*)&swin[(size_t)bh * S_ + t * 4];
  __syncthreads();

  int i_row = iw * 16 + m;
  float qs_i = qsT[(size_t)bh * S_ + i_row];
  const bf16* cr = cont + ((size_t)bh << 20) + (size_t)i_row * S_;

  f32x4 acc[8];
#pragma unroll
  for (int nf = 0; nf < 8; ++nf) acc[nf] = (f32x4){0.f, 0.f, 0.f, 0.f};
  float m_run = -INFINITY, l_run = 0.f;

  for (int jt = q; jt < ntile; jt += 4) {
    int j0 = jt * 64;
    float pv[2][8];
    float mx = -INFINITY;
    bf16x8 cv[2];
    cv[0] = *(const bf16x8*)&cr[j0 + ko * 8];
    cv[1] = *(const bf16x8*)&cr[j0 + 32 + ko * 8];
#pragma unroll
    for (int s = 0; s < 2; ++s) {
      int bj = j0 + s * 32 + ko * 8;
      float4 km0 = *(const float4*)&kmT[(size_t)bh * S_ + bj];
      float4 km1 = *(const float4*)&kmT[(size_t)bh * S_ + bj + 4];
      float kmv[8] = {km0.x, km0.y, km0.z, km0.w, km1.x, km1.y, km1.z, km1.w};
#pragma unroll
      for (int e = 0; e < 8; ++e) {
        int j = bj + e;
        int dd = i_row - j;
        float val = sw[dd >= 0 ? dd : 0] + qs_i + kmv[e] + 0.25f * (float)cv[s][e];
        val = (dd >= 0) ? val : -INFINITY;   // cndmask, branch-free
        pv[s][e] = val;
        mx = fmaxf(mx, val);
      }
    }
    mx = fmaxf(mx, __shfl_xor(mx, 16));
    mx = fmaxf(mx, __shfl_xor(mx, 32));
    float mnew = fmaxf(m_run, mx);
    float scale = __expf(m_run - mnew);
    float lsum = 0.f;
    bf16x8 pa[2];
#pragma unroll
    for (int s = 0; s < 2; ++s)
#pragma unroll
      for (int e = 0; e < 8; ++e) {
        float p = __expf(pv[s][e] - mnew);
        lsum += p;
        pa[s][e] = (bf16)p;
      }
    lsum += __shfl_xor(lsum, 16);
    lsum += __shfl_xor(lsum, 32);
    l_run = l_run * scale + lsum;
    m_run = mnew;
    float sc[4];
#pragma unroll
    for (int r = 0; r < 4; ++r) sc[r] = __shfl(scale, ko * 4 + r);
#pragma unroll
    for (int nf = 0; nf < 8; ++nf)
#pragma unroll
      for (int r = 0; r < 4; ++r) acc[nf][r] *= sc[r];
#pragma unroll
    for (int s = 0; s < 2; ++s) {
      int bj = j0 + s * 32 + ko * 8;
#pragma unroll
      for (int nf = 0; nf < 8; ++nf) {
        int d = nf * 16 + m;
        bf16x8 bv = *(const bf16x8*)&vT[((size_t)bh * HD_ + d) * S_ + bj];
        acc[nf] = __builtin_amdgcn_mfma_f32_16x16x32_bf16(pa[s], bv, acc[nf], 0, 0, 0);
      }
    }
  }

  if (ntile == 1) {                // iw<4 (only q==0): finalize directly
    float lr[4];
#pragma unroll
    for (int r = 0; r < 4; ++r) lr[r] = __shfl(l_run, ko * 4 + r);
#pragma unroll
    for (int nf = 0; nf < 8; ++nf) {
      int d = nf * 16 + m;
#pragma unroll
      for (int r = 0; r < 4; ++r) {
        int row = iw * 16 + ko * 4 + r;
        o[(((size_t)b * S_ + row) * H_ + h) * HD_ + d] = (bf16)(acc[nf][r] / lr[r]);
      }
    }
  } else {
    bf16* op = opart + ((size_t)(q * 16 + bh) * 64 + iw) * 2048;
#pragma unroll
    for (int nf = 0; nf < 8; ++nf) {
      int d = nf * 16 + m;
#pragma unroll
      for (int r = 0; r < 4; ++r) op[(ko * 4 + r) * 128 + d] = (bf16)acc[nf][r];
    }
    if (lane < 16) {
      float* mlp = mlpart + ((size_t)(q * 16 + bh) * 64 + iw) * 32;
      mlp[m * 2 + 0] = m_run;
      mlp[m * 2 + 1] = l_run;
    }
  }
}

// ---------------- combine up to 4 attention quarters (rows iw>=4) -----------
__global__ __launch_bounds__(256) void k_comb(const bf16* __restrict__ opart,
                                              const float* __restrict__ mlpart,
                                              bf16* __restrict__ o) {
  int blk = blockIdx.x;
  int bh = blk / 60, iw = blk % 60 + 4;
  int b = bh >> 3, h = bh & 7;
  int t = threadIdx.x;
  int r = t >> 4, d0 = (t & 15) * 8;
  int nq = iw / 4 + 1;
  if (nq > 4) nq = 4;
  float mq[4], lq[4];
  float mm = -INFINITY;
#pragma unroll
  for (int q = 0; q < 4; ++q) {
    if (q < nq) {
      size_t idx = (size_t)(q * 16 + bh) * 64 + iw;
      mq[q] = mlpart[idx * 32 + r * 2];
      lq[q] = mlpart[idx * 32 + r * 2 + 1];
      mm = fmaxf(mm, mq[q]);
    }
  }
  float L = 0.f;
  float acc[8] = {0.f, 0.f, 0.f, 0.f, 0.f, 0.f, 0.f, 0.f};
#pragma unroll
  for (int q = 0; q < 4; ++q) {
    if (q < nq) {
      float e = __expf(mq[q] - mm);
      L += lq[q] * e;
      size_t idx = (size_t)(q * 16 + bh) * 64 + iw;
      bf16x8 v = *(const bf16x8*)&opart[(idx * 16 + r) * 128 + d0];
#pragma unroll
      for (int k = 0; k < 8; ++k) acc[k] += (float)v[k] * e;
    }
  }
  float inv = 1.f / L;
  bf16x8 ov;
#pragma unroll
  for (int k = 0; k < 8; ++k) ov[k] = (bf16)(acc[k] * inv);
  int row = iw * 16 + r;
  *(bf16x8*)&o[(((size_t)b * S_ + row) * H_ + h) * HD_ + d0] = ov;
}

}  // namespace

extern "C" void kernel_launch(void* const* d_in, const int* in_sizes, int n_in,
                              void* d_out, int out_size, void* d_ws, size_t ws_size,
                              hipStream_t stream) {
  (void)in_sizes; (void)n_in; (void)out_size; (void)ws_size;
  const float* x       = (const float*)d_in[0];
  const float* v_w     = (const float*)d_in[1];
  const float* v_b     = (const float*)d_in[2];
  const float* out_w   = (const float*)d_in[3];
  const float* out_b   = (const float*)d_in[4];
  const float* qmod_w  = (const float*)d_in[5];
  const float* qmod_b  = (const float*)d_in[6];
  const float* kmod_w  = (const float*)d_in[7];
  const float* kmod_b  = (const float*)d_in[8];
  const float* gate_w1 = (const float*)d_in[9];
  const float* gate_b1 = (const float*)d_in[10];
  const float* gate_w2 = (const float*)d_in[11];
  const float* gate_b2 = (const float*)d_in[12];
  const float* mod_w1  = (const float*)d_in[13];
  const float* mod_b1  = (const float*)d_in[14];
  const float* mod_w2  = (const float*)d_in[15];
  const float* mod_b2  = (const float*)d_in[16];
  const float* mod_basis = (const float*)d_in[17];
  const float* freqs   = (const float*)d_in[18];
  const float* amps    = (const float*)d_in[19];
  const float* phases  = (const float*)d_in[20];
  const float* cwq     = (const float*)d_in[21];
  const float* cwk     = (const float*)d_in[22];
  const float* ffn_w1  = (const float*)d_in[23];
  const float* ffn_b1  = (const float*)d_in[24];
  const float* ffn_w2  = (const float*)d_in[25];
  const float* ffn_b2  = (const float*)d_in[26];
  const float* ln_ag   = (const float*)d_in[27];
  const float* ln_ab   = (const float*)d_in[28];
  const float* ln_fg   = (const float*)d_in[29];
  const float* ln_fb   = (const float*)d_in[30];

  char* wsc = (char*)d_ws;
  size_t off = 0;
  auto alloc = [&](size_t bytes) -> void* {
    void* p = wsc + off;
    off += (bytes + 255) & ~(size_t)255;
    return p;
  };
  float* pooled = (float*)alloc(2048 * 4);
  float* part   = (float*)alloc(65536 * 4);
  float2* gpart = (float2*)alloc((size_t)2 * H_ * 16 * 128 * 8);
  float* wmod   = (float*)alloc(2048 * 4);
  float* kerns  = (float*)alloc((size_t)H_ * M_ * S_ * 4);
  float* swin   = (float*)alloc((size_t)B_ * H_ * S_ * 4);
  float* qsT    = (float*)alloc((size_t)B_ * H_ * S_ * 4);
  float* kmT    = (float*)alloc((size_t)B_ * H_ * S_ * 4);
  float* qcb    = (float*)alloc((size_t)B_ * H_ * S_ * R_ * 4);
  float* kcb    = (float*)alloc((size_t)B_ * H_ * S_ * R_ * 4);
  float* ybuf   = (float*)alloc((size_t)B_ * S_ * E_ * 4);       // 8MB (post-LN y)
  bf16* xb      = (bf16*)alloc((size_t)B_ * S_ * E_ * 2);
  bf16* yb      = (bf16*)alloc((size_t)B_ * S_ * E_ * 2);
  bf16* vwT     = (bf16*)alloc((size_t)E_ * E_ * 2);
  bf16* outwT   = (bf16*)alloc((size_t)E_ * E_ * 2);
  bf16* ffn1T   = (bf16*)alloc((size_t)E_ * FFNH_ * 2);
  bf16* ffn2T   = (bf16*)alloc((size_t)FFNH_ * E_ * 2);
  bf16* wcatT   = (bf16*)alloc((size_t)256 * E_ * 2);            // 0.5MB
  bf16* vT      = (bf16*)alloc((size_t)B_ * S_ * E_ * 2);        // v [b,hd,s]
  bf16* ob      = (bf16*)alloc((size_t)B_ * S_ * E_ * 2);        // attn out
  float* mlpart = (float*)alloc((size_t)4 * 16 * 64 * 16 * 2 * 4);
  char* poolU2  = (char*)alloc((size_t)B_ * S_ * FFNH_ * 2);     // 16MB union
  bf16* opart = (bf16*)poolU2;     // 16MB (attn phase)
  bf16* hb    = (bf16*)poolU2;     // 16MB (FFN phase)
  // P1: 64MB union. fp16 partials: qk [0,8MB); v [0,16MB); out [0,16MB);
  // ffn2 [0,16MB). cont (32MB bf16) at [16MB,48MB) until attn2 completes.
  char* P1c = (char*)alloc((size_t)64 * 1024 * 1024);
  f16*  P1  = (f16*)P1c;
  bf16* cont = (bf16*)(P1c + (size_t)16 * 1024 * 1024);

  float* outp = (float*)d_out;
  const int BS = B_ * S_;

  // prep
  k_cvt_bf16<<<(BS * E_) / 1024, 256, 0, stream>>>(x, xb);
  k_wt<<<dim3(E_ / 32, E_ / 32), 256, 0, stream>>>(v_w, vwT, E_, E_);
  k_wt<<<dim3(E_ / 32, E_ / 32), 256, 0, stream>>>(out_w, outwT, E_, E_);
  k_wt<<<dim3(FFNH_ / 32, E_ / 32), 256, 0, stream>>>(ffn_w1, ffn1T, E_, FFNH_);
  k_wt<<<dim3(E_ / 32, FFNH_ / 32), 256, 0, stream>>>(ffn_w2, ffn2T, FFNH_, E_);
  k_wcat<<<(256 * E_) / 256, 256, 0, stream>>>(qmod_w, kmod_w, cwq, cwk, wcatT);

  // scores pipeline
  k_pool_partial<<<B_ * SCH, 256, 0, stream>>>(x, part);
  k_pool_reduce<<<B_, 256, 0, stream>>>(part, pooled);
  k_gate1<<<dim3(16, H_, 2), 256, 0, stream>>>(pooled, gate_w1, mod_w1, gpart);
  k_gate2<<<B_ * H_, 256, 0, stream>>>(gpart, gate_b1, gate_w2, gate_b2,
                                       mod_b1, mod_w2, mod_b2, mod_basis, wmod);
  k_waves<<<H_ * M_ * (S_ / 256), 256, 0, stream>>>(freqs, amps, phases, kerns);
  k_swin<<<B_ * H_ * (S_ / 256), 256, 0, stream>>>(wmod, kerns, swin);

  // qs/km/qc/kc via one MFMA GEMM: [xb (2048x1024)] @ WcatT^T -> 2048x256
  k_gemm_sk<1><<<dim3(2, 16, 8), 256, 0, stream>>>(
      xb, wcatT, P1, 256, E_, 128, 0, (size_t)2048 * 256);
  k_fin_qk<<<2048, 256, 0, stream>>>(P1, qmod_b, kmod_b, qsT, kmT, qcb, kcb);

  // content logits precompute (lower-tri 128-tiles), bf16
  k_cont<<<dim3(8, 8, 16), 256, 0, stream>>>(qcb, kcb, cont);

  // vT[b][hd][s] = vwT x xb^T, split-K=4 x batch2, fp16 partials
  k_gemm_sk<2><<<dim3(8, 8, 8), 256, 0, stream>>>(
      vwT, xb, P1, S_, E_, 256, (size_t)S_ * E_, (size_t)1024 * 1024);
  k_fin_vT<<<2048, 256, 0, stream>>>(P1, v_b, vT);

  k_attn2<<<dim3(64, 16), 256, 0, stream>>>(qsT, kmT, cont, swin, vT, ob, opart, mlpart);
  k_comb<<<16 * 60, 256, 0, stream>>>(opart, mlpart, ob);

  // y = LN(o @ out_w + out_b + x)  (split-K=4, fused fin+LN -> ybuf fp32 + yb bf16)
  k_gemm_sk<1><<<dim3(8, 16, 4), 256, 0, stream>>>(
      ob, outwT, P1, E_, E_, 256, 0, (size_t)2048 * 1024);
  k_fin_ln<4, true><<<2048, 256, 0, stream>>>(P1, out_b, x, ln_ag, ln_ab, ybuf, yb);

  // h = gelu(y @ ffn_w1 + b1)  (fused epilogue, no partial round-trip)
  k_gemm_mfma<true, false, false, true><<<dim3(FFNH_ / 128, BS / 128), 256, 0, stream>>>(
      yb, ffn1T, ffn_b1, nullptr, nullptr, hb, FFNH_, E_);

  // out = LN(h @ ffn_w2 + b2 + y)  (split-K=4, fused fin+LN -> outp)
  k_gemm_sk<1><<<dim3(8, 16, 4), 256, 0, stream>>>(
      hb, ffn2T, P1, E_, FFNH_, 1024, 0, (size_t)2048 * 1024);
  k_fin_ln<4, false><<<2048, 256, 0, stream>>>(P1, ffn_b2, ybuf, ln_fg, ln_fb, outp, nullptr);
}

// Round 16
// 256.975 us; speedup vs baseline: 1.3369x; 1.0551x over previous
//
#include <hip/hip_runtime.h>
#include <math.h>
#include <stdint.h>

namespace {

constexpr int B_ = 2, S_ = 1024, E_ = 1024, H_ = 8, HD_ = 128;
constexpr int M_ = 128, W_ = 32, GH_ = 128, R_ = 8, MR_ = 8, FFNH_ = 4096;
constexpr int SCH = 32;            // s-chunks for pooling
constexpr int SPC = S_ / SCH;      // 32 rows per chunk

typedef __bf16 bf16;
typedef _Float16 f16;
typedef __attribute__((ext_vector_type(8))) __bf16 bf16x8;
typedef __attribute__((ext_vector_type(4))) __bf16 bf16x4;
typedef __attribute__((ext_vector_type(4))) _Float16 f16x4;
typedef __attribute__((ext_vector_type(4))) float f32x4;

__device__ inline float gelu_tanh(float u) {
  float u3 = u * u * u;
  return 0.5f * u * (1.f + tanhf(0.7978845608028654f * (u + 0.044715f * u3)));
}

__device__ __forceinline__ void gl_lds16(const void* g, void* l) {
  __builtin_amdgcn_global_load_lds((const __attribute__((address_space(1))) void*)g,
                                   (__attribute__((address_space(3))) void*)l, 16, 0, 0);
}

// ---------------- fused prep: cvt + 4x weight transpose + wcat --------------
// blocks [0,2048): x->xb bf16; [2048,3072): v_w^T; [3072,4096): out_w^T;
// [4096,8192): ffn_w1^T; [8192,12288): ffn_w2^T; [12288,13312): wcat.
// Each block's branch is uniform -> __syncthreads inside branches is safe.
__global__ __launch_bounds__(256) void k_prep(
    const float* __restrict__ x, bf16* __restrict__ xb,
    const float* __restrict__ v_w, bf16* __restrict__ vwT,
    const float* __restrict__ out_w, bf16* __restrict__ outwT,
    const float* __restrict__ ffn_w1, bf16* __restrict__ ffn1T,
    const float* __restrict__ ffn_w2, bf16* __restrict__ ffn2T,
    const float* __restrict__ qmw, const float* __restrict__ kmw,
    const float* __restrict__ cwq, const float* __restrict__ cwk,
    bf16* __restrict__ wcat) {
  __shared__ float tile[32][33];
  int b = blockIdx.x, t = threadIdx.x;
  if (b < 2048) {                  // fp32 -> bf16 elementwise (x)
    size_t i = ((size_t)b * 256 + t) * 4;
    float4 v = *(const float4*)(x + i);
    bf16x4 o;
    o.x = (bf16)v.x; o.y = (bf16)v.y; o.z = (bf16)v.z; o.w = (bf16)v.w;
    *(bf16x4*)(xb + i) = o;
    return;
  }
  if (b < 12288) {                 // weight (K,N) fp32 -> (N,K) bf16 transpose
    const float* w; bf16* wT; int K, N, bx, by;
    if (b < 3072) {
      w = v_w; wT = vwT; K = 1024; N = 1024;
      int l = b - 2048; bx = l & 31; by = l >> 5;
    } else if (b < 4096) {
      w = out_w; wT = outwT; K = 1024; N = 1024;
      int l = b - 3072; bx = l & 31; by = l >> 5;
    } else if (b < 8192) {
      w = ffn_w1; wT = ffn1T; K = 1024; N = 4096;
      int l = b - 4096; bx = l & 127; by = l >> 7;
    } else {
      w = ffn_w2; wT = ffn2T; K = 4096; N = 1024;
      int l = b - 8192; bx = l & 31; by = l >> 5;
    }
    int n0 = bx * 32, k0 = by * 32;
    int tx = t & 31, ty = t >> 5;
    for (int r = ty; r < 32; r += 8) tile[r][tx] = w[(size_t)(k0 + r) * N + n0 + tx];
    __syncthreads();
    for (int r = ty; r < 32; r += 8) wT[(size_t)(n0 + r) * K + k0 + tx] = (bf16)tile[tx][r];
    return;
  }
  // Wcat^T (256 x 1024): [qmod|kmod|diag(cwq)|diag(cwk)]
  int idx = (b - 12288) * 256 + t;
  int n = idx >> 10, k = idx & 1023;
  float v = 0.f;
  if (n < 8) {
    v = qmw[k * 8 + n];
  } else if (n < 16) {
    v = kmw[k * 8 + (n - 8)];
  } else if (n < 80) {
    int u = n - 16, h = u >> 3, r = u & 7;
    int kk = k - h * 128;
    if (kk >= 0 && kk < 128) v = cwq[((size_t)h * 128 + kk) * 8 + r];
  } else if (n < 144) {
    int u = n - 80, h = u >> 3, r = u & 7;
    int kk = k - h * 128;
    if (kk >= 0 && kk < 128) v = cwk[((size_t)h * 128 + kk) * 8 + r];
  }
  wcat[idx] = (bf16)v;
}

// ---------------- fused pool_partial + waves (independent work) -------------
// blocks [0,64): pooled partials; [64, 64+4096): wave kernel synthesis.
__global__ __launch_bounds__(256) void k_pw(
    const float* __restrict__ x, float* __restrict__ part,
    const float* __restrict__ freqs, const float* __restrict__ amps,
    const float* __restrict__ phases, float* __restrict__ kerns) {
  __shared__ float f0[W_], f1[W_], am[W_], ph[W_];
  int b0 = blockIdx.x, t = threadIdx.x;
  if (b0 < 64) {                   // pool_partial
    int b = b0 / SCH, c = b0 % SCH;
    const float* xp = x + (size_t)b * S_ * E_ + (size_t)c * SPC * E_;
    float acc[4] = {0.f, 0.f, 0.f, 0.f};
    for (int s = 0; s < SPC; ++s) {
      const float* row = xp + (size_t)s * E_;
#pragma unroll
      for (int q = 0; q < 4; ++q) acc[q] += row[t + q * 256];
    }
    float* pp = part + (size_t)b0 * E_;
#pragma unroll
    for (int q = 0; q < 4; ++q) pp[t + q * 256] = acc[q];
    return;
  }
  int blk = b0 - 64;               // waves
  int lt = blk & 3;
  int hm = blk >> 2;
  if (t < W_) {
    f0[t] = freqs[((size_t)hm * W_ + t) * 2 + 0];
    f1[t] = freqs[((size_t)hm * W_ + t) * 2 + 1];
    am[t] = amps[(size_t)hm * W_ + t];
    ph[t] = phases[(size_t)hm * W_ + t];
  }
  __syncthreads();
  int l = lt * 256 + t;
  float rel = (float)(l - (S_ - 1));
  float p1 = rel * (1.0f / S_);
  float p2 = (rel < 0.f) ? (-sqrtf(-rel + 1e-6f) * (1.0f / 32.0f)) : 0.f;
  const float TWO_PI = 6.28318530717958647692f;
  float acc = 0.f;
#pragma unroll
  for (int w = 0; w < W_; ++w)
    acc += am[w] * __sinf(TWO_PI * (f0[w] * p1 + f1[w] * p2) + ph[w]);
  kerns[(size_t)hm * S_ + l] = acc;
}

// ---------------- finish qk GEMM: sum fp16 partials, scatter -----------------
__global__ __launch_bounds__(256) void k_fin_qk(
    const f16* __restrict__ P, const float* __restrict__ qmb,
    const float* __restrict__ kmb, float* __restrict__ qsT,
    float* __restrict__ kmT, float* __restrict__ qc, float* __restrict__ kc) {
  int row = blockIdx.x;            // 0..2047
  int t = threadIdx.x;
  if (t >= 144) return;
  int b = row >> 10, s = row & 1023;
  const size_t mn = (size_t)2048 * 256;
  float sum = 0.f;
#pragma unroll
  for (int z = 0; z < 8; ++z) sum += (float)P[(size_t)z * mn + (size_t)row * 256 + t];
  if (t < 8) {
    qsT[((size_t)(b * 8 + t)) * 1024 + s] = sum + qmb[t];
  } else if (t < 16) {
    kmT[((size_t)(b * 8 + t - 8)) * 1024 + s] = sum + kmb[t - 8];
  } else if (t < 80) {
    int u = t - 16, h = u >> 3, r = u & 7;
    qc[(((size_t)(b * 8 + h)) * 1024 + s) * 8 + r] = sum;
  } else {
    int u = t - 80, h = u >> 3, r = u & 7;
    kc[(((size_t)(b * 8 + h)) * 1024 + s) * 8 + r] = sum;
  }
}

__global__ __launch_bounds__(256) void k_pool_reduce(const float* __restrict__ part,
                                                     float* __restrict__ pooled) {
  int b = blockIdx.x;
  int t = threadIdx.x;
#pragma unroll
  for (int q = 0; q < 4; ++q) {
    int e = t + q * 256;
    float s = 0.f;
    for (int c = 0; c < SCH; ++c) s += part[(size_t)(b * SCH + c) * E_ + e];
    pooled[b * E_ + e] = s * (1.0f / S_);
  }
}

// ---------------- gate first layer: coalesced split-E partials --------------
__global__ __launch_bounds__(256) void k_gate1(
    const float* __restrict__ pooled,
    const float* __restrict__ gw1, const float* __restrict__ mw1,
    float2* __restrict__ part) {
  int chunk = blockIdx.x;          // 0..15
  int h = blockIdx.y;              // 0..7
  int mat = blockIdx.z;            // 0: gate, 1: mod
  const float* w = mat ? mw1 : gw1;
  int t = threadIdx.x;
  int g = t & 127, half = t >> 7;
  int e0 = chunk * 64 + half * 32;
  const float* wp = w + (size_t)h * E_ * GH_ + (size_t)e0 * GH_ + g;
  const float* p0 = pooled + e0;
  const float* p1 = pooled + E_ + e0;
  float a0 = 0.f, a1 = 0.f;
#pragma unroll 8
  for (int r = 0; r < 32; ++r) {
    float wv = wp[(size_t)r * GH_];
    a0 += p0[r] * wv;
    a1 += p1[r] * wv;
  }
  __shared__ float red[2][2][128];
  red[half][0][g] = a0;
  red[half][1][g] = a1;
  __syncthreads();
  if (half == 0) {
    float2 o;
    o.x = red[0][0][g] + red[1][0][g];
    o.y = red[0][1][g] + red[1][1][g];
    part[(((size_t)mat * H_ + h) * 16 + chunk) * 128 + g] = o;
  }
}

// ---------------- gate finish ------------------------------------------------
__global__ __launch_bounds__(256) void k_gate2(
    const float2* __restrict__ part,
    const float* __restrict__ gb1, const float* __restrict__ gw2, const float* __restrict__ gb2,
    const float* __restrict__ mb1, const float* __restrict__ mw2, const float* __restrict__ mb2,
    const float* __restrict__ mbasis, float* __restrict__ wmod) {
  int bh = blockIdx.x;
  int b = bh >> 3, h = bh & 7;
  int t = threadIdx.x;
  __shared__ float ghs[GH_], mhs[GH_], glog[M_], mrs[MR_];
  __shared__ float red2[2][128];
  __shared__ float rbuf[128];
  {
    int g = t & 127, mat = t >> 7;
    const float2* pp = part + ((size_t)mat * H_ + h) * 16 * 128 + g;
    float acc = 0.f;
#pragma unroll
    for (int c = 0; c < 16; ++c) {
      float2 v = pp[(size_t)c * 128];
      acc += b ? v.y : v.x;
    }
    acc += (mat ? mb1 : gb1)[h * GH_ + g];
    acc = fmaxf(acc, 0.f);
    if (mat == 0) ghs[g] = acc; else mhs[g] = acc;
  }
  __syncthreads();
  {
    int m = t & 127, half = t >> 7;
    float acc = 0.f;
    const float* wp = gw2 + (size_t)h * GH_ * M_ + m;
#pragma unroll 4
    for (int g = half * 64; g < half * 64 + 64; ++g)
      acc += ghs[g] * wp[(size_t)g * M_];
    red2[half][m] = acc;
  }
  __syncthreads();
  if (t < 128) glog[t] = red2[0][t] + red2[1][t] + gb2[h * M_ + t];
  if (t < 64) {
    int r = t & 7, seg = t >> 3;
    float acc = 0.f;
    const float* wp = mw2 + (size_t)h * GH_ * MR_ + r;
    for (int g = seg * 16; g < seg * 16 + 16; ++g) acc += mhs[g] * wp[(size_t)g * MR_];
    acc += __shfl_xor(acc, 8);
    acc += __shfl_xor(acc, 16);
    acc += __shfl_xor(acc, 32);
    if (t < 8) mrs[t] = acc + mb2[h * MR_ + t];
  }
  __syncthreads();
  if (t < 128) rbuf[t] = glog[t];
  __syncthreads();
  for (int off = 64; off >= 1; off >>= 1) {
    if (t < off) rbuf[t] = fmaxf(rbuf[t], rbuf[t + off]);
    __syncthreads();
  }
  float mx = rbuf[0];
  __syncthreads();
  float ev = 0.f;
  if (t < 128) ev = expf(glog[t] - mx);
  __syncthreads();
  if (t < 128) rbuf[t] = ev;
  __syncthreads();
  for (int off = 64; off >= 1; off >>= 1) {
    if (t < off) rbuf[t] += rbuf[t + off];
    __syncthreads();
  }
  float inv = 1.f / rbuf[0];
  if (t < 128) {
    float wsel = ev * inv;
    float md = 0.f;
#pragma unroll
    for (int r = 0; r < MR_; ++r) md += mrs[r] * mbasis[((size_t)h * MR_ + r) * M_ + t];
    wmod[bh * M_ + t] = wsel * (1.f + md);
  }
}

// ---------------- swin ------------------------------------------------------
__global__ __launch_bounds__(256) void k_swin(const float* __restrict__ wmod,
                                              const float* __restrict__ kerns,
                                              float* __restrict__ swin) {
  int blk = blockIdx.x;
  int dt = blk & 3;
  int bh = blk >> 2;
  int h = bh & 7;
  int t = threadIdx.x;
  __shared__ float wm[M_];
  if (t < M_) wm[t] = wmod[bh * M_ + t];
  __syncthreads();
  int d = dt * 256 + t;
  int l = (S_ - 1) - d;
  float acc = 0.f;
  for (int m = 0; m < M_; ++m) acc += wm[m] * kerns[((size_t)h * M_ + m) * S_ + l];
  float dd = (float)d;
  float win = expf(-dd * dd * (1.0f / 131072.0f));
  swin[(size_t)bh * S_ + d] = 3.0f * win * acc;
}

// ---------------- cont[bh][i][j] = qc_i . kc_j  (bf16, lower-tri 128-tiles) -
__global__ __launch_bounds__(256) void k_cont(const float* __restrict__ qc,
                                              const float* __restrict__ kc,
                                              bf16* __restrict__ cont) {
  int jt = blockIdx.x, it = blockIdx.y;
  if (jt > it) return;
  int bh = blockIdx.z;
  int t = threadIdx.x;
  int w = t >> 6, lane = t & 63;
  int ln = lane & 15, ko = lane >> 4;
  int i0 = it * 128 + w * 32;
  int j0 = jt * 128;

  bf16x8 av[2];
#pragma unroll
  for (int mi = 0; mi < 2; ++mi) {
    bf16x8 a;
#pragma unroll
    for (int k = 0; k < 8; ++k) a[k] = (bf16)0.f;
    if (ko == 0) {
      const float* qp = &qc[((size_t)bh * S_ + i0 + mi * 16 + ln) * 8];
      float4 q0 = *(const float4*)qp;
      float4 q1 = *(const float4*)(qp + 4);
      a[0] = (bf16)q0.x; a[1] = (bf16)q0.y; a[2] = (bf16)q0.z; a[3] = (bf16)q0.w;
      a[4] = (bf16)q1.x; a[5] = (bf16)q1.y; a[6] = (bf16)q1.z; a[7] = (bf16)q1.w;
    }
    av[mi] = a;
  }
  bf16x8 bv[8];
#pragma unroll
  for (int nb = 0; nb < 8; ++nb) {
    bf16x8 bb;
#pragma unroll
    for (int k = 0; k < 8; ++k) bb[k] = (bf16)0.f;
    if (ko == 0) {
      const float* kp = &kc[((size_t)bh * S_ + j0 + nb * 16 + ln) * 8];
      float4 k0 = *(const float4*)kp;
      float4 k1 = *(const float4*)(kp + 4);
      bb[0] = (bf16)k0.x; bb[1] = (bf16)k0.y; bb[2] = (bf16)k0.z; bb[3] = (bf16)k0.w;
      bb[4] = (bf16)k1.x; bb[5] = (bf16)k1.y; bb[6] = (bf16)k1.z; bb[7] = (bf16)k1.w;
    }
    bv[nb] = bb;
  }
  f32x4 acc[2][8];
#pragma unroll
  for (int mi = 0; mi < 2; ++mi)
#pragma unroll
    for (int nb = 0; nb < 8; ++nb) {
      acc[mi][nb] = (f32x4){0.f, 0.f, 0.f, 0.f};
      acc[mi][nb] = __builtin_amdgcn_mfma_f32_16x16x32_bf16(av[mi], bv[nb], acc[mi][nb], 0, 0, 0);
    }
  bf16* cb = cont + ((size_t)bh << 20);
#pragma unroll
  for (int mi = 0; mi < 2; ++mi)
#pragma unroll
    for (int nb = 0; nb < 8; ++nb) {
      int col = j0 + nb * 16 + ln;
#pragma unroll
      for (int reg = 0; reg < 4; ++reg) {
        int row = i0 + mi * 16 + ko * 4 + reg;
        cb[(size_t)row * S_ + col] = (bf16)acc[mi][nb][reg];
      }
    }
}

// ---------------- bf16 MFMA GEMM, BK=64, fused epilogue (FFN1), swizzled ----
template <bool GELU, bool RES, bool OUTF32, bool OUTBF16>
__global__ __launch_bounds__(256) void k_gemm_mfma(
    const bf16* __restrict__ A, const bf16* __restrict__ BT,
    const float* __restrict__ bias, const float* __restrict__ res,
    float* __restrict__ C, bf16* __restrict__ Cb, int N, int K) {
  __shared__ bf16 Asb[2][8192];
  __shared__ bf16 Bsb[2][8192];
  int t = threadIdx.x;
  // XCD-aware bijective remap, row-tile fastest (L2 locality)
  int gx = gridDim.x, gy = gridDim.y;
  int nwg = gx * gy;
  int lin = blockIdx.y * gx + blockIdx.x;
  if (!(nwg & 7)) {
    int cpx = nwg >> 3;
    lin = (lin & 7) * cpx + (lin >> 3);
  }
  int by = lin % gy;
  int bx = lin / gy;
  int row0 = by * 128, col0 = bx * 128;
  int lane = t & 63, wid = t >> 6;
  int wr = wid >> 1, wc = wid & 1;

  const bf16* AgP[4];
  const bf16* BgP[4];
  int ldo[4];
#pragma unroll
  for (int j = 0; j < 4; ++j) {
    int p = t + j * 256;           // 0..1023
    int sub = p >> 9;
    int pp = p & 511;
    int rt = ((pp >> 6) << 4) | (pp & 15);
    int kb = (pp >> 4) & 3;
    AgP[j] = A + (size_t)(row0 + rt) * K + sub * 32 + kb * 8;
    BgP[j] = BT + (size_t)(col0 + rt) * K + sub * 32 + kb * 8;
    ldo[j] = sub * 4096 + pp * 8;
  }

  f32x4 acc[4][4];
#pragma unroll
  for (int m = 0; m < 4; ++m)
#pragma unroll
    for (int n = 0; n < 4; ++n) acc[m][n] = (f32x4){0.f, 0.f, 0.f, 0.f};

#pragma unroll
  for (int j = 0; j < 4; ++j) {
    gl_lds16(AgP[j], &Asb[0][ldo[j]]);
    gl_lds16(BgP[j], &Bsb[0][ldo[j]]);
  }

  const int nt = K >> 6;
  for (int kt = 0; kt < nt; ++kt) {
    int cur = kt & 1;
    __syncthreads();
    if (kt + 1 < nt) {
      size_t go = (size_t)(kt + 1) * 64;
      int nb = cur ^ 1;
#pragma unroll
      for (int j = 0; j < 4; ++j) {
        gl_lds16(AgP[j] + go, &Asb[nb][ldo[j]]);
        gl_lds16(BgP[j] + go, &Bsb[nb][ldo[j]]);
      }
    }
#pragma unroll
    for (int kk = 0; kk < 2; ++kk) {
      bf16x8 af[4], bfr[4];
#pragma unroll
      for (int m = 0; m < 4; ++m)
        af[m] = *(const bf16x8*)&Asb[cur][kk * 4096 + ((wr * 4 + m) * 64 + lane) * 8];
#pragma unroll
      for (int n = 0; n < 4; ++n)
        bfr[n] = *(const bf16x8*)&Bsb[cur][kk * 4096 + ((wc * 4 + n) * 64 + lane) * 8];
#pragma unroll
      for (int m = 0; m < 4; ++m)
#pragma unroll
        for (int n = 0; n < 4; ++n)
          acc[m][n] = __builtin_amdgcn_mfma_f32_16x16x32_bf16(af[m], bfr[n], acc[m][n], 0, 0, 0);
    }
  }

  int r0 = row0 + wr * 64, c0 = col0 + wc * 64;
#pragma unroll
  for (int m = 0; m < 4; ++m) {
#pragma unroll
    for (int n = 0; n < 4; ++n) {
      int col = c0 + n * 16 + (lane & 15);
      float bcol = bias[col];
#pragma unroll
      for (int reg = 0; reg < 4; ++reg) {
        int row = r0 + m * 16 + ((lane >> 4) << 2) + reg;
        float u = acc[m][n][reg] + bcol;
        if (GELU) u = gelu_tanh(u);
        if (RES) u += res[(size_t)row * N + col];
        if (OUTF32) C[(size_t)row * N + col] = u;
        if (OUTBF16) Cb[(size_t)row * N + col] = (bf16)u;
      }
    }
  }
}

// ---------------- split-K bf16 MFMA GEMM, BK=64, swizzled (by-fastest) ------
template <int NB>
__global__ __launch_bounds__(256) void k_gemm_sk(
    const bf16* __restrict__ A, const bf16* __restrict__ BT,
    f16* __restrict__ P, int N, int K, int Kslice, size_t strideB, size_t mn) {
  __shared__ bf16 Asb[2][8192];
  __shared__ bf16 Bsb[2][8192];
  int t = threadIdx.x;
  // XCD-aware bijective remap, row-tile (by) fastest for L2 locality
  int gx = gridDim.x, gy = gridDim.y;
  int nwg = gx * gy * gridDim.z;
  int lin = (blockIdx.z * gy + blockIdx.y) * gx + blockIdx.x;
  if (!(nwg & 7)) {
    int cpx = nwg >> 3;
    lin = (lin & 7) * cpx + (lin >> 3);
  }
  int by = lin % gy;
  int rem = lin / gy;
  int bx = rem % gx;
  int z = rem / gx;

  int bb = z % NB;
  int k0 = (z / NB) * Kslice;
  const bf16* Bbase = BT + (size_t)bb * strideB;
  int row0 = by * 128, col0 = bx * 128;
  int lane = t & 63, wid = t >> 6;
  int wr = wid >> 1, wc = wid & 1;

  const bf16* AgP[4];
  const bf16* BgP[4];
  int ldo[4];
#pragma unroll
  for (int j = 0; j < 4; ++j) {
    int p = t + j * 256;
    int sub = p >> 9;
    int pp = p & 511;
    int rt = ((pp >> 6) << 4) | (pp & 15);
    int kb = (pp >> 4) & 3;
    AgP[j] = A + (size_t)(row0 + rt) * K + k0 + sub * 32 + kb * 8;
    BgP[j] = Bbase + (size_t)(col0 + rt) * K + k0 + sub * 32 + kb * 8;
    ldo[j] = sub * 4096 + pp * 8;
  }

  f32x4 acc[4][4];
#pragma unroll
  for (int m = 0; m < 4; ++m)
#pragma unroll
    for (int n = 0; n < 4; ++n) acc[m][n] = (f32x4){0.f, 0.f, 0.f, 0.f};

#pragma unroll
  for (int j = 0; j < 4; ++j) {
    gl_lds16(AgP[j], &Asb[0][ldo[j]]);
    gl_lds16(BgP[j], &Bsb[0][ldo[j]]);
  }

  const int nt = Kslice >> 6;
  for (int kt = 0; kt < nt; ++kt) {
    int cur = kt & 1;
    __syncthreads();
    if (kt + 1 < nt) {
      size_t go = (size_t)(kt + 1) * 64;
      int nb = cur ^ 1;
#pragma unroll
      for (int j = 0; j < 4; ++j) {
        gl_lds16(AgP[j] + go, &Asb[nb][ldo[j]]);
        gl_lds16(BgP[j] + go, &Bsb[nb][ldo[j]]);
      }
    }
#pragma unroll
    for (int kk = 0; kk < 2; ++kk) {
      bf16x8 af[4], bfr[4];
#pragma unroll
      for (int m = 0; m < 4; ++m)
        af[m] = *(const bf16x8*)&Asb[cur][kk * 4096 + ((wr * 4 + m) * 64 + lane) * 8];
#pragma unroll
      for (int n = 0; n < 4; ++n)
        bfr[n] = *(const bf16x8*)&Bsb[cur][kk * 4096 + ((wc * 4 + n) * 64 + lane) * 8];
#pragma unroll
      for (int m = 0; m < 4; ++m)
#pragma unroll
        for (int n = 0; n < 4; ++n)
          acc[m][n] = __builtin_amdgcn_mfma_f32_16x16x32_bf16(af[m], bfr[n], acc[m][n], 0, 0, 0);
    }
  }

  f16* Pz = P + (size_t)z * mn;
  int r0 = row0 + wr * 64, c0 = col0 + wc * 64;
#pragma unroll
  for (int m = 0; m < 4; ++m)
#pragma unroll
    for (int n = 0; n < 4; ++n) {
      int col = c0 + n * 16 + (lane & 15);
#pragma unroll
      for (int reg = 0; reg < 4; ++reg) {
        int row = r0 + m * 16 + ((lane >> 4) << 2) + reg;
        Pz[(size_t)row * N + col] = (f16)acc[m][n][reg];
      }
    }
}

// ---------------- combine: vT = sum_sk P + v_b (bf16 out, [b][hd][s]) -------
__global__ __launch_bounds__(256) void k_fin_vT(const f16* __restrict__ P,
                                                const float* __restrict__ bias,
                                                bf16* __restrict__ vT) {
  size_t i = ((size_t)blockIdx.x * 256 + threadIdx.x) * 4;
  const size_t mn = (size_t)1024 * 1024;
  float sx = 0.f, sy = 0.f, sz = 0.f, sw2 = 0.f;
#pragma unroll
  for (int sk = 0; sk < 4; ++sk) {
    f16x4 v = *(const f16x4*)&P[(size_t)sk * 2 * mn + i];
    sx += (float)v.x; sy += (float)v.y; sz += (float)v.z; sw2 += (float)v.w;
  }
  float bcol = bias[(i >> 10) & 1023];
  bf16x4 o;
  o.x = (bf16)(sx + bcol); o.y = (bf16)(sy + bcol);
  o.z = (bf16)(sz + bcol); o.w = (bf16)(sw2 + bcol);
  *(bf16x4*)&vT[i] = o;
}

// ---------------- fused fin+LayerNorm: u = sumP + bias + res; LN(u) ---------
template <int SK, bool OUTBF16>
__global__ __launch_bounds__(256) void k_fin_ln(
    const f16* __restrict__ P, const float* __restrict__ bias,
    const float* __restrict__ res, const float* __restrict__ g,
    const float* __restrict__ bb, float* __restrict__ outF,
    bf16* __restrict__ outB) {
  int row = blockIdx.x, t = threadIdx.x;
  size_t base = (size_t)row * E_ + t * 4;
  const size_t mn = (size_t)2048 * 1024;
  float u0 = 0.f, u1 = 0.f, u2 = 0.f, u3 = 0.f;
#pragma unroll
  for (int sk = 0; sk < SK; ++sk) {
    f16x4 v = *(const f16x4*)&P[(size_t)sk * mn + base];
    u0 += (float)v.x; u1 += (float)v.y; u2 += (float)v.z; u3 += (float)v.w;
  }
  float4 bv = *(const float4*)&bias[t * 4];
  float4 rv = *(const float4*)&res[base];
  u0 += bv.x + rv.x; u1 += bv.y + rv.y; u2 += bv.z + rv.z; u3 += bv.w + rv.w;
  float s = u0 + u1 + u2 + u3;
  float s2 = u0 * u0 + u1 * u1 + u2 * u2 + u3 * u3;
#pragma unroll
  for (int off = 32; off >= 1; off >>= 1) {
    s += __shfl_xor(s, off);
    s2 += __shfl_xor(s2, off);
  }
  __shared__ float rs[4], rs2[4];
  int wid = t >> 6;
  if ((t & 63) == 0) { rs[wid] = s; rs2[wid] = s2; }
  __syncthreads();
  float S1 = rs[0] + rs[1] + rs[2] + rs[3];
  float S2 = rs2[0] + rs2[1] + rs2[2] + rs2[3];
  float mu = S1 * (1.f / E_);
  float var = S2 * (1.f / E_) - mu * mu;
  float inv = rsqrtf(var + 1e-5f);
  float4 gv = *(const float4*)&g[t * 4];
  float4 bbv = *(const float4*)&bb[t * 4];
  float4 ov;
  ov.x = (u0 - mu) * inv * gv.x + bbv.x;
  ov.y = (u1 - mu) * inv * gv.y + bbv.y;
  ov.z = (u2 - mu) * inv * gv.z + bbv.z;
  ov.w = (u3 - mu) * inv * gv.w + bbv.w;
  *(float4*)&outF[base] = ov;
  if (OUTBF16) {
    bf16x4 obv;
    obv.x = (bf16)ov.x; obv.y = (bf16)ov.y; obv.z = (bf16)ov.z; obv.w = (bf16)ov.w;
    *(bf16x4*)&outB[base] = obv;
  }
}

// ---------------- MFMA flash attention (cont-based scores) ------------------
__global__ __launch_bounds__(256) void k_attn2(
    const float* __restrict__ qsT, const float* __restrict__ kmT,
    const bf16* __restrict__ cont, const float* __restrict__ swin,
    const bf16* __restrict__ vT,
    bf16* __restrict__ o, bf16* __restrict__ opart, float* __restrict__ mlpart) {
  int q = blockIdx.x & 3;
  int iwg = blockIdx.x >> 2;       // 0..15
  if (q > iwg) return;             // ntile = iwg+1; quarter q needs q < ntile
  int bh = blockIdx.y;
  int b = bh >> 3, h = bh & 7;
  int t = threadIdx.x;
  int wid = t >> 6, lane = t & 63;
  int iw = iwg * 4 + wid;          // 0..63
  int m = lane & 15, ko = lane >> 4;
  int ntile = iwg + 1;

  __shared__ float sw[S_];
  *(float4*)&sw[t * 4] = *(const float4*)&swin[(size_t)bh * S_ + t * 4];
  __syncthreads();

  int i_row = iw * 16 + m;
  float qs_i = qsT[(size_t)bh * S_ + i_row];
  const bf16* cr = cont + ((size_t)bh << 20) + (size_t)i_row * S_;

  f32x4 acc[8];
#pragma unroll
  for (int nf = 0; nf < 8; ++nf) acc[nf] = (f32x4){0.f, 0.f, 0.f, 0.f};
  float m_run = -INFINITY, l_run = 0.f;

  for (int jt = q; jt < ntile; jt += 4) {
    int j0 = jt * 64;
    float pv[2][8];
    float mx = -INFINITY;
    bf16x8 cv[2];
    cv[0] = *(const bf16x8*)&cr[j0 + ko * 8];
    cv[1] = *(const bf16x8*)&cr[j0 + 32 + ko * 8];
#pragma unroll
    for (int s = 0; s < 2; ++s) {
      int bj = j0 + s * 32 + ko * 8;
      float4 km0 = *(const float4*)&kmT[(size_t)bh * S_ + bj];
      float4 km1 = *(const float4*)&kmT[(size_t)bh * S_ + bj + 4];
      float kmv[8] = {km0.x, km0.y, km0.z, km0.w, km1.x, km1.y, km1.z, km1.w};
#pragma unroll
      for (int e = 0; e < 8; ++e) {
        int j = bj + e;
        int dd = i_row - j;
        float val = sw[dd >= 0 ? dd : 0] + qs_i + kmv[e] + 0.25f * (float)cv[s][e];
        val = (dd >= 0) ? val : -INFINITY;   // cndmask, branch-free
        pv[s][e] = val;
        mx = fmaxf(mx, val);
      }
    }
    mx = fmaxf(mx, __shfl_xor(mx, 16));
    mx = fmaxf(mx, __shfl_xor(mx, 32));
    float mnew = fmaxf(m_run, mx);
    float scale = __expf(m_run - mnew);
    float lsum = 0.f;
    bf16x8 pa[2];
#pragma unroll
    for (int s = 0; s < 2; ++s)
#pragma unroll
      for (int e = 0; e < 8; ++e) {
        float p = __expf(pv[s][e] - mnew);
        lsum += p;
        pa[s][e] = (bf16)p;
      }
    lsum += __shfl_xor(lsum, 16);
    lsum += __shfl_xor(lsum, 32);
    l_run = l_run * scale + lsum;
    m_run = mnew;
    float sc[4];
#pragma unroll
    for (int r = 0; r < 4; ++r) sc[r] = __shfl(scale, ko * 4 + r);
#pragma unroll
    for (int nf = 0; nf < 8; ++nf)
#pragma unroll
      for (int r = 0; r < 4; ++r) acc[nf][r] *= sc[r];
#pragma unroll
    for (int s = 0; s < 2; ++s) {
      int bj = j0 + s * 32 + ko * 8;
#pragma unroll
      for (int nf = 0; nf < 8; ++nf) {
        int d = nf * 16 + m;
        bf16x8 bv = *(const bf16x8*)&vT[((size_t)bh * HD_ + d) * S_ + bj];
        acc[nf] = __builtin_amdgcn_mfma_f32_16x16x32_bf16(pa[s], bv, acc[nf], 0, 0, 0);
      }
    }
  }

  if (ntile == 1) {                // iw<4 (only q==0): finalize directly
    float lr[4];
#pragma unroll
    for (int r = 0; r < 4; ++r) lr[r] = __shfl(l_run, ko * 4 + r);
#pragma unroll
    for (int nf = 0; nf < 8; ++nf) {
      int d = nf * 16 + m;
#pragma unroll
      for (int r = 0; r < 4; ++r) {
        int row = iw * 16 + ko * 4 + r;
        o[(((size_t)b * S_ + row) * H_ + h) * HD_ + d] = (bf16)(acc[nf][r] / lr[r]);
      }
    }
  } else {
    bf16* op = opart + ((size_t)(q * 16 + bh) * 64 + iw) * 2048;
#pragma unroll
    for (int nf = 0; nf < 8; ++nf) {
      int d = nf * 16 + m;
#pragma unroll
      for (int r = 0; r < 4; ++r) op[(ko * 4 + r) * 128 + d] = (bf16)acc[nf][r];
    }
    if (lane < 16) {
      float* mlp = mlpart + ((size_t)(q * 16 + bh) * 64 + iw) * 32;
      mlp[m * 2 + 0] = m_run;
      mlp[m * 2 + 1] = l_run;
    }
  }
}

// ---------------- combine up to 4 attention quarters (rows iw>=4) -----------
__global__ __launch_bounds__(256) void k_comb(const bf16* __restrict__ opart,
                                              const float* __restrict__ mlpart,
                                              bf16* __restrict__ o) {
  int blk = blockIdx.x;
  int bh = blk / 60, iw = blk % 60 + 4;
  int b = bh >> 3, h = bh & 7;
  int t = threadIdx.x;
  int r = t >> 4, d0 = (t & 15) * 8;
  int nq = iw / 4 + 1;
  if (nq > 4) nq = 4;
  float mq[4], lq[4];
  float mm = -INFINITY;
#pragma unroll
  for (int q = 0; q < 4; ++q) {
    if (q < nq) {
      size_t idx = (size_t)(q * 16 + bh) * 64 + iw;
      mq[q] = mlpart[idx * 32 + r * 2];
      lq[q] = mlpart[idx * 32 + r * 2 + 1];
      mm = fmaxf(mm, mq[q]);
    }
  }
  float L = 0.f;
  float acc[8] = {0.f, 0.f, 0.f, 0.f, 0.f, 0.f, 0.f, 0.f};
#pragma unroll
  for (int q = 0; q < 4; ++q) {
    if (q < nq) {
      float e = __expf(mq[q] - mm);
      L += lq[q] * e;
      size_t idx = (size_t)(q * 16 + bh) * 64 + iw;
      bf16x8 v = *(const bf16x8*)&opart[(idx * 16 + r) * 128 + d0];
#pragma unroll
      for (int k = 0; k < 8; ++k) acc[k] += (float)v[k] * e;
    }
  }
  float inv = 1.f / L;
  bf16x8 ov;
#pragma unroll
  for (int k = 0; k < 8; ++k) ov[k] = (bf16)(acc[k] * inv);
  int row = iw * 16 + r;
  *(bf16x8*)&o[(((size_t)b * S_ + row) * H_ + h) * HD_ + d0] = ov;
}

}  // namespace

extern "C" void kernel_launch(void* const* d_in, const int* in_sizes, int n_in,
                              void* d_out, int out_size, void* d_ws, size_t ws_size,
                              hipStream_t stream) {
  (void)in_sizes; (void)n_in; (void)out_size; (void)ws_size;
  const float* x       = (const float*)d_in[0];
  const float* v_w     = (const float*)d_in[1];
  const float* v_b     = (const float*)d_in[2];
  const float* out_w   = (const float*)d_in[3];
  const float* out_b   = (const float*)d_in[4];
  const float* qmod_w  = (const float*)d_in[5];
  const float* qmod_b  = (const float*)d_in[6];
  const float* kmod_w  = (const float*)d_in[7];
  const float* kmod_b  = (const float*)d_in[8];
  const float* gate_w1 = (const float*)d_in[9];
  const float* gate_b1 = (const float*)d_in[10];
  const float* gate_w2 = (const float*)d_in[11];
  const float* gate_b2 = (const float*)d_in[12];
  const float* mod_w1  = (const float*)d_in[13];
  const float* mod_b1  = (const float*)d_in[14];
  const float* mod_w2  = (const float*)d_in[15];
  const float* mod_b2  = (const float*)d_in[16];
  const float* mod_basis = (const float*)d_in[17];
  const float* freqs   = (const float*)d_in[18];
  const float* amps    = (const float*)d_in[19];
  const float* phases  = (const float*)d_in[20];
  const float* cwq     = (const float*)d_in[21];
  const float* cwk     = (const float*)d_in[22];
  const float* ffn_w1  = (const float*)d_in[23];
  const float* ffn_b1  = (const float*)d_in[24];
  const float* ffn_w2  = (const float*)d_in[25];
  const float* ffn_b2  = (const float*)d_in[26];
  const float* ln_ag   = (const float*)d_in[27];
  const float* ln_ab   = (const float*)d_in[28];
  const float* ln_fg   = (const float*)d_in[29];
  const float* ln_fb   = (const float*)d_in[30];

  char* wsc = (char*)d_ws;
  size_t off = 0;
  auto alloc = [&](size_t bytes) -> void* {
    void* p = wsc + off;
    off += (bytes + 255) & ~(size_t)255;
    return p;
  };
  float* pooled = (float*)alloc(2048 * 4);
  float* part   = (float*)alloc(65536 * 4);
  float2* gpart = (float2*)alloc((size_t)2 * H_ * 16 * 128 * 8);
  float* wmod   = (float*)alloc(2048 * 4);
  float* kerns  = (float*)alloc((size_t)H_ * M_ * S_ * 4);
  float* swin   = (float*)alloc((size_t)B_ * H_ * S_ * 4);
  float* qsT    = (float*)alloc((size_t)B_ * H_ * S_ * 4);
  float* kmT    = (float*)alloc((size_t)B_ * H_ * S_ * 4);
  float* qcb    = (float*)alloc((size_t)B_ * H_ * S_ * R_ * 4);
  float* kcb    = (float*)alloc((size_t)B_ * H_ * S_ * R_ * 4);
  float* ybuf   = (float*)alloc((size_t)B_ * S_ * E_ * 4);       // 8MB (post-LN y)
  bf16* xb      = (bf16*)alloc((size_t)B_ * S_ * E_ * 2);
  bf16* yb      = (bf16*)alloc((size_t)B_ * S_ * E_ * 2);
  bf16* vwT     = (bf16*)alloc((size_t)E_ * E_ * 2);
  bf16* outwT   = (bf16*)alloc((size_t)E_ * E_ * 2);
  bf16* ffn1T   = (bf16*)alloc((size_t)E_ * FFNH_ * 2);
  bf16* ffn2T   = (bf16*)alloc((size_t)FFNH_ * E_ * 2);
  bf16* wcatT   = (bf16*)alloc((size_t)256 * E_ * 2);            // 0.5MB
  bf16* vT      = (bf16*)alloc((size_t)B_ * S_ * E_ * 2);        // v [b,hd,s]
  bf16* ob      = (bf16*)alloc((size_t)B_ * S_ * E_ * 2);        // attn out
  float* mlpart = (float*)alloc((size_t)4 * 16 * 64 * 16 * 2 * 4);
  char* poolU2  = (char*)alloc((size_t)B_ * S_ * FFNH_ * 2);     // 16MB union
  bf16* opart = (bf16*)poolU2;     // 16MB (attn phase)
  bf16* hb    = (bf16*)poolU2;     // 16MB (FFN phase)
  // P1: 64MB union. fp16 partials: qk [0,8MB); v [0,16MB); out [0,16MB);
  // ffn2 [0,16MB). cont (32MB bf16) at [16MB,48MB) until attn2 completes.
  char* P1c = (char*)alloc((size_t)64 * 1024 * 1024);
  f16*  P1  = (f16*)P1c;
  bf16* cont = (bf16*)(P1c + (size_t)16 * 1024 * 1024);

  float* outp = (float*)d_out;
  const int BS = B_ * S_;

  // fused prep (cvt + 4x transpose + wcat) and fused pool_partial + waves
  k_prep<<<13312, 256, 0, stream>>>(x, xb, v_w, vwT, out_w, outwT,
                                    ffn_w1, ffn1T, ffn_w2, ffn2T,
                                    qmod_w, kmod_w, cwq, cwk, wcatT);
  k_pw<<<64 + 4096, 256, 0, stream>>>(x, part, freqs, amps, phases, kerns);

  // scores pipeline
  k_pool_reduce<<<B_, 256, 0, stream>>>(part, pooled);
  k_gate1<<<dim3(16, H_, 2), 256, 0, stream>>>(pooled, gate_w1, mod_w1, gpart);
  k_gate2<<<B_ * H_, 256, 0, stream>>>(gpart, gate_b1, gate_w2, gate_b2,
                                       mod_b1, mod_w2, mod_b2, mod_basis, wmod);
  k_swin<<<B_ * H_ * (S_ / 256), 256, 0, stream>>>(wmod, kerns, swin);

  // qs/km/qc/kc via one MFMA GEMM: [xb (2048x1024)] @ WcatT^T -> 2048x256
  k_gemm_sk<1><<<dim3(2, 16, 8), 256, 0, stream>>>(
      xb, wcatT, P1, 256, E_, 128, 0, (size_t)2048 * 256);
  k_fin_qk<<<2048, 256, 0, stream>>>(P1, qmod_b, kmod_b, qsT, kmT, qcb, kcb);

  // content logits precompute (lower-tri 128-tiles), bf16
  k_cont<<<dim3(8, 8, 16), 256, 0, stream>>>(qcb, kcb, cont);

  // vT[b][hd][s] = vwT x xb^T, split-K=4 x batch2, fp16 partials
  k_gemm_sk<2><<<dim3(8, 8, 8), 256, 0, stream>>>(
      vwT, xb, P1, S_, E_, 256, (size_t)S_ * E_, (size_t)1024 * 1024);
  k_fin_vT<<<2048, 256, 0, stream>>>(P1, v_b, vT);

  k_attn2<<<dim3(64, 16), 256, 0, stream>>>(qsT, kmT, cont, swin, vT, ob, opart, mlpart);
  k_comb<<<16 * 60, 256, 0, stream>>>(opart, mlpart, ob);

  // y = LN(o @ out_w + out_b + x)  (split-K=4, fused fin+LN -> ybuf fp32 + yb bf16)
  k_gemm_sk<1><<<dim3(8, 16, 4), 256, 0, stream>>>(
      ob, outwT, P1, E_, E_, 256, 0, (size_t)2048 * 1024);
  k_fin_ln<4, true><<<2048, 256, 0, stream>>>(P1, out_b, x, ln_ag, ln_ab, ybuf, yb);

  // h = gelu(y @ ffn_w1 + b1)  (fused epilogue, no partial round-trip)
  k_gemm_mfma<true, false, false, true><<<dim3(FFNH_ / 128, BS / 128), 256, 0, stream>>>(
      yb, ffn1T, ffn_b1, nullptr, nullptr, hb, FFNH_, E_);

  // out = LN(h @ ffn_w2 + b2 + y)  (split-K=4, fused fin+LN -> outp)
  k_gemm_sk<1><<<dim3(8, 16, 4), 256, 0, stream>>>(
      hb, ffn2T, P1, E_, FFNH_, 1024, 0, (size_t)2048 * 1024);
  k_fin_ln<4, false><<<2048, 256, 0, stream>>>(P1, ffn_b2, ybuf, ln_fg, ln_fb, outp, nullptr);
}

// Round 17
// 236.474 us; speedup vs baseline: 1.4528x; 1.0867x over previous
//
#include <hip/hip_runtime.h>
#include <math.h>
#include <stdint.h>

namespace {

constexpr int B_ = 2, S_ = 1024, E_ = 1024, H_ = 8, HD_ = 128;
constexpr int M_ = 128, W_ = 32, GH_ = 128, R_ = 8, MR_ = 8, FFNH_ = 4096;
constexpr int SCH = 32;            // s-chunks for pooling
constexpr int SPC = S_ / SCH;      // 32 rows per chunk

typedef __bf16 bf16;
typedef _Float16 f16;
typedef __attribute__((ext_vector_type(8))) __bf16 bf16x8;
typedef __attribute__((ext_vector_type(4))) __bf16 bf16x4;
typedef __attribute__((ext_vector_type(4))) _Float16 f16x4;
typedef __attribute__((ext_vector_type(4))) float f32x4;

__device__ inline float gelu_tanh(float u) {
  float u3 = u * u * u;
  return 0.5f * u * (1.f + tanhf(0.7978845608028654f * (u + 0.044715f * u3)));
}

__device__ __forceinline__ void gl_lds16(const void* g, void* l) {
  __builtin_amdgcn_global_load_lds((const __attribute__((address_space(1))) void*)g,
                                   (__attribute__((address_space(3))) void*)l, 16, 0, 0);
}

// ---------------- fused prep: cvt + 4x transpose + wcat + pool + waves ------
// blocks [0,2048): x->xb; [2048,3072): v_w^T; [3072,4096): out_w^T;
// [4096,8192): ffn_w1^T; [8192,12288): ffn_w2^T; [12288,13312): wcat;
// [13312,13376): pool partials; [13376,17472): wave synthesis.
// Branches are uniform per block -> __syncthreads inside branches is safe.
__global__ __launch_bounds__(256) void k_prep(
    const float* __restrict__ x, bf16* __restrict__ xb,
    const float* __restrict__ v_w, bf16* __restrict__ vwT,
    const float* __restrict__ out_w, bf16* __restrict__ outwT,
    const float* __restrict__ ffn_w1, bf16* __restrict__ ffn1T,
    const float* __restrict__ ffn_w2, bf16* __restrict__ ffn2T,
    const float* __restrict__ qmw, const float* __restrict__ kmw,
    const float* __restrict__ cwq, const float* __restrict__ cwk,
    bf16* __restrict__ wcat, float* __restrict__ part,
    const float* __restrict__ freqs, const float* __restrict__ amps,
    const float* __restrict__ phases, float* __restrict__ kerns) {
  __shared__ float tile[32][33];
  __shared__ float f0[W_], f1[W_], am[W_], ph[W_];
  int b = blockIdx.x, t = threadIdx.x;
  if (b < 2048) {                  // fp32 -> bf16 elementwise (x)
    size_t i = ((size_t)b * 256 + t) * 4;
    float4 v = *(const float4*)(x + i);
    bf16x4 o;
    o.x = (bf16)v.x; o.y = (bf16)v.y; o.z = (bf16)v.z; o.w = (bf16)v.w;
    *(bf16x4*)(xb + i) = o;
    return;
  }
  if (b < 12288) {                 // weight (K,N) fp32 -> (N,K) bf16 transpose
    const float* w; bf16* wT; int K, N, bx, by;
    if (b < 3072) {
      w = v_w; wT = vwT; K = 1024; N = 1024;
      int l = b - 2048; bx = l & 31; by = l >> 5;
    } else if (b < 4096) {
      w = out_w; wT = outwT; K = 1024; N = 1024;
      int l = b - 3072; bx = l & 31; by = l >> 5;
    } else if (b < 8192) {
      w = ffn_w1; wT = ffn1T; K = 1024; N = 4096;
      int l = b - 4096; bx = l & 127; by = l >> 7;
    } else {
      w = ffn_w2; wT = ffn2T; K = 4096; N = 1024;
      int l = b - 8192; bx = l & 31; by = l >> 5;
    }
    int n0 = bx * 32, k0 = by * 32;
    int tx = t & 31, ty = t >> 5;
    for (int r = ty; r < 32; r += 8) tile[r][tx] = w[(size_t)(k0 + r) * N + n0 + tx];
    __syncthreads();
    for (int r = ty; r < 32; r += 8) wT[(size_t)(n0 + r) * K + k0 + tx] = (bf16)tile[tx][r];
    return;
  }
  if (b < 13312) {                 // Wcat^T (256 x 1024)
    int idx = (b - 12288) * 256 + t;
    int n = idx >> 10, k = idx & 1023;
    float v = 0.f;
    if (n < 8) {
      v = qmw[k * 8 + n];
    } else if (n < 16) {
      v = kmw[k * 8 + (n - 8)];
    } else if (n < 80) {
      int u = n - 16, h = u >> 3, r = u & 7;
      int kk = k - h * 128;
      if (kk >= 0 && kk < 128) v = cwq[((size_t)h * 128 + kk) * 8 + r];
    } else if (n < 144) {
      int u = n - 80, h = u >> 3, r = u & 7;
      int kk = k - h * 128;
      if (kk >= 0 && kk < 128) v = cwk[((size_t)h * 128 + kk) * 8 + r];
    }
    wcat[idx] = (bf16)v;
    return;
  }
  if (b < 13376) {                 // pool partials
    int b0 = b - 13312;
    int bb = b0 / SCH, c = b0 % SCH;
    const float* xp = x + (size_t)bb * S_ * E_ + (size_t)c * SPC * E_;
    float acc[4] = {0.f, 0.f, 0.f, 0.f};
    for (int s = 0; s < SPC; ++s) {
      const float* row = xp + (size_t)s * E_;
#pragma unroll
      for (int q = 0; q < 4; ++q) acc[q] += row[t + q * 256];
    }
    float* pp = part + (size_t)b0 * E_;
#pragma unroll
    for (int q = 0; q < 4; ++q) pp[t + q * 256] = acc[q];
    return;
  }
  {                                // waves
    int blk = b - 13376;
    int lt = blk & 3;
    int hm = blk >> 2;
    if (t < W_) {
      f0[t] = freqs[((size_t)hm * W_ + t) * 2 + 0];
      f1[t] = freqs[((size_t)hm * W_ + t) * 2 + 1];
      am[t] = amps[(size_t)hm * W_ + t];
      ph[t] = phases[(size_t)hm * W_ + t];
    }
    __syncthreads();
    int l = lt * 256 + t;
    float rel = (float)(l - (S_ - 1));
    float p1 = rel * (1.0f / S_);
    float p2 = (rel < 0.f) ? (-sqrtf(-rel + 1e-6f) * (1.0f / 32.0f)) : 0.f;
    const float TWO_PI = 6.28318530717958647692f;
    float acc = 0.f;
#pragma unroll
    for (int w = 0; w < W_; ++w)
      acc += am[w] * __sinf(TWO_PI * (f0[w] * p1 + f1[w] * p2) + ph[w]);
    kerns[(size_t)hm * S_ + l] = acc;
  }
}

// ---------------- finish qk GEMM: sum fp16 partials, scatter -----------------
__global__ __launch_bounds__(256) void k_fin_qk(
    const f16* __restrict__ P, const float* __restrict__ qmb,
    const float* __restrict__ kmb, float* __restrict__ qsT,
    float* __restrict__ kmT, float* __restrict__ qc, float* __restrict__ kc) {
  int row = blockIdx.x;            // 0..2047
  int t = threadIdx.x;
  if (t >= 144) return;
  int b = row >> 10, s = row & 1023;
  const size_t mn = (size_t)2048 * 256;
  float sum = 0.f;
#pragma unroll
  for (int z = 0; z < 8; ++z) sum += (float)P[(size_t)z * mn + (size_t)row * 256 + t];
  if (t < 8) {
    qsT[((size_t)(b * 8 + t)) * 1024 + s] = sum + qmb[t];
  } else if (t < 16) {
    kmT[((size_t)(b * 8 + t - 8)) * 1024 + s] = sum + kmb[t - 8];
  } else if (t < 80) {
    int u = t - 16, h = u >> 3, r = u & 7;
    qc[(((size_t)(b * 8 + h)) * 1024 + s) * 8 + r] = sum;
  } else {
    int u = t - 80, h = u >> 3, r = u & 7;
    kc[(((size_t)(b * 8 + h)) * 1024 + s) * 8 + r] = sum;
  }
}

// ---------------- gate first layer (pooled computed in-kernel from part) ----
__global__ __launch_bounds__(256) void k_gate1(
    const float* __restrict__ part,
    const float* __restrict__ gw1, const float* __restrict__ mw1,
    float2* __restrict__ outp) {
  int chunk = blockIdx.x;          // 0..15
  int h = blockIdx.y;              // 0..7
  int mat = blockIdx.z;            // 0: gate, 1: mod
  const float* w = mat ? mw1 : gw1;
  int t = threadIdx.x;
  __shared__ float spool[2][64];
  if (t < 128) {                   // pooled slice: same summation order as
    int bb = t >> 6;               // the old k_pool_reduce (c=0..31, x 1/S)
    int e = chunk * 64 + (t & 63);
    float s = 0.f;
    for (int c = 0; c < SCH; ++c) s += part[(size_t)(bb * SCH + c) * E_ + e];
    spool[bb][t & 63] = s * (1.0f / S_);
  }
  __syncthreads();
  int g = t & 127, half = t >> 7;
  int e0 = chunk * 64 + half * 32;
  const float* wp = w + (size_t)h * E_ * GH_ + (size_t)e0 * GH_ + g;
  float a0 = 0.f, a1 = 0.f;
#pragma unroll 8
  for (int r = 0; r < 32; ++r) {
    float wv = wp[(size_t)r * GH_];
    a0 += spool[0][half * 32 + r] * wv;
    a1 += spool[1][half * 32 + r] * wv;
  }
  __shared__ float red[2][2][128];
  red[half][0][g] = a0;
  red[half][1][g] = a1;
  __syncthreads();
  if (half == 0) {
    float2 o;
    o.x = red[0][0][g] + red[1][0][g];
    o.y = red[0][1][g] + red[1][1][g];
    outp[(((size_t)mat * H_ + h) * 16 + chunk) * 128 + g] = o;
  }
}

// ---------------- gate finish ------------------------------------------------
__global__ __launch_bounds__(256) void k_gate2(
    const float2* __restrict__ part,
    const float* __restrict__ gb1, const float* __restrict__ gw2, const float* __restrict__ gb2,
    const float* __restrict__ mb1, const float* __restrict__ mw2, const float* __restrict__ mb2,
    const float* __restrict__ mbasis, float* __restrict__ wmod) {
  int bh = blockIdx.x;
  int b = bh >> 3, h = bh & 7;
  int t = threadIdx.x;
  __shared__ float ghs[GH_], mhs[GH_], glog[M_], mrs[MR_];
  __shared__ float red2[2][128];
  __shared__ float rbuf[128];
  {
    int g = t & 127, mat = t >> 7;
    const float2* pp = part + ((size_t)mat * H_ + h) * 16 * 128 + g;
    float acc = 0.f;
#pragma unroll
    for (int c = 0; c < 16; ++c) {
      float2 v = pp[(size_t)c * 128];
      acc += b ? v.y : v.x;
    }
    acc += (mat ? mb1 : gb1)[h * GH_ + g];
    acc = fmaxf(acc, 0.f);
    if (mat == 0) ghs[g] = acc; else mhs[g] = acc;
  }
  __syncthreads();
  {
    int m = t & 127, half = t >> 7;
    float acc = 0.f;
    const float* wp = gw2 + (size_t)h * GH_ * M_ + m;
#pragma unroll 4
    for (int g = half * 64; g < half * 64 + 64; ++g)
      acc += ghs[g] * wp[(size_t)g * M_];
    red2[half][m] = acc;
  }
  __syncthreads();
  if (t < 128) glog[t] = red2[0][t] + red2[1][t] + gb2[h * M_ + t];
  if (t < 64) {
    int r = t & 7, seg = t >> 3;
    float acc = 0.f;
    const float* wp = mw2 + (size_t)h * GH_ * MR_ + r;
    for (int g = seg * 16; g < seg * 16 + 16; ++g) acc += mhs[g] * wp[(size_t)g * MR_];
    acc += __shfl_xor(acc, 8);
    acc += __shfl_xor(acc, 16);
    acc += __shfl_xor(acc, 32);
    if (t < 8) mrs[t] = acc + mb2[h * MR_ + t];
  }
  __syncthreads();
  if (t < 128) rbuf[t] = glog[t];
  __syncthreads();
  for (int off = 64; off >= 1; off >>= 1) {
    if (t < off) rbuf[t] = fmaxf(rbuf[t], rbuf[t + off]);
    __syncthreads();
  }
  float mx = rbuf[0];
  __syncthreads();
  float ev = 0.f;
  if (t < 128) ev = expf(glog[t] - mx);
  __syncthreads();
  if (t < 128) rbuf[t] = ev;
  __syncthreads();
  for (int off = 64; off >= 1; off >>= 1) {
    if (t < off) rbuf[t] += rbuf[t + off];
    __syncthreads();
  }
  float inv = 1.f / rbuf[0];
  if (t < 128) {
    float wsel = ev * inv;
    float md = 0.f;
#pragma unroll
    for (int r = 0; r < MR_; ++r) md += mrs[r] * mbasis[((size_t)h * MR_ + r) * M_ + t];
    wmod[bh * M_ + t] = wsel * (1.f + md);
  }
}

// ---------------- cont (lower-tri 128-tiles) + swin (z==16) -----------------
__global__ __launch_bounds__(256) void k_cont(const float* __restrict__ qc,
                                              const float* __restrict__ kc,
                                              bf16* __restrict__ cont,
                                              const float* __restrict__ wmod,
                                              const float* __restrict__ kerns,
                                              float* __restrict__ swin) {
  int jt = blockIdx.x, it = blockIdx.y;
  int bh = blockIdx.z;
  int t = threadIdx.x;
  if (bh == 16) {                  // swin: 8x8 = 64 blocks
    __shared__ float wm[M_];
    int blk = it * 8 + jt;         // 0..63
    int dt = blk & 3;
    int sbh = blk >> 2;            // 0..15
    int h = sbh & 7;
    if (t < M_) wm[t] = wmod[sbh * M_ + t];
    __syncthreads();
    int d = dt * 256 + t;
    int l = (S_ - 1) - d;
    float acc = 0.f;
    for (int m = 0; m < M_; ++m) acc += wm[m] * kerns[((size_t)h * M_ + m) * S_ + l];
    float dd = (float)d;
    float win = expf(-dd * dd * (1.0f / 131072.0f));
    swin[(size_t)sbh * S_ + d] = 3.0f * win * acc;
    return;
  }
  if (jt > it) return;
  int w = t >> 6, lane = t & 63;
  int ln = lane & 15, ko = lane >> 4;
  int i0 = it * 128 + w * 32;
  int j0 = jt * 128;

  bf16x8 av[2];
#pragma unroll
  for (int mi = 0; mi < 2; ++mi) {
    bf16x8 a;
#pragma unroll
    for (int k = 0; k < 8; ++k) a[k] = (bf16)0.f;
    if (ko == 0) {
      const float* qp = &qc[((size_t)bh * S_ + i0 + mi * 16 + ln) * 8];
      float4 q0 = *(const float4*)qp;
      float4 q1 = *(const float4*)(qp + 4);
      a[0] = (bf16)q0.x; a[1] = (bf16)q0.y; a[2] = (bf16)q0.z; a[3] = (bf16)q0.w;
      a[4] = (bf16)q1.x; a[5] = (bf16)q1.y; a[6] = (bf16)q1.z; a[7] = (bf16)q1.w;
    }
    av[mi] = a;
  }
  bf16x8 bv[8];
#pragma unroll
  for (int nb = 0; nb < 8; ++nb) {
    bf16x8 bb;
#pragma unroll
    for (int k = 0; k < 8; ++k) bb[k] = (bf16)0.f;
    if (ko == 0) {
      const float* kp = &kc[((size_t)bh * S_ + j0 + nb * 16 + ln) * 8];
      float4 k0 = *(const float4*)kp;
      float4 k1 = *(const float4*)(kp + 4);
      bb[0] = (bf16)k0.x; bb[1] = (bf16)k0.y; bb[2] = (bf16)k0.z; bb[3] = (bf16)k0.w;
      bb[4] = (bf16)k1.x; bb[5] = (bf16)k1.y; bb[6] = (bf16)k1.z; bb[7] = (bf16)k1.w;
    }
    bv[nb] = bb;
  }
  f32x4 acc[2][8];
#pragma unroll
  for (int mi = 0; mi < 2; ++mi)
#pragma unroll
    for (int nb = 0; nb < 8; ++nb) {
      acc[mi][nb] = (f32x4){0.f, 0.f, 0.f, 0.f};
      acc[mi][nb] = __builtin_amdgcn_mfma_f32_16x16x32_bf16(av[mi], bv[nb], acc[mi][nb], 0, 0, 0);
    }
  bf16* cb = cont + ((size_t)bh << 20);
#pragma unroll
  for (int mi = 0; mi < 2; ++mi)
#pragma unroll
    for (int nb = 0; nb < 8; ++nb) {
      int col = j0 + nb * 16 + ln;
#pragma unroll
      for (int reg = 0; reg < 4; ++reg) {
        int row = i0 + mi * 16 + ko * 4 + reg;
        cb[(size_t)row * S_ + col] = (bf16)acc[mi][nb][reg];
      }
    }
}

// ---------------- bf16 MFMA GEMM, BK=64, fused epilogue (FFN1), swizzled ----
template <bool GELU, bool RES, bool OUTF32, bool OUTBF16>
__global__ __launch_bounds__(256) void k_gemm_mfma(
    const bf16* __restrict__ A, const bf16* __restrict__ BT,
    const float* __restrict__ bias, const float* __restrict__ res,
    float* __restrict__ C, bf16* __restrict__ Cb, int N, int K) {
  __shared__ bf16 Asb[2][8192];
  __shared__ bf16 Bsb[2][8192];
  int t = threadIdx.x;
  // XCD-aware bijective remap, row-tile fastest (L2 locality)
  int gx = gridDim.x, gy = gridDim.y;
  int nwg = gx * gy;
  int lin = blockIdx.y * gx + blockIdx.x;
  if (!(nwg & 7)) {
    int cpx = nwg >> 3;
    lin = (lin & 7) * cpx + (lin >> 3);
  }
  int by = lin % gy;
  int bx = lin / gy;
  int row0 = by * 128, col0 = bx * 128;
  int lane = t & 63, wid = t >> 6;
  int wr = wid >> 1, wc = wid & 1;

  const bf16* AgP[4];
  const bf16* BgP[4];
  int ldo[4];
#pragma unroll
  for (int j = 0; j < 4; ++j) {
    int p = t + j * 256;           // 0..1023
    int sub = p >> 9;
    int pp = p & 511;
    int rt = ((pp >> 6) << 4) | (pp & 15);
    int kb = (pp >> 4) & 3;
    AgP[j] = A + (size_t)(row0 + rt) * K + sub * 32 + kb * 8;
    BgP[j] = BT + (size_t)(col0 + rt) * K + sub * 32 + kb * 8;
    ldo[j] = sub * 4096 + pp * 8;
  }

  f32x4 acc[4][4];
#pragma unroll
  for (int m = 0; m < 4; ++m)
#pragma unroll
    for (int n = 0; n < 4; ++n) acc[m][n] = (f32x4){0.f, 0.f, 0.f, 0.f};

#pragma unroll
  for (int j = 0; j < 4; ++j) {
    gl_lds16(AgP[j], &Asb[0][ldo[j]]);
    gl_lds16(BgP[j], &Bsb[0][ldo[j]]);
  }

  const int nt = K >> 6;
  for (int kt = 0; kt < nt; ++kt) {
    int cur = kt & 1;
    __syncthreads();
    if (kt + 1 < nt) {
      size_t go = (size_t)(kt + 1) * 64;
      int nb = cur ^ 1;
#pragma unroll
      for (int j = 0; j < 4; ++j) {
        gl_lds16(AgP[j] + go, &Asb[nb][ldo[j]]);
        gl_lds16(BgP[j] + go, &Bsb[nb][ldo[j]]);
      }
    }
#pragma unroll
    for (int kk = 0; kk < 2; ++kk) {
      bf16x8 af[4], bfr[4];
#pragma unroll
      for (int m = 0; m < 4; ++m)
        af[m] = *(const bf16x8*)&Asb[cur][kk * 4096 + ((wr * 4 + m) * 64 + lane) * 8];
#pragma unroll
      for (int n = 0; n < 4; ++n)
        bfr[n] = *(const bf16x8*)&Bsb[cur][kk * 4096 + ((wc * 4 + n) * 64 + lane) * 8];
#pragma unroll
      for (int m = 0; m < 4; ++m)
#pragma unroll
        for (int n = 0; n < 4; ++n)
          acc[m][n] = __builtin_amdgcn_mfma_f32_16x16x32_bf16(af[m], bfr[n], acc[m][n], 0, 0, 0);
    }
  }

  int r0 = row0 + wr * 64, c0 = col0 + wc * 64;
#pragma unroll
  for (int m = 0; m < 4; ++m) {
#pragma unroll
    for (int n = 0; n < 4; ++n) {
      int col = c0 + n * 16 + (lane & 15);
      float bcol = bias[col];
#pragma unroll
      for (int reg = 0; reg < 4; ++reg) {
        int row = r0 + m * 16 + ((lane >> 4) << 2) + reg;
        float u = acc[m][n][reg] + bcol;
        if (GELU) u = gelu_tanh(u);
        if (RES) u += res[(size_t)row * N + col];
        if (OUTF32) C[(size_t)row * N + col] = u;
        if (OUTBF16) Cb[(size_t)row * N + col] = (bf16)u;
      }
    }
  }
}

// ---------------- split-K bf16 MFMA GEMM, BK=64, swizzled (by-fastest) ------
template <int NB>
__global__ __launch_bounds__(256) void k_gemm_sk(
    const bf16* __restrict__ A, const bf16* __restrict__ BT,
    f16* __restrict__ P, int N, int K, int Kslice, size_t strideB, size_t mn) {
  __shared__ bf16 Asb[2][8192];
  __shared__ bf16 Bsb[2][8192];
  int t = threadIdx.x;
  // XCD-aware bijective remap, row-tile (by) fastest for L2 locality
  int gx = gridDim.x, gy = gridDim.y;
  int nwg = gx * gy * gridDim.z;
  int lin = (blockIdx.z * gy + blockIdx.y) * gx + blockIdx.x;
  if (!(nwg & 7)) {
    int cpx = nwg >> 3;
    lin = (lin & 7) * cpx + (lin >> 3);
  }
  int by = lin % gy;
  int rem = lin / gy;
  int bx = rem % gx;
  int z = rem / gx;

  int bb = z % NB;
  int k0 = (z / NB) * Kslice;
  const bf16* Bbase = BT + (size_t)bb * strideB;
  int row0 = by * 128, col0 = bx * 128;
  int lane = t & 63, wid = t >> 6;
  int wr = wid >> 1, wc = wid & 1;

  const bf16* AgP[4];
  const bf16* BgP[4];
  int ldo[4];
#pragma unroll
  for (int j = 0; j < 4; ++j) {
    int p = t + j * 256;
    int sub = p >> 9;
    int pp = p & 511;
    int rt = ((pp >> 6) << 4) | (pp & 15);
    int kb = (pp >> 4) & 3;
    AgP[j] = A + (size_t)(row0 + rt) * K + k0 + sub * 32 + kb * 8;
    BgP[j] = Bbase + (size_t)(col0 + rt) * K + k0 + sub * 32 + kb * 8;
    ldo[j] = sub * 4096 + pp * 8;
  }

  f32x4 acc[4][4];
#pragma unroll
  for (int m = 0; m < 4; ++m)
#pragma unroll
    for (int n = 0; n < 4; ++n) acc[m][n] = (f32x4){0.f, 0.f, 0.f, 0.f};

#pragma unroll
  for (int j = 0; j < 4; ++j) {
    gl_lds16(AgP[j], &Asb[0][ldo[j]]);
    gl_lds16(BgP[j], &Bsb[0][ldo[j]]);
  }

  const int nt = Kslice >> 6;
  for (int kt = 0; kt < nt; ++kt) {
    int cur = kt & 1;
    __syncthreads();
    if (kt + 1 < nt) {
      size_t go = (size_t)(kt + 1) * 64;
      int nb = cur ^ 1;
#pragma unroll
      for (int j = 0; j < 4; ++j) {
        gl_lds16(AgP[j] + go, &Asb[nb][ldo[j]]);
        gl_lds16(BgP[j] + go, &Bsb[nb][ldo[j]]);
      }
    }
#pragma unroll
    for (int kk = 0; kk < 2; ++kk) {
      bf16x8 af[4], bfr[4];
#pragma unroll
      for (int m = 0; m < 4; ++m)
        af[m] = *(const bf16x8*)&Asb[cur][kk * 4096 + ((wr * 4 + m) * 64 + lane) * 8];
#pragma unroll
      for (int n = 0; n < 4; ++n)
        bfr[n] = *(const bf16x8*)&Bsb[cur][kk * 4096 + ((wc * 4 + n) * 64 + lane) * 8];
#pragma unroll
      for (int m = 0; m < 4; ++m)
#pragma unroll
        for (int n = 0; n < 4; ++n)
          acc[m][n] = __builtin_amdgcn_mfma_f32_16x16x32_bf16(af[m], bfr[n], acc[m][n], 0, 0, 0);
    }
  }

  f16* Pz = P + (size_t)z * mn;
  int r0 = row0 + wr * 64, c0 = col0 + wc * 64;
#pragma unroll
  for (int m = 0; m < 4; ++m)
#pragma unroll
    for (int n = 0; n < 4; ++n) {
      int col = c0 + n * 16 + (lane & 15);
#pragma unroll
      for (int reg = 0; reg < 4; ++reg) {
        int row = r0 + m * 16 + ((lane >> 4) << 2) + reg;
        Pz[(size_t)row * N + col] = (f16)acc[m][n][reg];
      }
    }
}

// ---------------- combine: vT = sum_sk P + v_b (bf16 out, [b][hd][s]) -------
__global__ __launch_bounds__(256) void k_fin_vT(const f16* __restrict__ P,
                                                const float* __restrict__ bias,
                                                bf16* __restrict__ vT) {
  size_t i = ((size_t)blockIdx.x * 256 + threadIdx.x) * 4;
  const size_t mn = (size_t)1024 * 1024;
  float sx = 0.f, sy = 0.f, sz = 0.f, sw2 = 0.f;
#pragma unroll
  for (int sk = 0; sk < 4; ++sk) {
    f16x4 v = *(const f16x4*)&P[(size_t)sk * 2 * mn + i];
    sx += (float)v.x; sy += (float)v.y; sz += (float)v.z; sw2 += (float)v.w;
  }
  float bcol = bias[(i >> 10) & 1023];
  bf16x4 o;
  o.x = (bf16)(sx + bcol); o.y = (bf16)(sy + bcol);
  o.z = (bf16)(sz + bcol); o.w = (bf16)(sw2 + bcol);
  *(bf16x4*)&vT[i] = o;
}

// ---------------- fused fin+LayerNorm: u = sumP + bias + res; LN(u) ---------
template <int SK, bool OUTBF16>
__global__ __launch_bounds__(256) void k_fin_ln(
    const f16* __restrict__ P, const float* __restrict__ bias,
    const float* __restrict__ res, const float* __restrict__ g,
    const float* __restrict__ bb, float* __restrict__ outF,
    bf16* __restrict__ outB) {
  int row = blockIdx.x, t = threadIdx.x;
  size_t base = (size_t)row * E_ + t * 4;
  const size_t mn = (size_t)2048 * 1024;
  float u0 = 0.f, u1 = 0.f, u2 = 0.f, u3 = 0.f;
#pragma unroll
  for (int sk = 0; sk < SK; ++sk) {
    f16x4 v = *(const f16x4*)&P[(size_t)sk * mn + base];
    u0 += (float)v.x; u1 += (float)v.y; u2 += (float)v.z; u3 += (float)v.w;
  }
  float4 bv = *(const float4*)&bias[t * 4];
  float4 rv = *(const float4*)&res[base];
  u0 += bv.x + rv.x; u1 += bv.y + rv.y; u2 += bv.z + rv.z; u3 += bv.w + rv.w;
  float s = u0 + u1 + u2 + u3;
  float s2 = u0 * u0 + u1 * u1 + u2 * u2 + u3 * u3;
#pragma unroll
  for (int off = 32; off >= 1; off >>= 1) {
    s += __shfl_xor(s, off);
    s2 += __shfl_xor(s2, off);
  }
  __shared__ float rs[4], rs2[4];
  int wid = t >> 6;
  if ((t & 63) == 0) { rs[wid] = s; rs2[wid] = s2; }
  __syncthreads();
  float S1 = rs[0] + rs[1] + rs[2] + rs[3];
  float S2 = rs2[0] + rs2[1] + rs2[2] + rs2[3];
  float mu = S1 * (1.f / E_);
  float var = S2 * (1.f / E_) - mu * mu;
  float inv = rsqrtf(var + 1e-5f);
  float4 gv = *(const float4*)&g[t * 4];
  float4 bbv = *(const float4*)&bb[t * 4];
  float4 ov;
  ov.x = (u0 - mu) * inv * gv.x + bbv.x;
  ov.y = (u1 - mu) * inv * gv.y + bbv.y;
  ov.z = (u2 - mu) * inv * gv.z + bbv.z;
  ov.w = (u3 - mu) * inv * gv.w + bbv.w;
  *(float4*)&outF[base] = ov;
  if (OUTBF16) {
    bf16x4 obv;
    obv.x = (bf16)ov.x; obv.y = (bf16)ov.y; obv.z = (bf16)ov.z; obv.w = (bf16)ov.w;
    *(bf16x4*)&outB[base] = obv;
  }
}

// ---------------- MFMA flash attention (cont-based scores) ------------------
__global__ __launch_bounds__(256) void k_attn2(
    const float* __restrict__ qsT, const float* __restrict__ kmT,
    const bf16* __restrict__ cont, const float* __restrict__ swin,
    const bf16* __restrict__ vT,
    bf16* __restrict__ o, bf16* __restrict__ opart, float* __restrict__ mlpart) {
  int q = blockIdx.x & 3;
  int iwg = blockIdx.x >> 2;       // 0..15
  if (q > iwg) return;             // ntile = iwg+1; quarter q needs q < ntile
  int bh = blockIdx.y;
  int b = bh >> 3, h = bh & 7;
  int t = threadIdx.x;
  int wid = t >> 6, lane = t & 63;
  int iw = iwg * 4 + wid;          // 0..63
  int m = lane & 15, ko = lane >> 4;
  int ntile = iwg + 1;

  __shared__ float sw[S_];
  *(float4*)&sw[t * 4] = *(const float4*)&swin[(size_t)bh * S_ + t * 4];
  __syncthreads();

  int i_row = iw * 16 + m;
  float qs_i = qsT[(size_t)bh * S_ + i_row];
  const bf16* cr = cont + ((size_t)bh << 20) + (size_t)i_row * S_;

  f32x4 acc[8];
#pragma unroll
  for (int nf = 0; nf < 8; ++nf) acc[nf] = (f32x4){0.f, 0.f, 0.f, 0.f};
  float m_run = -INFINITY, l_run = 0.f;

  for (int jt = q; jt < ntile; jt += 4) {
    int j0 = jt * 64;
    float pv[2][8];
    float mx = -INFINITY;
    bf16x8 cv[2];
    cv[0] = *(const bf16x8*)&cr[j0 + ko * 8];
    cv[1] = *(const bf16x8*)&cr[j0 + 32 + ko * 8];
#pragma unroll
    for (int s = 0; s < 2; ++s) {
      int bj = j0 + s * 32 + ko * 8;
      float4 km0 = *(const float4*)&kmT[(size_t)bh * S_ + bj];
      float4 km1 = *(const float4*)&kmT[(size_t)bh * S_ + bj + 4];
      float kmv[8] = {km0.x, km0.y, km0.z, km0.w, km1.x, km1.y, km1.z, km1.w};
#pragma unroll
      for (int e = 0; e < 8; ++e) {
        int j = bj + e;
        int dd = i_row - j;
        float val = sw[dd >= 0 ? dd : 0] + qs_i + kmv[e] + 0.25f * (float)cv[s][e];
        val = (dd >= 0) ? val : -INFINITY;   // cndmask, branch-free
        pv[s][e] = val;
        mx = fmaxf(mx, val);
      }
    }
    mx = fmaxf(mx, __shfl_xor(mx, 16));
    mx = fmaxf(mx, __shfl_xor(mx, 32));
    float mnew = fmaxf(m_run, mx);
    float scale = __expf(m_run - mnew);
    float lsum = 0.f;
    bf16x8 pa[2];
#pragma unroll
    for (int s = 0; s < 2; ++s)
#pragma unroll
      for (int e = 0; e < 8; ++e) {
        float p = __expf(pv[s][e] - mnew);
        lsum += p;
        pa[s][e] = (bf16)p;
      }
    lsum += __shfl_xor(lsum, 16);
    lsum += __shfl_xor(lsum, 32);
    l_run = l_run * scale + lsum;
    m_run = mnew;
    float sc[4];
#pragma unroll
    for (int r = 0; r < 4; ++r) sc[r] = __shfl(scale, ko * 4 + r);
#pragma unroll
    for (int nf = 0; nf < 8; ++nf)
#pragma unroll
      for (int r = 0; r < 4; ++r) acc[nf][r] *= sc[r];
#pragma unroll
    for (int s = 0; s < 2; ++s) {
      int bj = j0 + s * 32 + ko * 8;
#pragma unroll
      for (int nf = 0; nf < 8; ++nf) {
        int d = nf * 16 + m;
        bf16x8 bv = *(const bf16x8*)&vT[((size_t)bh * HD_ + d) * S_ + bj];
        acc[nf] = __builtin_amdgcn_mfma_f32_16x16x32_bf16(pa[s], bv, acc[nf], 0, 0, 0);
      }
    }
  }

  if (ntile == 1) {                // iw<4 (only q==0): finalize directly
    float lr[4];
#pragma unroll
    for (int r = 0; r < 4; ++r) lr[r] = __shfl(l_run, ko * 4 + r);
#pragma unroll
    for (int nf = 0; nf < 8; ++nf) {
      int d = nf * 16 + m;
#pragma unroll
      for (int r = 0; r < 4; ++r) {
        int row = iw * 16 + ko * 4 + r;
        o[(((size_t)b * S_ + row) * H_ + h) * HD_ + d] = (bf16)(acc[nf][r] / lr[r]);
      }
    }
  } else {
    bf16* op = opart + ((size_t)(q * 16 + bh) * 64 + iw) * 2048;
#pragma unroll
    for (int nf = 0; nf < 8; ++nf) {
      int d = nf * 16 + m;
#pragma unroll
      for (int r = 0; r < 4; ++r) op[(ko * 4 + r) * 128 + d] = (bf16)acc[nf][r];
    }
    if (lane < 16) {
      float* mlp = mlpart + ((size_t)(q * 16 + bh) * 64 + iw) * 32;
      mlp[m * 2 + 0] = m_run;
      mlp[m * 2 + 1] = l_run;
    }
  }
}

// ---------------- combine up to 4 attention quarters (rows iw>=4) -----------
__global__ __launch_bounds__(256) void k_comb(const bf16* __restrict__ opart,
                                              const float* __restrict__ mlpart,
                                              bf16* __restrict__ o) {
  int blk = blockIdx.x;
  int bh = blk / 60, iw = blk % 60 + 4;
  int b = bh >> 3, h = bh & 7;
  int t = threadIdx.x;
  int r = t >> 4, d0 = (t & 15) * 8;
  int nq = iw / 4 + 1;
  if (nq > 4) nq = 4;
  float mq[4], lq[4];
  float mm = -INFINITY;
#pragma unroll
  for (int q = 0; q < 4; ++q) {
    if (q < nq) {
      size_t idx = (size_t)(q * 16 + bh) * 64 + iw;
      mq[q] = mlpart[idx * 32 + r * 2];
      lq[q] = mlpart[idx * 32 + r * 2 + 1];
      mm = fmaxf(mm, mq[q]);
    }
  }
  float L = 0.f;
  float acc[8] = {0.f, 0.f, 0.f, 0.f, 0.f, 0.f, 0.f, 0.f};
#pragma unroll
  for (int q = 0; q < 4; ++q) {
    if (q < nq) {
      float e = __expf(mq[q] - mm);
      L += lq[q] * e;
      size_t idx = (size_t)(q * 16 + bh) * 64 + iw;
      bf16x8 v = *(const bf16x8*)&opart[(idx * 16 + r) * 128 + d0];
#pragma unroll
      for (int k = 0; k < 8; ++k) acc[k] += (float)v[k] * e;
    }
  }
  float inv = 1.f / L;
  bf16x8 ov;
#pragma unroll
  for (int k = 0; k < 8; ++k) ov[k] = (bf16)(acc[k] * inv);
  int row = iw * 16 + r;
  *(bf16x8*)&o[(((size_t)b * S_ + row) * H_ + h) * HD_ + d0] = ov;
}

}  // namespace

extern "C" void kernel_launch(void* const* d_in, const int* in_sizes, int n_in,
                              void* d_out, int out_size, void* d_ws, size_t ws_size,
                              hipStream_t stream) {
  (void)in_sizes; (void)n_in; (void)out_size; (void)ws_size;
  const float* x       = (const float*)d_in[0];
  const float* v_w     = (const float*)d_in[1];
  const float* v_b     = (const float*)d_in[2];
  const float* out_w   = (const float*)d_in[3];
  const float* out_b   = (const float*)d_in[4];
  const float* qmod_w  = (const float*)d_in[5];
  const float* qmod_b  = (const float*)d_in[6];
  const float* kmod_w  = (const float*)d_in[7];
  const float* kmod_b  = (const float*)d_in[8];
  const float* gate_w1 = (const float*)d_in[9];
  const float* gate_b1 = (const float*)d_in[10];
  const float* gate_w2 = (const float*)d_in[11];
  const float* gate_b2 = (const float*)d_in[12];
  const float* mod_w1  = (const float*)d_in[13];
  const float* mod_b1  = (const float*)d_in[14];
  const float* mod_w2  = (const float*)d_in[15];
  const float* mod_b2  = (const float*)d_in[16];
  const float* mod_basis = (const float*)d_in[17];
  const float* freqs   = (const float*)d_in[18];
  const float* amps    = (const float*)d_in[19];
  const float* phases  = (const float*)d_in[20];
  const float* cwq     = (const float*)d_in[21];
  const float* cwk     = (const float*)d_in[22];
  const float* ffn_w1  = (const float*)d_in[23];
  const float* ffn_b1  = (const float*)d_in[24];
  const float* ffn_w2  = (const float*)d_in[25];
  const float* ffn_b2  = (const float*)d_in[26];
  const float* ln_ag   = (const float*)d_in[27];
  const float* ln_ab   = (const float*)d_in[28];
  const float* ln_fg   = (const float*)d_in[29];
  const float* ln_fb   = (const float*)d_in[30];

  char* wsc = (char*)d_ws;
  size_t off = 0;
  auto alloc = [&](size_t bytes) -> void* {
    void* p = wsc + off;
    off += (bytes + 255) & ~(size_t)255;
    return p;
  };
  float* pooled = (float*)alloc(2048 * 4);   // unused (kept for layout stability)
  float* part   = (float*)alloc(65536 * 4);
  float2* gpart = (float2*)alloc((size_t)2 * H_ * 16 * 128 * 8);
  float* wmod   = (float*)alloc(2048 * 4);
  float* kerns  = (float*)alloc((size_t)H_ * M_ * S_ * 4);
  float* swin   = (float*)alloc((size_t)B_ * H_ * S_ * 4);
  float* qsT    = (float*)alloc((size_t)B_ * H_ * S_ * 4);
  float* kmT    = (float*)alloc((size_t)B_ * H_ * S_ * 4);
  float* qcb    = (float*)alloc((size_t)B_ * H_ * S_ * R_ * 4);
  float* kcb    = (float*)alloc((size_t)B_ * H_ * S_ * R_ * 4);
  float* ybuf   = (float*)alloc((size_t)B_ * S_ * E_ * 4);       // 8MB (post-LN y)
  bf16* xb      = (bf16*)alloc((size_t)B_ * S_ * E_ * 2);
  bf16* yb      = (bf16*)alloc((size_t)B_ * S_ * E_ * 2);
  bf16* vwT     = (bf16*)alloc((size_t)E_ * E_ * 2);
  bf16* outwT   = (bf16*)alloc((size_t)E_ * E_ * 2);
  bf16* ffn1T   = (bf16*)alloc((size_t)E_ * FFNH_ * 2);
  bf16* ffn2T   = (bf16*)alloc((size_t)FFNH_ * E_ * 2);
  bf16* wcatT   = (bf16*)alloc((size_t)256 * E_ * 2);            // 0.5MB
  bf16* vT      = (bf16*)alloc((size_t)B_ * S_ * E_ * 2);        // v [b,hd,s]
  bf16* ob      = (bf16*)alloc((size_t)B_ * S_ * E_ * 2);        // attn out
  float* mlpart = (float*)alloc((size_t)4 * 16 * 64 * 16 * 2 * 4);
  char* poolU2  = (char*)alloc((size_t)B_ * S_ * FFNH_ * 2);     // 16MB union
  bf16* opart = (bf16*)poolU2;     // 16MB (attn phase)
  bf16* hb    = (bf16*)poolU2;     // 16MB (FFN phase)
  // P1: 64MB union. fp16 partials: qk [0,8MB); v [0,16MB); out [0,16MB);
  // ffn2 [0,16MB). cont (32MB bf16) at [16MB,48MB) until attn2 completes.
  char* P1c = (char*)alloc((size_t)64 * 1024 * 1024);
  f16*  P1  = (f16*)P1c;
  bf16* cont = (bf16*)(P1c + (size_t)16 * 1024 * 1024);
  (void)pooled;

  float* outp = (float*)d_out;
  const int BS = B_ * S_;

  // fused prep: cvt + 4x transpose + wcat + pool partials + wave synthesis
  k_prep<<<17472, 256, 0, stream>>>(x, xb, v_w, vwT, out_w, outwT,
                                    ffn_w1, ffn1T, ffn_w2, ffn2T,
                                    qmod_w, kmod_w, cwq, cwk, wcatT,
                                    part, freqs, amps, phases, kerns);

  // scores pipeline (gate1 reduces pooled in-kernel from part)
  k_gate1<<<dim3(16, H_, 2), 256, 0, stream>>>(part, gate_w1, mod_w1, gpart);
  k_gate2<<<B_ * H_, 256, 0, stream>>>(gpart, gate_b1, gate_w2, gate_b2,
                                       mod_b1, mod_w2, mod_b2, mod_basis, wmod);

  // qs/km/qc/kc via one MFMA GEMM: [xb (2048x1024)] @ WcatT^T -> 2048x256
  k_gemm_sk<1><<<dim3(2, 16, 8), 256, 0, stream>>>(
      xb, wcatT, P1, 256, E_, 128, 0, (size_t)2048 * 256);
  k_fin_qk<<<2048, 256, 0, stream>>>(P1, qmod_b, kmod_b, qsT, kmT, qcb, kcb);

  // content logits precompute (lower-tri 128-tiles) + swin at z==16
  k_cont<<<dim3(8, 8, 17), 256, 0, stream>>>(qcb, kcb, cont, wmod, kerns, swin);

  // vT[b][hd][s] = vwT x xb^T, split-K=4 x batch2, fp16 partials
  k_gemm_sk<2><<<dim3(8, 8, 8), 256, 0, stream>>>(
      vwT, xb, P1, S_, E_, 256, (size_t)S_ * E_, (size_t)1024 * 1024);
  k_fin_vT<<<2048, 256, 0, stream>>>(P1, v_b, vT);

  k_attn2<<<dim3(64, 16), 256, 0, stream>>>(qsT, kmT, cont, swin, vT, ob, opart, mlpart);
  k_comb<<<16 * 60, 256, 0, stream>>>(opart, mlpart, ob);

  // y = LN(o @ out_w + out_b + x)  (split-K=4, fused fin+LN -> ybuf fp32 + yb bf16)
  k_gemm_sk<1><<<dim3(8, 16, 4), 256, 0, stream>>>(
      ob, outwT, P1, E_, E_, 256, 0, (size_t)2048 * 1024);
  k_fin_ln<4, true><<<2048, 256, 0, stream>>>(P1, out_b, x, ln_ag, ln_ab, ybuf, yb);

  // h = gelu(y @ ffn_w1 + b1)  (fused epilogue, no partial round-trip)
  k_gemm_mfma<true, false, false, true><<<dim3(FFNH_ / 128, BS / 128), 256, 0, stream>>>(
      yb, ffn1T, ffn_b1, nullptr, nullptr, hb, FFNH_, E_);

  // out = LN(h @ ffn_w2 + b2 + y)  (split-K=4, fused fin+LN -> outp)
  k_gemm_sk<1><<<dim3(8, 16, 4), 256, 0, stream>>>(
      hb, ffn2T, P1, E_, FFNH_, 1024, 0, (size_t)2048 * 1024);
  k_fin_ln<4, false><<<2048, 256, 0, stream>>>(P1, ffn_b2, ybuf, ln_fg, ln_fb, outp, nullptr);
}

// Round 18
// 228.183 us; speedup vs baseline: 1.5056x; 1.0363x over previous
//
#include <hip/hip_runtime.h>
#include <math.h>
#include <stdint.h>

namespace {

constexpr int B_ = 2, S_ = 1024, E_ = 1024, H_ = 8, HD_ = 128;
constexpr int M_ = 128, W_ = 32, GH_ = 128, R_ = 8, MR_ = 8, FFNH_ = 4096;
constexpr int SCH = 32;            // s-chunks for pooling
constexpr int SPC = S_ / SCH;      // 32 rows per chunk

typedef __bf16 bf16;
typedef _Float16 f16;
typedef __attribute__((ext_vector_type(8))) __bf16 bf16x8;
typedef __attribute__((ext_vector_type(4))) __bf16 bf16x4;
typedef __attribute__((ext_vector_type(4))) _Float16 f16x4;
typedef __attribute__((ext_vector_type(4))) float f32x4;

__device__ inline float gelu_tanh(float u) {
  float u3 = u * u * u;
  return 0.5f * u * (1.f + tanhf(0.7978845608028654f * (u + 0.044715f * u3)));
}

__device__ __forceinline__ void gl_lds16(const void* g, void* l) {
  __builtin_amdgcn_global_load_lds((const __attribute__((address_space(1))) void*)g,
                                   (__attribute__((address_space(3))) void*)l, 16, 0, 0);
}

// ---------------- shared split-K GEMM body (BK=64), lin pre-swizzled --------
template <int NB>
__device__ __forceinline__ void gemm_body(
    const bf16* __restrict__ A, const bf16* __restrict__ BT,
    f16* __restrict__ P, int N, int K, int Kslice, size_t strideB, size_t mn,
    int lin, int gx, int gy, bf16* Asb, bf16* Bsb) {
  int t = threadIdx.x;
  int by = lin % gy;
  int rem = lin / gy;
  int bx = rem % gx;
  int z = rem / gx;
  int bb = z % NB;
  int k0 = (z / NB) * Kslice;
  const bf16* Bbase = BT + (size_t)bb * strideB;
  int row0 = by * 128, col0 = bx * 128;
  int lane = t & 63, wid = t >> 6;
  int wr = wid >> 1, wc = wid & 1;

  const bf16* AgP[4];
  const bf16* BgP[4];
  int ldo[4];
#pragma unroll
  for (int j = 0; j < 4; ++j) {
    int p = t + j * 256;
    int sub = p >> 9;
    int pp = p & 511;
    int rt = ((pp >> 6) << 4) | (pp & 15);
    int kb = (pp >> 4) & 3;
    AgP[j] = A + (size_t)(row0 + rt) * K + k0 + sub * 32 + kb * 8;
    BgP[j] = Bbase + (size_t)(col0 + rt) * K + k0 + sub * 32 + kb * 8;
    ldo[j] = sub * 4096 + pp * 8;
  }

  f32x4 acc[4][4];
#pragma unroll
  for (int m = 0; m < 4; ++m)
#pragma unroll
    for (int n = 0; n < 4; ++n) acc[m][n] = (f32x4){0.f, 0.f, 0.f, 0.f};

#pragma unroll
  for (int j = 0; j < 4; ++j) {
    gl_lds16(AgP[j], &Asb[ldo[j]]);
    gl_lds16(BgP[j], &Bsb[ldo[j]]);
  }

  const int nt = Kslice >> 6;
  for (int kt = 0; kt < nt; ++kt) {
    int cur = kt & 1;
    __syncthreads();
    if (kt + 1 < nt) {
      size_t go = (size_t)(kt + 1) * 64;
      int nb = cur ^ 1;
#pragma unroll
      for (int j = 0; j < 4; ++j) {
        gl_lds16(AgP[j] + go, &Asb[nb * 8192 + ldo[j]]);
        gl_lds16(BgP[j] + go, &Bsb[nb * 8192 + ldo[j]]);
      }
    }
#pragma unroll
    for (int kk = 0; kk < 2; ++kk) {
      bf16x8 af[4], bfr[4];
#pragma unroll
      for (int m = 0; m < 4; ++m)
        af[m] = *(const bf16x8*)&Asb[cur * 8192 + kk * 4096 + ((wr * 4 + m) * 64 + lane) * 8];
#pragma unroll
      for (int n = 0; n < 4; ++n)
        bfr[n] = *(const bf16x8*)&Bsb[cur * 8192 + kk * 4096 + ((wc * 4 + n) * 64 + lane) * 8];
#pragma unroll
      for (int m = 0; m < 4; ++m)
#pragma unroll
        for (int n = 0; n < 4; ++n)
          acc[m][n] = __builtin_amdgcn_mfma_f32_16x16x32_bf16(af[m], bfr[n], acc[m][n], 0, 0, 0);
    }
  }

  f16* Pz = P + (size_t)z * mn;
  int r0 = row0 + wr * 64, c0 = col0 + wc * 64;
#pragma unroll
  for (int m = 0; m < 4; ++m)
#pragma unroll
    for (int n = 0; n < 4; ++n) {
      int col = c0 + n * 16 + (lane & 15);
#pragma unroll
      for (int reg = 0; reg < 4; ++reg) {
        int row = r0 + m * 16 + ((lane >> 4) << 2) + reg;
        Pz[(size_t)row * N + col] = (f16)acc[m][n][reg];
      }
    }
}

// ---------------- fused prep: cvt + 4x transpose + wcat + pool + waves ------
__global__ __launch_bounds__(256) void k_prep(
    const float* __restrict__ x, bf16* __restrict__ xb,
    const float* __restrict__ v_w, bf16* __restrict__ vwT,
    const float* __restrict__ out_w, bf16* __restrict__ outwT,
    const float* __restrict__ ffn_w1, bf16* __restrict__ ffn1T,
    const float* __restrict__ ffn_w2, bf16* __restrict__ ffn2T,
    const float* __restrict__ qmw, const float* __restrict__ kmw,
    const float* __restrict__ cwq, const float* __restrict__ cwk,
    bf16* __restrict__ wcat, float* __restrict__ part,
    const float* __restrict__ freqs, const float* __restrict__ amps,
    const float* __restrict__ phases, float* __restrict__ kerns) {
  __shared__ float tile[32][33];
  __shared__ float f0[W_], f1[W_], am[W_], ph[W_];
  int b = blockIdx.x, t = threadIdx.x;
  if (b < 2048) {                  // fp32 -> bf16 elementwise (x)
    size_t i = ((size_t)b * 256 + t) * 4;
    float4 v = *(const float4*)(x + i);
    bf16x4 o;
    o.x = (bf16)v.x; o.y = (bf16)v.y; o.z = (bf16)v.z; o.w = (bf16)v.w;
    *(bf16x4*)(xb + i) = o;
    return;
  }
  if (b < 12288) {                 // weight (K,N) fp32 -> (N,K) bf16 transpose
    const float* w; bf16* wT; int K, N, bx, by;
    if (b < 3072) {
      w = v_w; wT = vwT; K = 1024; N = 1024;
      int l = b - 2048; bx = l & 31; by = l >> 5;
    } else if (b < 4096) {
      w = out_w; wT = outwT; K = 1024; N = 1024;
      int l = b - 3072; bx = l & 31; by = l >> 5;
    } else if (b < 8192) {
      w = ffn_w1; wT = ffn1T; K = 1024; N = 4096;
      int l = b - 4096; bx = l & 127; by = l >> 7;
    } else {
      w = ffn_w2; wT = ffn2T; K = 4096; N = 1024;
      int l = b - 8192; bx = l & 31; by = l >> 5;
    }
    int n0 = bx * 32, k0 = by * 32;
    int tx = t & 31, ty = t >> 5;
    for (int r = ty; r < 32; r += 8) tile[r][tx] = w[(size_t)(k0 + r) * N + n0 + tx];
    __syncthreads();
    for (int r = ty; r < 32; r += 8) wT[(size_t)(n0 + r) * K + k0 + tx] = (bf16)tile[tx][r];
    return;
  }
  if (b < 13312) {                 // Wcat^T (256 x 1024)
    int idx = (b - 12288) * 256 + t;
    int n = idx >> 10, k = idx & 1023;
    float v = 0.f;
    if (n < 8) {
      v = qmw[k * 8 + n];
    } else if (n < 16) {
      v = kmw[k * 8 + (n - 8)];
    } else if (n < 80) {
      int u = n - 16, h = u >> 3, r = u & 7;
      int kk = k - h * 128;
      if (kk >= 0 && kk < 128) v = cwq[((size_t)h * 128 + kk) * 8 + r];
    } else if (n < 144) {
      int u = n - 80, h = u >> 3, r = u & 7;
      int kk = k - h * 128;
      if (kk >= 0 && kk < 128) v = cwk[((size_t)h * 128 + kk) * 8 + r];
    }
    wcat[idx] = (bf16)v;
    return;
  }
  if (b < 13376) {                 // pool partials
    int b0 = b - 13312;
    int bb = b0 / SCH, c = b0 % SCH;
    const float* xp = x + (size_t)bb * S_ * E_ + (size_t)c * SPC * E_;
    float acc[4] = {0.f, 0.f, 0.f, 0.f};
    for (int s = 0; s < SPC; ++s) {
      const float* row = xp + (size_t)s * E_;
#pragma unroll
      for (int q = 0; q < 4; ++q) acc[q] += row[t + q * 256];
    }
    float* pp = part + (size_t)b0 * E_;
#pragma unroll
    for (int q = 0; q < 4; ++q) pp[t + q * 256] = acc[q];
    return;
  }
  {                                // waves
    int blk = b - 13376;
    int lt = blk & 3;
    int hm = blk >> 2;
    if (t < W_) {
      f0[t] = freqs[((size_t)hm * W_ + t) * 2 + 0];
      f1[t] = freqs[((size_t)hm * W_ + t) * 2 + 1];
      am[t] = amps[(size_t)hm * W_ + t];
      ph[t] = phases[(size_t)hm * W_ + t];
    }
    __syncthreads();
    int l = lt * 256 + t;
    float rel = (float)(l - (S_ - 1));
    float p1 = rel * (1.0f / S_);
    float p2 = (rel < 0.f) ? (-sqrtf(-rel + 1e-6f) * (1.0f / 32.0f)) : 0.f;
    const float TWO_PI = 6.28318530717958647692f;
    float acc = 0.f;
#pragma unroll
    for (int w = 0; w < W_; ++w)
      acc += am[w] * __sinf(TWO_PI * (f0[w] * p1 + f1[w] * p2) + ph[w]);
    kerns[(size_t)hm * S_ + l] = acc;
  }
}

// ---------------- fused: qk GEMM (blocks 0..255) || gate1 (256..511) --------
__global__ __launch_bounds__(256) void k_qkg(
    const bf16* __restrict__ xb, const bf16* __restrict__ wcatT,
    f16* __restrict__ P,
    const float* __restrict__ part,
    const float* __restrict__ gw1, const float* __restrict__ mw1,
    float2* __restrict__ gpart) {
  __shared__ bf16 Asb[2 * 8192];
  __shared__ bf16 Bsb[2 * 8192];
  __shared__ float spool[2][64];
  __shared__ float red[2][2][128];
  int b = blockIdx.x, t = threadIdx.x;
  if (b < 256) {                   // qk GEMM: grid(2,16,8), nwg=256, cpx=32
    int lin = (b & 7) * 32 + (b >> 3);
    gemm_body<1>(xb, wcatT, P, 256, E_, 128, 0, (size_t)2048 * 256,
                 lin, 2, 16, Asb, Bsb);
    return;
  }
  // gate1 (pooled computed in-kernel from part)
  int b0 = b - 256;
  int chunk = b0 & 15, h = (b0 >> 4) & 7, mat = b0 >> 7;
  const float* w = mat ? mw1 : gw1;
  if (t < 128) {
    int bb = t >> 6;
    int e = chunk * 64 + (t & 63);
    float s = 0.f;
    for (int c = 0; c < SCH; ++c) s += part[(size_t)(bb * SCH + c) * E_ + e];
    spool[bb][t & 63] = s * (1.0f / S_);
  }
  __syncthreads();
  int g = t & 127, half = t >> 7;
  int e0 = chunk * 64 + half * 32;
  const float* wp = w + (size_t)h * E_ * GH_ + (size_t)e0 * GH_ + g;
  float a0 = 0.f, a1 = 0.f;
#pragma unroll 8
  for (int r = 0; r < 32; ++r) {
    float wv = wp[(size_t)r * GH_];
    a0 += spool[0][half * 32 + r] * wv;
    a1 += spool[1][half * 32 + r] * wv;
  }
  red[half][0][g] = a0;
  red[half][1][g] = a1;
  __syncthreads();
  if (half == 0) {
    float2 o;
    o.x = red[0][0][g] + red[1][0][g];
    o.y = red[0][1][g] + red[1][1][g];
    gpart[(((size_t)mat * H_ + h) * 16 + chunk) * 128 + g] = o;
  }
}

// ---------------- fused: fin_qk (0..2047) || gate2 (2048..2063) -------------
__global__ __launch_bounds__(256) void k_fg2(
    const f16* __restrict__ P, const float* __restrict__ qmb,
    const float* __restrict__ kmb, float* __restrict__ qsT,
    float* __restrict__ kmT, float* __restrict__ qc, float* __restrict__ kc,
    const float2* __restrict__ gpart,
    const float* __restrict__ gb1, const float* __restrict__ gw2, const float* __restrict__ gb2,
    const float* __restrict__ mb1, const float* __restrict__ mw2, const float* __restrict__ mb2,
    const float* __restrict__ mbasis, float* __restrict__ wmod) {
  __shared__ float ghs[GH_], mhs[GH_], glog[M_], mrs[MR_];
  __shared__ float red2[2][128];
  __shared__ float rbuf[128];
  int blk = blockIdx.x, t = threadIdx.x;
  if (blk < 2048) {                // fin_qk
    if (t >= 144) return;
    int row = blk;
    int b = row >> 10, s = row & 1023;
    const size_t mn = (size_t)2048 * 256;
    float sum = 0.f;
#pragma unroll
    for (int z = 0; z < 8; ++z) sum += (float)P[(size_t)z * mn + (size_t)row * 256 + t];
    if (t < 8) {
      qsT[((size_t)(b * 8 + t)) * 1024 + s] = sum + qmb[t];
    } else if (t < 16) {
      kmT[((size_t)(b * 8 + t - 8)) * 1024 + s] = sum + kmb[t - 8];
    } else if (t < 80) {
      int u = t - 16, h = u >> 3, r = u & 7;
      qc[(((size_t)(b * 8 + h)) * 1024 + s) * 8 + r] = sum;
    } else {
      int u = t - 80, h = u >> 3, r = u & 7;
      kc[(((size_t)(b * 8 + h)) * 1024 + s) * 8 + r] = sum;
    }
    return;
  }
  // gate2
  int bh = blk - 2048;
  int b = bh >> 3, h = bh & 7;
  {
    int g = t & 127, mat = t >> 7;
    const float2* pp = gpart + ((size_t)mat * H_ + h) * 16 * 128 + g;
    float acc = 0.f;
#pragma unroll
    for (int c = 0; c < 16; ++c) {
      float2 v = pp[(size_t)c * 128];
      acc += b ? v.y : v.x;
    }
    acc += (mat ? mb1 : gb1)[h * GH_ + g];
    acc = fmaxf(acc, 0.f);
    if (mat == 0) ghs[g] = acc; else mhs[g] = acc;
  }
  __syncthreads();
  {
    int m = t & 127, half = t >> 7;
    float acc = 0.f;
    const float* wp = gw2 + (size_t)h * GH_ * M_ + m;
#pragma unroll 4
    for (int g = half * 64; g < half * 64 + 64; ++g)
      acc += ghs[g] * wp[(size_t)g * M_];
    red2[half][m] = acc;
  }
  __syncthreads();
  if (t < 128) glog[t] = red2[0][t] + red2[1][t] + gb2[h * M_ + t];
  if (t < 64) {
    int r = t & 7, seg = t >> 3;
    float acc = 0.f;
    const float* wp = mw2 + (size_t)h * GH_ * MR_ + r;
    for (int g = seg * 16; g < seg * 16 + 16; ++g) acc += mhs[g] * wp[(size_t)g * MR_];
    acc += __shfl_xor(acc, 8);
    acc += __shfl_xor(acc, 16);
    acc += __shfl_xor(acc, 32);
    if (t < 8) mrs[t] = acc + mb2[h * MR_ + t];
  }
  __syncthreads();
  if (t < 128) rbuf[t] = glog[t];
  __syncthreads();
  for (int off = 64; off >= 1; off >>= 1) {
    if (t < off) rbuf[t] = fmaxf(rbuf[t], rbuf[t + off]);
    __syncthreads();
  }
  float mx = rbuf[0];
  __syncthreads();
  float ev = 0.f;
  if (t < 128) ev = expf(glog[t] - mx);
  __syncthreads();
  if (t < 128) rbuf[t] = ev;
  __syncthreads();
  for (int off = 64; off >= 1; off >>= 1) {
    if (t < off) rbuf[t] += rbuf[t + off];
    __syncthreads();
  }
  float inv = 1.f / rbuf[0];
  if (t < 128) {
    float wsel = ev * inv;
    float md = 0.f;
#pragma unroll
    for (int r = 0; r < MR_; ++r) md += mrs[r] * mbasis[((size_t)h * MR_ + r) * M_ + t];
    wmod[bh * M_ + t] = wsel * (1.f + md);
  }
}

// ---------------- fused: cont+swin (0..1087) || v-GEMM (1088..1599) ---------
__global__ __launch_bounds__(256) void k_cv(
    const float* __restrict__ qc, const float* __restrict__ kc,
    bf16* __restrict__ cont,
    const float* __restrict__ wmod, const float* __restrict__ kerns,
    float* __restrict__ swin,
    const bf16* __restrict__ vwT, const bf16* __restrict__ xb,
    f16* __restrict__ P) {
  __shared__ bf16 Asb[2 * 8192];
  __shared__ bf16 Bsb[2 * 8192];
  __shared__ float wm[M_];
  int b = blockIdx.x, t = threadIdx.x;
  if (b >= 1088) {                 // v GEMM: grid(8,8,8) NB=2, nwg=512, cpx=64
    int l = b - 1088;
    int lin = (l & 7) * 64 + (l >> 3);
    gemm_body<2>(vwT, xb, P, S_, E_, 256, (size_t)S_ * E_, (size_t)1024 * 1024,
                 lin, 8, 8, Asb, Bsb);
    return;
  }
  int jt = b & 7, it = (b >> 3) & 7, bh = b >> 6;   // bh 0..16
  if (bh == 16) {                  // swin
    int blk = it * 8 + jt;
    int dt = blk & 3;
    int sbh = blk >> 2;
    int h = sbh & 7;
    if (t < M_) wm[t] = wmod[sbh * M_ + t];
    __syncthreads();
    int d = dt * 256 + t;
    int l = (S_ - 1) - d;
    float acc = 0.f;
    for (int m = 0; m < M_; ++m) acc += wm[m] * kerns[((size_t)h * M_ + m) * S_ + l];
    float dd = (float)d;
    float win = expf(-dd * dd * (1.0f / 131072.0f));
    swin[(size_t)sbh * S_ + d] = 3.0f * win * acc;
    return;
  }
  if (jt > it) return;
  int w = t >> 6, lane = t & 63;
  int ln = lane & 15, ko = lane >> 4;
  int i0 = it * 128 + w * 32;
  int j0 = jt * 128;

  bf16x8 av[2];
#pragma unroll
  for (int mi = 0; mi < 2; ++mi) {
    bf16x8 a;
#pragma unroll
    for (int k = 0; k < 8; ++k) a[k] = (bf16)0.f;
    if (ko == 0) {
      const float* qp = &qc[((size_t)bh * S_ + i0 + mi * 16 + ln) * 8];
      float4 q0 = *(const float4*)qp;
      float4 q1 = *(const float4*)(qp + 4);
      a[0] = (bf16)q0.x; a[1] = (bf16)q0.y; a[2] = (bf16)q0.z; a[3] = (bf16)q0.w;
      a[4] = (bf16)q1.x; a[5] = (bf16)q1.y; a[6] = (bf16)q1.z; a[7] = (bf16)q1.w;
    }
    av[mi] = a;
  }
  bf16x8 bv[8];
#pragma unroll
  for (int nb = 0; nb < 8; ++nb) {
    bf16x8 bb;
#pragma unroll
    for (int k = 0; k < 8; ++k) bb[k] = (bf16)0.f;
    if (ko == 0) {
      const float* kp = &kc[((size_t)bh * S_ + j0 + nb * 16 + ln) * 8];
      float4 k0 = *(const float4*)kp;
      float4 k1 = *(const float4*)(kp + 4);
      bb[0] = (bf16)k0.x; bb[1] = (bf16)k0.y; bb[2] = (bf16)k0.z; bb[3] = (bf16)k0.w;
      bb[4] = (bf16)k1.x; bb[5] = (bf16)k1.y; bb[6] = (bf16)k1.z; bb[7] = (bf16)k1.w;
    }
    bv[nb] = bb;
  }
  f32x4 acc[2][8];
#pragma unroll
  for (int mi = 0; mi < 2; ++mi)
#pragma unroll
    for (int nb = 0; nb < 8; ++nb) {
      acc[mi][nb] = (f32x4){0.f, 0.f, 0.f, 0.f};
      acc[mi][nb] = __builtin_amdgcn_mfma_f32_16x16x32_bf16(av[mi], bv[nb], acc[mi][nb], 0, 0, 0);
    }
  bf16* cb = cont + ((size_t)bh << 20);
#pragma unroll
  for (int mi = 0; mi < 2; ++mi)
#pragma unroll
    for (int nb = 0; nb < 8; ++nb) {
      int col = j0 + nb * 16 + ln;
#pragma unroll
      for (int reg = 0; reg < 4; ++reg) {
        int row = i0 + mi * 16 + ko * 4 + reg;
        cb[(size_t)row * S_ + col] = (bf16)acc[mi][nb][reg];
      }
    }
}

// ---------------- bf16 MFMA GEMM, BK=64, fused epilogue (FFN1), swizzled ----
template <bool GELU, bool RES, bool OUTF32, bool OUTBF16>
__global__ __launch_bounds__(256) void k_gemm_mfma(
    const bf16* __restrict__ A, const bf16* __restrict__ BT,
    const float* __restrict__ bias, const float* __restrict__ res,
    float* __restrict__ C, bf16* __restrict__ Cb, int N, int K) {
  __shared__ bf16 Asb[2][8192];
  __shared__ bf16 Bsb[2][8192];
  int t = threadIdx.x;
  int gx = gridDim.x, gy = gridDim.y;
  int nwg = gx * gy;
  int lin = blockIdx.y * gx + blockIdx.x;
  if (!(nwg & 7)) {
    int cpx = nwg >> 3;
    lin = (lin & 7) * cpx + (lin >> 3);
  }
  int by = lin % gy;
  int bx = lin / gy;
  int row0 = by * 128, col0 = bx * 128;
  int lane = t & 63, wid = t >> 6;
  int wr = wid >> 1, wc = wid & 1;

  const bf16* AgP[4];
  const bf16* BgP[4];
  int ldo[4];
#pragma unroll
  for (int j = 0; j < 4; ++j) {
    int p = t + j * 256;
    int sub = p >> 9;
    int pp = p & 511;
    int rt = ((pp >> 6) << 4) | (pp & 15);
    int kb = (pp >> 4) & 3;
    AgP[j] = A + (size_t)(row0 + rt) * K + sub * 32 + kb * 8;
    BgP[j] = BT + (size_t)(col0 + rt) * K + sub * 32 + kb * 8;
    ldo[j] = sub * 4096 + pp * 8;
  }

  f32x4 acc[4][4];
#pragma unroll
  for (int m = 0; m < 4; ++m)
#pragma unroll
    for (int n = 0; n < 4; ++n) acc[m][n] = (f32x4){0.f, 0.f, 0.f, 0.f};

#pragma unroll
  for (int j = 0; j < 4; ++j) {
    gl_lds16(AgP[j], &Asb[0][ldo[j]]);
    gl_lds16(BgP[j], &Bsb[0][ldo[j]]);
  }

  const int nt = K >> 6;
  for (int kt = 0; kt < nt; ++kt) {
    int cur = kt & 1;
    __syncthreads();
    if (kt + 1 < nt) {
      size_t go = (size_t)(kt + 1) * 64;
      int nb = cur ^ 1;
#pragma unroll
      for (int j = 0; j < 4; ++j) {
        gl_lds16(AgP[j] + go, &Asb[nb][ldo[j]]);
        gl_lds16(BgP[j] + go, &Bsb[nb][ldo[j]]);
      }
    }
#pragma unroll
    for (int kk = 0; kk < 2; ++kk) {
      bf16x8 af[4], bfr[4];
#pragma unroll
      for (int m = 0; m < 4; ++m)
        af[m] = *(const bf16x8*)&Asb[cur][kk * 4096 + ((wr * 4 + m) * 64 + lane) * 8];
#pragma unroll
      for (int n = 0; n < 4; ++n)
        bfr[n] = *(const bf16x8*)&Bsb[cur][kk * 4096 + ((wc * 4 + n) * 64 + lane) * 8];
#pragma unroll
      for (int m = 0; m < 4; ++m)
#pragma unroll
        for (int n = 0; n < 4; ++n)
          acc[m][n] = __builtin_amdgcn_mfma_f32_16x16x32_bf16(af[m], bfr[n], acc[m][n], 0, 0, 0);
    }
  }

  int r0 = row0 + wr * 64, c0 = col0 + wc * 64;
#pragma unroll
  for (int m = 0; m < 4; ++m) {
#pragma unroll
    for (int n = 0; n < 4; ++n) {
      int col = c0 + n * 16 + (lane & 15);
      float bcol = bias[col];
#pragma unroll
      for (int reg = 0; reg < 4; ++reg) {
        int row = r0 + m * 16 + ((lane >> 4) << 2) + reg;
        float u = acc[m][n][reg] + bcol;
        if (GELU) u = gelu_tanh(u);
        if (RES) u += res[(size_t)row * N + col];
        if (OUTF32) C[(size_t)row * N + col] = u;
        if (OUTBF16) Cb[(size_t)row * N + col] = (bf16)u;
      }
    }
  }
}

// ---------------- split-K bf16 MFMA GEMM, BK=64, swizzled (by-fastest) ------
template <int NB>
__global__ __launch_bounds__(256) void k_gemm_sk(
    const bf16* __restrict__ A, const bf16* __restrict__ BT,
    f16* __restrict__ P, int N, int K, int Kslice, size_t strideB, size_t mn) {
  __shared__ bf16 Asb[2 * 8192];
  __shared__ bf16 Bsb[2 * 8192];
  int gx = gridDim.x, gy = gridDim.y;
  int nwg = gx * gy * gridDim.z;
  int lin = (blockIdx.z * gy + blockIdx.y) * gx + blockIdx.x;
  if (!(nwg & 7)) {
    int cpx = nwg >> 3;
    lin = (lin & 7) * cpx + (lin >> 3);
  }
  gemm_body<NB>(A, BT, P, N, K, Kslice, strideB, mn, lin, gx, gy, Asb, Bsb);
}

// ---------------- combine: vT = sum_sk P + v_b (bf16 out, [b][hd][s]) -------
__global__ __launch_bounds__(256) void k_fin_vT(const f16* __restrict__ P,
                                                const float* __restrict__ bias,
                                                bf16* __restrict__ vT) {
  size_t i = ((size_t)blockIdx.x * 256 + threadIdx.x) * 4;
  const size_t mn = (size_t)1024 * 1024;
  float sx = 0.f, sy = 0.f, sz = 0.f, sw2 = 0.f;
#pragma unroll
  for (int sk = 0; sk < 4; ++sk) {
    f16x4 v = *(const f16x4*)&P[(size_t)sk * 2 * mn + i];
    sx += (float)v.x; sy += (float)v.y; sz += (float)v.z; sw2 += (float)v.w;
  }
  float bcol = bias[(i >> 10) & 1023];
  bf16x4 o;
  o.x = (bf16)(sx + bcol); o.y = (bf16)(sy + bcol);
  o.z = (bf16)(sz + bcol); o.w = (bf16)(sw2 + bcol);
  *(bf16x4*)&vT[i] = o;
}

// ---------------- fused fin+LayerNorm: u = sumP + bias + res; LN(u) ---------
template <int SK, bool OUTBF16>
__global__ __launch_bounds__(256) void k_fin_ln(
    const f16* __restrict__ P, const float* __restrict__ bias,
    const float* __restrict__ res, const float* __restrict__ g,
    const float* __restrict__ bb, float* __restrict__ outF,
    bf16* __restrict__ outB) {
  int row = blockIdx.x, t = threadIdx.x;
  size_t base = (size_t)row * E_ + t * 4;
  const size_t mn = (size_t)2048 * 1024;
  float u0 = 0.f, u1 = 0.f, u2 = 0.f, u3 = 0.f;
#pragma unroll
  for (int sk = 0; sk < SK; ++sk) {
    f16x4 v = *(const f16x4*)&P[(size_t)sk * mn + base];
    u0 += (float)v.x; u1 += (float)v.y; u2 += (float)v.z; u3 += (float)v.w;
  }
  float4 bv = *(const float4*)&bias[t * 4];
  float4 rv = *(const float4*)&res[base];
  u0 += bv.x + rv.x; u1 += bv.y + rv.y; u2 += bv.z + rv.z; u3 += bv.w + rv.w;
  float s = u0 + u1 + u2 + u3;
  float s2 = u0 * u0 + u1 * u1 + u2 * u2 + u3 * u3;
#pragma unroll
  for (int off = 32; off >= 1; off >>= 1) {
    s += __shfl_xor(s, off);
    s2 += __shfl_xor(s2, off);
  }
  __shared__ float rs[4], rs2[4];
  int wid = t >> 6;
  if ((t & 63) == 0) { rs[wid] = s; rs2[wid] = s2; }
  __syncthreads();
  float S1 = rs[0] + rs[1] + rs[2] + rs[3];
  float S2 = rs2[0] + rs2[1] + rs2[2] + rs2[3];
  float mu = S1 * (1.f / E_);
  float var = S2 * (1.f / E_) - mu * mu;
  float inv = rsqrtf(var + 1e-5f);
  float4 gv = *(const float4*)&g[t * 4];
  float4 bbv = *(const float4*)&bb[t * 4];
  float4 ov;
  ov.x = (u0 - mu) * inv * gv.x + bbv.x;
  ov.y = (u1 - mu) * inv * gv.y + bbv.y;
  ov.z = (u2 - mu) * inv * gv.z + bbv.z;
  ov.w = (u3 - mu) * inv * gv.w + bbv.w;
  *(float4*)&outF[base] = ov;
  if (OUTBF16) {
    bf16x4 obv;
    obv.x = (bf16)ov.x; obv.y = (bf16)ov.y; obv.z = (bf16)ov.z; obv.w = (bf16)ov.w;
    *(bf16x4*)&outB[base] = obv;
  }
}

// ---------------- MFMA flash attention (cont-based scores) ------------------
__global__ __launch_bounds__(256) void k_attn2(
    const float* __restrict__ qsT, const float* __restrict__ kmT,
    const bf16* __restrict__ cont, const float* __restrict__ swin,
    const bf16* __restrict__ vT,
    bf16* __restrict__ o, bf16* __restrict__ opart, float* __restrict__ mlpart) {
  int q = blockIdx.x & 3;
  int iwg = blockIdx.x >> 2;       // 0..15
  if (q > iwg) return;             // ntile = iwg+1; quarter q needs q < ntile
  int bh = blockIdx.y;
  int b = bh >> 3, h = bh & 7;
  int t = threadIdx.x;
  int wid = t >> 6, lane = t & 63;
  int iw = iwg * 4 + wid;          // 0..63
  int m = lane & 15, ko = lane >> 4;
  int ntile = iwg + 1;

  __shared__ float sw[S_];
  *(float4*)&sw[t * 4] = *(const float4*)&swin[(size_t)bh * S_ + t * 4];
  __syncthreads();

  int i_row = iw * 16 + m;
  float qs_i = qsT[(size_t)bh * S_ + i_row];
  const bf16* cr = cont + ((size_t)bh << 20) + (size_t)i_row * S_;

  f32x4 acc[8];
#pragma unroll
  for (int nf = 0; nf < 8; ++nf) acc[nf] = (f32x4){0.f, 0.f, 0.f, 0.f};
  float m_run = -INFINITY, l_run = 0.f;

  for (int jt = q; jt < ntile; jt += 4) {
    int j0 = jt * 64;
    float pv[2][8];
    float mx = -INFINITY;
    bf16x8 cv[2];
    cv[0] = *(const bf16x8*)&cr[j0 + ko * 8];
    cv[1] = *(const bf16x8*)&cr[j0 + 32 + ko * 8];
#pragma unroll
    for (int s = 0; s < 2; ++s) {
      int bj = j0 + s * 32 + ko * 8;
      float4 km0 = *(const float4*)&kmT[(size_t)bh * S_ + bj];
      float4 km1 = *(const float4*)&kmT[(size_t)bh * S_ + bj + 4];
      float kmv[8] = {km0.x, km0.y, km0.z, km0.w, km1.x, km1.y, km1.z, km1.w};
#pragma unroll
      for (int e = 0; e < 8; ++e) {
        int j = bj + e;
        int dd = i_row - j;
        float val = sw[dd >= 0 ? dd : 0] + qs_i + kmv[e] + 0.25f * (float)cv[s][e];
        val = (dd >= 0) ? val : -INFINITY;   // cndmask, branch-free
        pv[s][e] = val;
        mx = fmaxf(mx, val);
      }
    }
    mx = fmaxf(mx, __shfl_xor(mx, 16));
    mx = fmaxf(mx, __shfl_xor(mx, 32));
    float mnew = fmaxf(m_run, mx);
    float scale = __expf(m_run - mnew);
    float lsum = 0.f;
    bf16x8 pa[2];
#pragma unroll
    for (int s = 0; s < 2; ++s)
#pragma unroll
      for (int e = 0; e < 8; ++e) {
        float p = __expf(pv[s][e] - mnew);
        lsum += p;
        pa[s][e] = (bf16)p;
      }
    lsum += __shfl_xor(lsum, 16);
    lsum += __shfl_xor(lsum, 32);
    l_run = l_run * scale + lsum;
    m_run = mnew;
    float sc[4];
#pragma unroll
    for (int r = 0; r < 4; ++r) sc[r] = __shfl(scale, ko * 4 + r);
#pragma unroll
    for (int nf = 0; nf < 8; ++nf)
#pragma unroll
      for (int r = 0; r < 4; ++r) acc[nf][r] *= sc[r];
#pragma unroll
    for (int s = 0; s < 2; ++s) {
      int bj = j0 + s * 32 + ko * 8;
#pragma unroll
      for (int nf = 0; nf < 8; ++nf) {
        int d = nf * 16 + m;
        bf16x8 bv = *(const bf16x8*)&vT[((size_t)bh * HD_ + d) * S_ + bj];
        acc[nf] = __builtin_amdgcn_mfma_f32_16x16x32_bf16(pa[s], bv, acc[nf], 0, 0, 0);
      }
    }
  }

  if (ntile == 1) {                // iw<4 (only q==0): finalize directly
    float lr[4];
#pragma unroll
    for (int r = 0; r < 4; ++r) lr[r] = __shfl(l_run, ko * 4 + r);
#pragma unroll
    for (int nf = 0; nf < 8; ++nf) {
      int d = nf * 16 + m;
#pragma unroll
      for (int r = 0; r < 4; ++r) {
        int row = iw * 16 + ko * 4 + r;
        o[(((size_t)b * S_ + row) * H_ + h) * HD_ + d] = (bf16)(acc[nf][r] / lr[r]);
      }
    }
  } else {
    bf16* op = opart + ((size_t)(q * 16 + bh) * 64 + iw) * 2048;
#pragma unroll
    for (int nf = 0; nf < 8; ++nf) {
      int d = nf * 16 + m;
#pragma unroll
      for (int r = 0; r < 4; ++r) op[(ko * 4 + r) * 128 + d] = (bf16)acc[nf][r];
    }
    if (lane < 16) {
      float* mlp = mlpart + ((size_t)(q * 16 + bh) * 64 + iw) * 32;
      mlp[m * 2 + 0] = m_run;
      mlp[m * 2 + 1] = l_run;
    }
  }
}

// ---------------- combine up to 4 attention quarters (rows iw>=4) -----------
__global__ __launch_bounds__(256) void k_comb(const bf16* __restrict__ opart,
                                              const float* __restrict__ mlpart,
                                              bf16* __restrict__ o) {
  int blk = blockIdx.x;
  int bh = blk / 60, iw = blk % 60 + 4;
  int b = bh >> 3, h = bh & 7;
  int t = threadIdx.x;
  int r = t >> 4, d0 = (t & 15) * 8;
  int nq = iw / 4 + 1;
  if (nq > 4) nq = 4;
  float mq[4], lq[4];
  float mm = -INFINITY;
#pragma unroll
  for (int q = 0; q < 4; ++q) {
    if (q < nq) {
      size_t idx = (size_t)(q * 16 + bh) * 64 + iw;
      mq[q] = mlpart[idx * 32 + r * 2];
      lq[q] = mlpart[idx * 32 + r * 2 + 1];
      mm = fmaxf(mm, mq[q]);
    }
  }
  float L = 0.f;
  float acc[8] = {0.f, 0.f, 0.f, 0.f, 0.f, 0.f, 0.f, 0.f};
#pragma unroll
  for (int q = 0; q < 4; ++q) {
    if (q < nq) {
      float e = __expf(mq[q] - mm);
      L += lq[q] * e;
      size_t idx = (size_t)(q * 16 + bh) * 64 + iw;
      bf16x8 v = *(const bf16x8*)&opart[(idx * 16 + r) * 128 + d0];
#pragma unroll
      for (int k = 0; k < 8; ++k) acc[k] += (float)v[k] * e;
    }
  }
  float inv = 1.f / L;
  bf16x8 ov;
#pragma unroll
  for (int k = 0; k < 8; ++k) ov[k] = (bf16)(acc[k] * inv);
  int row = iw * 16 + r;
  *(bf16x8*)&o[(((size_t)b * S_ + row) * H_ + h) * HD_ + d0] = ov;
}

}  // namespace

extern "C" void kernel_launch(void* const* d_in, const int* in_sizes, int n_in,
                              void* d_out, int out_size, void* d_ws, size_t ws_size,
                              hipStream_t stream) {
  (void)in_sizes; (void)n_in; (void)out_size; (void)ws_size;
  const float* x       = (const float*)d_in[0];
  const float* v_w     = (const float*)d_in[1];
  const float* v_b     = (const float*)d_in[2];
  const float* out_w   = (const float*)d_in[3];
  const float* out_b   = (const float*)d_in[4];
  const float* qmod_w  = (const float*)d_in[5];
  const float* qmod_b  = (const float*)d_in[6];
  const float* kmod_w  = (const float*)d_in[7];
  const float* kmod_b  = (const float*)d_in[8];
  const float* gate_w1 = (const float*)d_in[9];
  const float* gate_b1 = (const float*)d_in[10];
  const float* gate_w2 = (const float*)d_in[11];
  const float* gate_b2 = (const float*)d_in[12];
  const float* mod_w1  = (const float*)d_in[13];
  const float* mod_b1  = (const float*)d_in[14];
  const float* mod_w2  = (const float*)d_in[15];
  const float* mod_b2  = (const float*)d_in[16];
  const float* mod_basis = (const float*)d_in[17];
  const float* freqs   = (const float*)d_in[18];
  const float* amps    = (const float*)d_in[19];
  const float* phases  = (const float*)d_in[20];
  const float* cwq     = (const float*)d_in[21];
  const float* cwk     = (const float*)d_in[22];
  const float* ffn_w1  = (const float*)d_in[23];
  const float* ffn_b1  = (const float*)d_in[24];
  const float* ffn_w2  = (const float*)d_in[25];
  const float* ffn_b2  = (const float*)d_in[26];
  const float* ln_ag   = (const float*)d_in[27];
  const float* ln_ab   = (const float*)d_in[28];
  const float* ln_fg   = (const float*)d_in[29];
  const float* ln_fb   = (const float*)d_in[30];

  char* wsc = (char*)d_ws;
  size_t off = 0;
  auto alloc = [&](size_t bytes) -> void* {
    void* p = wsc + off;
    off += (bytes + 255) & ~(size_t)255;
    return p;
  };
  float* pooled = (float*)alloc(2048 * 4);   // unused (layout stability)
  float* part   = (float*)alloc(65536 * 4);
  float2* gpart = (float2*)alloc((size_t)2 * H_ * 16 * 128 * 8);
  float* wmod   = (float*)alloc(2048 * 4);
  float* kerns  = (float*)alloc((size_t)H_ * M_ * S_ * 4);
  float* swin   = (float*)alloc((size_t)B_ * H_ * S_ * 4);
  float* qsT    = (float*)alloc((size_t)B_ * H_ * S_ * 4);
  float* kmT    = (float*)alloc((size_t)B_ * H_ * S_ * 4);
  float* qcb    = (float*)alloc((size_t)B_ * H_ * S_ * R_ * 4);
  float* kcb    = (float*)alloc((size_t)B_ * H_ * S_ * R_ * 4);
  float* ybuf   = (float*)alloc((size_t)B_ * S_ * E_ * 4);       // 8MB (post-LN y)
  bf16* xb      = (bf16*)alloc((size_t)B_ * S_ * E_ * 2);
  bf16* yb      = (bf16*)alloc((size_t)B_ * S_ * E_ * 2);
  bf16* vwT     = (bf16*)alloc((size_t)E_ * E_ * 2);
  bf16* outwT   = (bf16*)alloc((size_t)E_ * E_ * 2);
  bf16* ffn1T   = (bf16*)alloc((size_t)E_ * FFNH_ * 2);
  bf16* ffn2T   = (bf16*)alloc((size_t)FFNH_ * E_ * 2);
  bf16* wcatT   = (bf16*)alloc((size_t)256 * E_ * 2);            // 0.5MB
  bf16* vT      = (bf16*)alloc((size_t)B_ * S_ * E_ * 2);        // v [b,hd,s]
  bf16* ob      = (bf16*)alloc((size_t)B_ * S_ * E_ * 2);        // attn out
  float* mlpart = (float*)alloc((size_t)4 * 16 * 64 * 16 * 2 * 4);
  char* poolU2  = (char*)alloc((size_t)B_ * S_ * FFNH_ * 2);     // 16MB union
  bf16* opart = (bf16*)poolU2;     // 16MB (attn phase)
  bf16* hb    = (bf16*)poolU2;     // 16MB (FFN phase)
  // P1: 64MB union. fp16 partials: qk [0,8MB); v [0,16MB); out [0,16MB);
  // ffn2 [0,16MB). cont (32MB bf16) at [16MB,48MB) until attn2 completes.
  char* P1c = (char*)alloc((size_t)64 * 1024 * 1024);
  f16*  P1  = (f16*)P1c;
  bf16* cont = (bf16*)(P1c + (size_t)16 * 1024 * 1024);
  (void)pooled;

  float* outp = (float*)d_out;
  const int BS = B_ * S_;

  // fused prep: cvt + 4x transpose + wcat + pool partials + wave synthesis
  k_prep<<<17472, 256, 0, stream>>>(x, xb, v_w, vwT, out_w, outwT,
                                    ffn_w1, ffn1T, ffn_w2, ffn2T,
                                    qmod_w, kmod_w, cwq, cwk, wcatT,
                                    part, freqs, amps, phases, kerns);

  // qk GEMM || gate1
  k_qkg<<<512, 256, 0, stream>>>(xb, wcatT, P1, part, gate_w1, mod_w1, gpart);

  // fin_qk || gate2
  k_fg2<<<2064, 256, 0, stream>>>(P1, qmod_b, kmod_b, qsT, kmT, qcb, kcb,
                                  gpart, gate_b1, gate_w2, gate_b2,
                                  mod_b1, mod_w2, mod_b2, mod_basis, wmod);

  // cont+swin || v GEMM
  k_cv<<<1600, 256, 0, stream>>>(qcb, kcb, cont, wmod, kerns, swin,
                                 vwT, xb, P1);
  k_fin_vT<<<2048, 256, 0, stream>>>(P1, v_b, vT);

  k_attn2<<<dim3(64, 16), 256, 0, stream>>>(qsT, kmT, cont, swin, vT, ob, opart, mlpart);
  k_comb<<<16 * 60, 256, 0, stream>>>(opart, mlpart, ob);

  // y = LN(o @ out_w + out_b + x)  (split-K=4, fused fin+LN -> ybuf fp32 + yb bf16)
  k_gemm_sk<1><<<dim3(8, 16, 4), 256, 0, stream>>>(
      ob, outwT, P1, E_, E_, 256, 0, (size_t)2048 * 1024);
  k_fin_ln<4, true><<<2048, 256, 0, stream>>>(P1, out_b, x, ln_ag, ln_ab, ybuf, yb);

  // h = gelu(y @ ffn_w1 + b1)  (fused epilogue, no partial round-trip)
  k_gemm_mfma<true, false, false, true><<<dim3(FFNH_ / 128, BS / 128), 256, 0, stream>>>(
      yb, ffn1T, ffn_b1, nullptr, nullptr, hb, FFNH_, E_);

  // out = LN(h @ ffn_w2 + b2 + y)  (split-K=4, fused fin+LN -> outp)
  k_gemm_sk<1><<<dim3(8, 16, 4), 256, 0, stream>>>(
      hb, ffn2T, P1, E_, FFNH_, 1024, 0, (size_t)2048 * 1024);
  k_fin_ln<4, false><<<2048, 256, 0, stream>>>(P1, ffn_b2, ybuf, ln_fg, ln_fb, outp, nullptr);
}

// Round 19
// 222.973 us; speedup vs baseline: 1.5408x; 1.0234x over previous
//
#include <hip/hip_runtime.h>
#include <math.h>
#include <stdint.h>

namespace {

constexpr int B_ = 2, S_ = 1024, E_ = 1024, H_ = 8, HD_ = 128;
constexpr int M_ = 128, W_ = 32, GH_ = 128, R_ = 8, MR_ = 8, FFNH_ = 4096;
constexpr int SCH = 32;            // s-chunks for pooling
constexpr int SPC = S_ / SCH;      // 32 rows per chunk

typedef __bf16 bf16;
typedef _Float16 f16;
typedef __attribute__((ext_vector_type(8))) __bf16 bf16x8;
typedef __attribute__((ext_vector_type(4))) __bf16 bf16x4;
typedef __attribute__((ext_vector_type(4))) _Float16 f16x4;
typedef __attribute__((ext_vector_type(4))) float f32x4;

__device__ inline float gelu_tanh(float u) {
  float u3 = u * u * u;
  return 0.5f * u * (1.f + tanhf(0.7978845608028654f * (u + 0.044715f * u3)));
}

__device__ __forceinline__ void gl_lds16(const void* g, void* l) {
  __builtin_amdgcn_global_load_lds((const __attribute__((address_space(1))) void*)g,
                                   (__attribute__((address_space(3))) void*)l, 16, 0, 0);
}

// ---------------- shared split-K GEMM body (BK=64), lin pre-swizzled --------
template <int NB>
__device__ __forceinline__ void gemm_body(
    const bf16* __restrict__ A, const bf16* __restrict__ BT,
    f16* __restrict__ P, int N, int K, int Kslice, size_t strideB, size_t mn,
    int lin, int gx, int gy, bf16* Asb, bf16* Bsb) {
  int t = threadIdx.x;
  int by = lin % gy;
  int rem = lin / gy;
  int bx = rem % gx;
  int z = rem / gx;
  int bb = z % NB;
  int k0 = (z / NB) * Kslice;
  const bf16* Bbase = BT + (size_t)bb * strideB;
  int row0 = by * 128, col0 = bx * 128;
  int lane = t & 63, wid = t >> 6;
  int wr = wid >> 1, wc = wid & 1;

  const bf16* AgP[4];
  const bf16* BgP[4];
  int ldo[4];
#pragma unroll
  for (int j = 0; j < 4; ++j) {
    int p = t + j * 256;
    int sub = p >> 9;
    int pp = p & 511;
    int rt = ((pp >> 6) << 4) | (pp & 15);
    int kb = (pp >> 4) & 3;
    AgP[j] = A + (size_t)(row0 + rt) * K + k0 + sub * 32 + kb * 8;
    BgP[j] = Bbase + (size_t)(col0 + rt) * K + k0 + sub * 32 + kb * 8;
    ldo[j] = sub * 4096 + pp * 8;
  }

  f32x4 acc[4][4];
#pragma unroll
  for (int m = 0; m < 4; ++m)
#pragma unroll
    for (int n = 0; n < 4; ++n) acc[m][n] = (f32x4){0.f, 0.f, 0.f, 0.f};

#pragma unroll
  for (int j = 0; j < 4; ++j) {
    gl_lds16(AgP[j], &Asb[ldo[j]]);
    gl_lds16(BgP[j], &Bsb[ldo[j]]);
  }

  const int nt = Kslice >> 6;
  for (int kt = 0; kt < nt; ++kt) {
    int cur = kt & 1;
    __syncthreads();
    if (kt + 1 < nt) {
      size_t go = (size_t)(kt + 1) * 64;
      int nb = cur ^ 1;
#pragma unroll
      for (int j = 0; j < 4; ++j) {
        gl_lds16(AgP[j] + go, &Asb[nb * 8192 + ldo[j]]);
        gl_lds16(BgP[j] + go, &Bsb[nb * 8192 + ldo[j]]);
      }
    }
#pragma unroll
    for (int kk = 0; kk < 2; ++kk) {
      bf16x8 af[4], bfr[4];
#pragma unroll
      for (int m = 0; m < 4; ++m)
        af[m] = *(const bf16x8*)&Asb[cur * 8192 + kk * 4096 + ((wr * 4 + m) * 64 + lane) * 8];
#pragma unroll
      for (int n = 0; n < 4; ++n)
        bfr[n] = *(const bf16x8*)&Bsb[cur * 8192 + kk * 4096 + ((wc * 4 + n) * 64 + lane) * 8];
#pragma unroll
      for (int m = 0; m < 4; ++m)
#pragma unroll
        for (int n = 0; n < 4; ++n)
          acc[m][n] = __builtin_amdgcn_mfma_f32_16x16x32_bf16(af[m], bfr[n], acc[m][n], 0, 0, 0);
    }
  }

  f16* Pz = P + (size_t)z * mn;
  int r0 = row0 + wr * 64, c0 = col0 + wc * 64;
#pragma unroll
  for (int m = 0; m < 4; ++m)
#pragma unroll
    for (int n = 0; n < 4; ++n) {
      int col = c0 + n * 16 + (lane & 15);
#pragma unroll
      for (int reg = 0; reg < 4; ++reg) {
        int row = r0 + m * 16 + ((lane >> 4) << 2) + reg;
        Pz[(size_t)row * N + col] = (f16)acc[m][n][reg];
      }
    }
}

// ---------------- fused prep: cvt + 4x transpose + wcat + pool + waves ------
__global__ __launch_bounds__(256) void k_prep(
    const float* __restrict__ x, bf16* __restrict__ xb,
    const float* __restrict__ v_w, bf16* __restrict__ vwT,
    const float* __restrict__ out_w, bf16* __restrict__ outwT,
    const float* __restrict__ ffn_w1, bf16* __restrict__ ffn1T,
    const float* __restrict__ ffn_w2, bf16* __restrict__ ffn2T,
    const float* __restrict__ qmw, const float* __restrict__ kmw,
    const float* __restrict__ cwq, const float* __restrict__ cwk,
    bf16* __restrict__ wcat, float* __restrict__ part,
    const float* __restrict__ freqs, const float* __restrict__ amps,
    const float* __restrict__ phases, float* __restrict__ kerns) {
  __shared__ float tile[32][33];
  __shared__ float f0[W_], f1[W_], am[W_], ph[W_];
  int b = blockIdx.x, t = threadIdx.x;
  if (b < 2048) {                  // fp32 -> bf16 elementwise (x)
    size_t i = ((size_t)b * 256 + t) * 4;
    float4 v = *(const float4*)(x + i);
    bf16x4 o;
    o.x = (bf16)v.x; o.y = (bf16)v.y; o.z = (bf16)v.z; o.w = (bf16)v.w;
    *(bf16x4*)(xb + i) = o;
    return;
  }
  if (b < 12288) {                 // weight (K,N) fp32 -> (N,K) bf16 transpose
    const float* w; bf16* wT; int K, N, bx, by;
    if (b < 3072) {
      w = v_w; wT = vwT; K = 1024; N = 1024;
      int l = b - 2048; bx = l & 31; by = l >> 5;
    } else if (b < 4096) {
      w = out_w; wT = outwT; K = 1024; N = 1024;
      int l = b - 3072; bx = l & 31; by = l >> 5;
    } else if (b < 8192) {
      w = ffn_w1; wT = ffn1T; K = 1024; N = 4096;
      int l = b - 4096; bx = l & 127; by = l >> 7;
    } else {
      w = ffn_w2; wT = ffn2T; K = 4096; N = 1024;
      int l = b - 8192; bx = l & 31; by = l >> 5;
    }
    int n0 = bx * 32, k0 = by * 32;
    int tx = t & 31, ty = t >> 5;
    for (int r = ty; r < 32; r += 8) tile[r][tx] = w[(size_t)(k0 + r) * N + n0 + tx];
    __syncthreads();
    for (int r = ty; r < 32; r += 8) wT[(size_t)(n0 + r) * K + k0 + tx] = (bf16)tile[tx][r];
    return;
  }
  if (b < 13312) {                 // Wcat^T (256 x 1024)
    int idx = (b - 12288) * 256 + t;
    int n = idx >> 10, k = idx & 1023;
    float v = 0.f;
    if (n < 8) {
      v = qmw[k * 8 + n];
    } else if (n < 16) {
      v = kmw[k * 8 + (n - 8)];
    } else if (n < 80) {
      int u = n - 16, h = u >> 3, r = u & 7;
      int kk = k - h * 128;
      if (kk >= 0 && kk < 128) v = cwq[((size_t)h * 128 + kk) * 8 + r];
    } else if (n < 144) {
      int u = n - 80, h = u >> 3, r = u & 7;
      int kk = k - h * 128;
      if (kk >= 0 && kk < 128) v = cwk[((size_t)h * 128 + kk) * 8 + r];
    }
    wcat[idx] = (bf16)v;
    return;
  }
  if (b < 13376) {                 // pool partials
    int b0 = b - 13312;
    int bb = b0 / SCH, c = b0 % SCH;
    const float* xp = x + (size_t)bb * S_ * E_ + (size_t)c * SPC * E_;
    float acc[4] = {0.f, 0.f, 0.f, 0.f};
    for (int s = 0; s < SPC; ++s) {
      const float* row = xp + (size_t)s * E_;
#pragma unroll
      for (int q = 0; q < 4; ++q) acc[q] += row[t + q * 256];
    }
    float* pp = part + (size_t)b0 * E_;
#pragma unroll
    for (int q = 0; q < 4; ++q) pp[t + q * 256] = acc[q];
    return;
  }
  {                                // waves
    int blk = b - 13376;
    int lt = blk & 3;
    int hm = blk >> 2;
    if (t < W_) {
      f0[t] = freqs[((size_t)hm * W_ + t) * 2 + 0];
      f1[t] = freqs[((size_t)hm * W_ + t) * 2 + 1];
      am[t] = amps[(size_t)hm * W_ + t];
      ph[t] = phases[(size_t)hm * W_ + t];
    }
    __syncthreads();
    int l = lt * 256 + t;
    float rel = (float)(l - (S_ - 1));
    float p1 = rel * (1.0f / S_);
    float p2 = (rel < 0.f) ? (-sqrtf(-rel + 1e-6f) * (1.0f / 32.0f)) : 0.f;
    const float TWO_PI = 6.28318530717958647692f;
    float acc = 0.f;
#pragma unroll
    for (int w = 0; w < W_; ++w)
      acc += am[w] * __sinf(TWO_PI * (f0[w] * p1 + f1[w] * p2) + ph[w]);
    kerns[(size_t)hm * S_ + l] = acc;
  }
}

// -------- fused: qk GEMM (0..255) || gate1 (256..511) || v GEMM (512..1023) -
__global__ __launch_bounds__(256) void k_qv(
    const bf16* __restrict__ xb, const bf16* __restrict__ wcatT,
    f16* __restrict__ Pqk, f16* __restrict__ Pv,
    const bf16* __restrict__ vwT,
    const float* __restrict__ part,
    const float* __restrict__ gw1, const float* __restrict__ mw1,
    float2* __restrict__ gpart) {
  __shared__ bf16 Asb[2 * 8192];
  __shared__ bf16 Bsb[2 * 8192];
  __shared__ float spool[2][64];
  __shared__ float red[2][2][128];
  int b = blockIdx.x, t = threadIdx.x;
  if (b < 256) {                   // qk GEMM: grid(2,16,8), nwg=256, cpx=32
    int lin = (b & 7) * 32 + (b >> 3);
    gemm_body<1>(xb, wcatT, Pqk, 256, E_, 128, 0, (size_t)2048 * 256,
                 lin, 2, 16, Asb, Bsb);
    return;
  }
  if (b >= 512) {                  // v GEMM: grid(8,8,8) NB=2, nwg=512, cpx=64
    int l = b - 512;
    int lin = (l & 7) * 64 + (l >> 3);
    gemm_body<2>(vwT, xb, Pv, S_, E_, 256, (size_t)S_ * E_, (size_t)1024 * 1024,
                 lin, 8, 8, Asb, Bsb);
    return;
  }
  // gate1 (pooled computed in-kernel from part)
  int b0 = b - 256;
  int chunk = b0 & 15, h = (b0 >> 4) & 7, mat = b0 >> 7;
  const float* w = mat ? mw1 : gw1;
  if (t < 128) {
    int bb = t >> 6;
    int e = chunk * 64 + (t & 63);
    float s = 0.f;
    for (int c = 0; c < SCH; ++c) s += part[(size_t)(bb * SCH + c) * E_ + e];
    spool[bb][t & 63] = s * (1.0f / S_);
  }
  __syncthreads();
  int g = t & 127, half = t >> 7;
  int e0 = chunk * 64 + half * 32;
  const float* wp = w + (size_t)h * E_ * GH_ + (size_t)e0 * GH_ + g;
  float a0 = 0.f, a1 = 0.f;
#pragma unroll 8
  for (int r = 0; r < 32; ++r) {
    float wv = wp[(size_t)r * GH_];
    a0 += spool[0][half * 32 + r] * wv;
    a1 += spool[1][half * 32 + r] * wv;
  }
  red[half][0][g] = a0;
  red[half][1][g] = a1;
  __syncthreads();
  if (half == 0) {
    float2 o;
    o.x = red[0][0][g] + red[1][0][g];
    o.y = red[0][1][g] + red[1][1][g];
    gpart[(((size_t)mat * H_ + h) * 16 + chunk) * 128 + g] = o;
  }
}

// -- fused: fin_qk (0..2047) || gate2 (2048..2063) || fin_vT (2064..4111) ----
__global__ __launch_bounds__(256) void k_fg2v(
    const f16* __restrict__ Pqk, const float* __restrict__ qmb,
    const float* __restrict__ kmb, float* __restrict__ qsT,
    float* __restrict__ kmT, float* __restrict__ qc, float* __restrict__ kc,
    const float2* __restrict__ gpart,
    const float* __restrict__ gb1, const float* __restrict__ gw2, const float* __restrict__ gb2,
    const float* __restrict__ mb1, const float* __restrict__ mw2, const float* __restrict__ mb2,
    const float* __restrict__ mbasis, float* __restrict__ wmod,
    const f16* __restrict__ Pv, const float* __restrict__ v_b,
    bf16* __restrict__ vT) {
  __shared__ float ghs[GH_], mhs[GH_], glog[M_], mrs[MR_];
  __shared__ float red2[2][128];
  __shared__ float rbuf[128];
  int blk = blockIdx.x, t = threadIdx.x;
  if (blk < 2048) {                // fin_qk
    if (t >= 144) return;
    int row = blk;
    int b = row >> 10, s = row & 1023;
    const size_t mn = (size_t)2048 * 256;
    float sum = 0.f;
#pragma unroll
    for (int z = 0; z < 8; ++z) sum += (float)Pqk[(size_t)z * mn + (size_t)row * 256 + t];
    if (t < 8) {
      qsT[((size_t)(b * 8 + t)) * 1024 + s] = sum + qmb[t];
    } else if (t < 16) {
      kmT[((size_t)(b * 8 + t - 8)) * 1024 + s] = sum + kmb[t - 8];
    } else if (t < 80) {
      int u = t - 16, h = u >> 3, r = u & 7;
      qc[(((size_t)(b * 8 + h)) * 1024 + s) * 8 + r] = sum;
    } else {
      int u = t - 80, h = u >> 3, r = u & 7;
      kc[(((size_t)(b * 8 + h)) * 1024 + s) * 8 + r] = sum;
    }
    return;
  }
  if (blk >= 2064) {               // fin_vT
    size_t i = ((size_t)(blk - 2064) * 256 + t) * 4;
    const size_t mn = (size_t)1024 * 1024;
    float sx = 0.f, sy = 0.f, sz = 0.f, sw2 = 0.f;
#pragma unroll
    for (int sk = 0; sk < 4; ++sk) {
      f16x4 v = *(const f16x4*)&Pv[(size_t)sk * 2 * mn + i];
      sx += (float)v.x; sy += (float)v.y; sz += (float)v.z; sw2 += (float)v.w;
    }
    float bcol = v_b[(i >> 10) & 1023];
    bf16x4 o;
    o.x = (bf16)(sx + bcol); o.y = (bf16)(sy + bcol);
    o.z = (bf16)(sz + bcol); o.w = (bf16)(sw2 + bcol);
    *(bf16x4*)&vT[i] = o;
    return;
  }
  // gate2
  int bh = blk - 2048;
  int b = bh >> 3, h = bh & 7;
  {
    int g = t & 127, mat = t >> 7;
    const float2* pp = gpart + ((size_t)mat * H_ + h) * 16 * 128 + g;
    float acc = 0.f;
#pragma unroll
    for (int c = 0; c < 16; ++c) {
      float2 v = pp[(size_t)c * 128];
      acc += b ? v.y : v.x;
    }
    acc += (mat ? mb1 : gb1)[h * GH_ + g];
    acc = fmaxf(acc, 0.f);
    if (mat == 0) ghs[g] = acc; else mhs[g] = acc;
  }
  __syncthreads();
  {
    int m = t & 127, half = t >> 7;
    float acc = 0.f;
    const float* wp = gw2 + (size_t)h * GH_ * M_ + m;
#pragma unroll 4
    for (int g = half * 64; g < half * 64 + 64; ++g)
      acc += ghs[g] * wp[(size_t)g * M_];
    red2[half][m] = acc;
  }
  __syncthreads();
  if (t < 128) glog[t] = red2[0][t] + red2[1][t] + gb2[h * M_ + t];
  if (t < 64) {
    int r = t & 7, seg = t >> 3;
    float acc = 0.f;
    const float* wp = mw2 + (size_t)h * GH_ * MR_ + r;
    for (int g = seg * 16; g < seg * 16 + 16; ++g) acc += mhs[g] * wp[(size_t)g * MR_];
    acc += __shfl_xor(acc, 8);
    acc += __shfl_xor(acc, 16);
    acc += __shfl_xor(acc, 32);
    if (t < 8) mrs[t] = acc + mb2[h * MR_ + t];
  }
  __syncthreads();
  if (t < 128) rbuf[t] = glog[t];
  __syncthreads();
  for (int off = 64; off >= 1; off >>= 1) {
    if (t < off) rbuf[t] = fmaxf(rbuf[t], rbuf[t + off]);
    __syncthreads();
  }
  float mx = rbuf[0];
  __syncthreads();
  float ev = 0.f;
  if (t < 128) ev = expf(glog[t] - mx);
  __syncthreads();
  if (t < 128) rbuf[t] = ev;
  __syncthreads();
  for (int off = 64; off >= 1; off >>= 1) {
    if (t < off) rbuf[t] += rbuf[t + off];
    __syncthreads();
  }
  float inv = 1.f / rbuf[0];
  if (t < 128) {
    float wsel = ev * inv;
    float md = 0.f;
#pragma unroll
    for (int r = 0; r < MR_; ++r) md += mrs[r] * mbasis[((size_t)h * MR_ + r) * M_ + t];
    wmod[bh * M_ + t] = wsel * (1.f + md);
  }
}

// ---------------- cont (lower-tri 128-tiles, 0..1023) + swin (1024..1087) ---
__global__ __launch_bounds__(256) void k_cs(
    const float* __restrict__ qc, const float* __restrict__ kc,
    bf16* __restrict__ cont,
    const float* __restrict__ wmod, const float* __restrict__ kerns,
    float* __restrict__ swin) {
  __shared__ float wm[M_];
  int b = blockIdx.x, t = threadIdx.x;
  int jt = b & 7, it = (b >> 3) & 7, bh = b >> 6;   // bh 0..16
  if (bh == 16) {                  // swin
    int blk = it * 8 + jt;
    int dt = blk & 3;
    int sbh = blk >> 2;
    int h = sbh & 7;
    if (t < M_) wm[t] = wmod[sbh * M_ + t];
    __syncthreads();
    int d = dt * 256 + t;
    int l = (S_ - 1) - d;
    float acc = 0.f;
    for (int m = 0; m < M_; ++m) acc += wm[m] * kerns[((size_t)h * M_ + m) * S_ + l];
    float dd = (float)d;
    float win = expf(-dd * dd * (1.0f / 131072.0f));
    swin[(size_t)sbh * S_ + d] = 3.0f * win * acc;
    return;
  }
  if (jt > it) return;
  int w = t >> 6, lane = t & 63;
  int ln = lane & 15, ko = lane >> 4;
  int i0 = it * 128 + w * 32;
  int j0 = jt * 128;

  bf16x8 av[2];
#pragma unroll
  for (int mi = 0; mi < 2; ++mi) {
    bf16x8 a;
#pragma unroll
    for (int k = 0; k < 8; ++k) a[k] = (bf16)0.f;
    if (ko == 0) {
      const float* qp = &qc[((size_t)bh * S_ + i0 + mi * 16 + ln) * 8];
      float4 q0 = *(const float4*)qp;
      float4 q1 = *(const float4*)(qp + 4);
      a[0] = (bf16)q0.x; a[1] = (bf16)q0.y; a[2] = (bf16)q0.z; a[3] = (bf16)q0.w;
      a[4] = (bf16)q1.x; a[5] = (bf16)q1.y; a[6] = (bf16)q1.z; a[7] = (bf16)q1.w;
    }
    av[mi] = a;
  }
  bf16x8 bv[8];
#pragma unroll
  for (int nb = 0; nb < 8; ++nb) {
    bf16x8 bb;
#pragma unroll
    for (int k = 0; k < 8; ++k) bb[k] = (bf16)0.f;
    if (ko == 0) {
      const float* kp = &kc[((size_t)bh * S_ + j0 + nb * 16 + ln) * 8];
      float4 k0 = *(const float4*)kp;
      float4 k1 = *(const float4*)(kp + 4);
      bb[0] = (bf16)k0.x; bb[1] = (bf16)k0.y; bb[2] = (bf16)k0.z; bb[3] = (bf16)k0.w;
      bb[4] = (bf16)k1.x; bb[5] = (bf16)k1.y; bb[6] = (bf16)k1.z; bb[7] = (bf16)k1.w;
    }
    bv[nb] = bb;
  }
  f32x4 acc[2][8];
#pragma unroll
  for (int mi = 0; mi < 2; ++mi)
#pragma unroll
    for (int nb = 0; nb < 8; ++nb) {
      acc[mi][nb] = (f32x4){0.f, 0.f, 0.f, 0.f};
      acc[mi][nb] = __builtin_amdgcn_mfma_f32_16x16x32_bf16(av[mi], bv[nb], acc[mi][nb], 0, 0, 0);
    }
  bf16* cb = cont + ((size_t)bh << 20);
#pragma unroll
  for (int mi = 0; mi < 2; ++mi)
#pragma unroll
    for (int nb = 0; nb < 8; ++nb) {
      int col = j0 + nb * 16 + ln;
#pragma unroll
      for (int reg = 0; reg < 4; ++reg) {
        int row = i0 + mi * 16 + ko * 4 + reg;
        cb[(size_t)row * S_ + col] = (bf16)acc[mi][nb][reg];
      }
    }
}

// ---------------- bf16 MFMA GEMM, BK=64, fused epilogue (FFN1), swizzled ----
template <bool GELU, bool RES, bool OUTF32, bool OUTBF16>
__global__ __launch_bounds__(256) void k_gemm_mfma(
    const bf16* __restrict__ A, const bf16* __restrict__ BT,
    const float* __restrict__ bias, const float* __restrict__ res,
    float* __restrict__ C, bf16* __restrict__ Cb, int N, int K) {
  __shared__ bf16 Asb[2][8192];
  __shared__ bf16 Bsb[2][8192];
  int t = threadIdx.x;
  int gx = gridDim.x, gy = gridDim.y;
  int nwg = gx * gy;
  int lin = blockIdx.y * gx + blockIdx.x;
  if (!(nwg & 7)) {
    int cpx = nwg >> 3;
    lin = (lin & 7) * cpx + (lin >> 3);
  }
  int by = lin % gy;
  int bx = lin / gy;
  int row0 = by * 128, col0 = bx * 128;
  int lane = t & 63, wid = t >> 6;
  int wr = wid >> 1, wc = wid & 1;

  const bf16* AgP[4];
  const bf16* BgP[4];
  int ldo[4];
#pragma unroll
  for (int j = 0; j < 4; ++j) {
    int p = t + j * 256;
    int sub = p >> 9;
    int pp = p & 511;
    int rt = ((pp >> 6) << 4) | (pp & 15);
    int kb = (pp >> 4) & 3;
    AgP[j] = A + (size_t)(row0 + rt) * K + sub * 32 + kb * 8;
    BgP[j] = BT + (size_t)(col0 + rt) * K + sub * 32 + kb * 8;
    ldo[j] = sub * 4096 + pp * 8;
  }

  f32x4 acc[4][4];
#pragma unroll
  for (int m = 0; m < 4; ++m)
#pragma unroll
    for (int n = 0; n < 4; ++n) acc[m][n] = (f32x4){0.f, 0.f, 0.f, 0.f};

#pragma unroll
  for (int j = 0; j < 4; ++j) {
    gl_lds16(AgP[j], &Asb[0][ldo[j]]);
    gl_lds16(BgP[j], &Bsb[0][ldo[j]]);
  }

  const int nt = K >> 6;
  for (int kt = 0; kt < nt; ++kt) {
    int cur = kt & 1;
    __syncthreads();
    if (kt + 1 < nt) {
      size_t go = (size_t)(kt + 1) * 64;
      int nb = cur ^ 1;
#pragma unroll
      for (int j = 0; j < 4; ++j) {
        gl_lds16(AgP[j] + go, &Asb[nb][ldo[j]]);
        gl_lds16(BgP[j] + go, &Bsb[nb][ldo[j]]);
      }
    }
#pragma unroll
    for (int kk = 0; kk < 2; ++kk) {
      bf16x8 af[4], bfr[4];
#pragma unroll
      for (int m = 0; m < 4; ++m)
        af[m] = *(const bf16x8*)&Asb[cur][kk * 4096 + ((wr * 4 + m) * 64 + lane) * 8];
#pragma unroll
      for (int n = 0; n < 4; ++n)
        bfr[n] = *(const bf16x8*)&Bsb[cur][kk * 4096 + ((wc * 4 + n) * 64 + lane) * 8];
#pragma unroll
      for (int m = 0; m < 4; ++m)
#pragma unroll
        for (int n = 0; n < 4; ++n)
          acc[m][n] = __builtin_amdgcn_mfma_f32_16x16x32_bf16(af[m], bfr[n], acc[m][n], 0, 0, 0);
    }
  }

  int r0 = row0 + wr * 64, c0 = col0 + wc * 64;
#pragma unroll
  for (int m = 0; m < 4; ++m) {
#pragma unroll
    for (int n = 0; n < 4; ++n) {
      int col = c0 + n * 16 + (lane & 15);
      float bcol = bias[col];
#pragma unroll
      for (int reg = 0; reg < 4; ++reg) {
        int row = r0 + m * 16 + ((lane >> 4) << 2) + reg;
        float u = acc[m][n][reg] + bcol;
        if (GELU) u = gelu_tanh(u);
        if (RES) u += res[(size_t)row * N + col];
        if (OUTF32) C[(size_t)row * N + col] = u;
        if (OUTBF16) Cb[(size_t)row * N + col] = (bf16)u;
      }
    }
  }
}

// ---------------- split-K bf16 MFMA GEMM, BK=64, swizzled (by-fastest) ------
template <int NB>
__global__ __launch_bounds__(256) void k_gemm_sk(
    const bf16* __restrict__ A, const bf16* __restrict__ BT,
    f16* __restrict__ P, int N, int K, int Kslice, size_t strideB, size_t mn) {
  __shared__ bf16 Asb[2 * 8192];
  __shared__ bf16 Bsb[2 * 8192];
  int gx = gridDim.x, gy = gridDim.y;
  int nwg = gx * gy * gridDim.z;
  int lin = (blockIdx.z * gy + blockIdx.y) * gx + blockIdx.x;
  if (!(nwg & 7)) {
    int cpx = nwg >> 3;
    lin = (lin & 7) * cpx + (lin >> 3);
  }
  gemm_body<NB>(A, BT, P, N, K, Kslice, strideB, mn, lin, gx, gy, Asb, Bsb);
}

// ---------------- fused fin+LayerNorm: u = sumP + bias + res; LN(u) ---------
template <int SK, bool OUTBF16>
__global__ __launch_bounds__(256) void k_fin_ln(
    const f16* __restrict__ P, const float* __restrict__ bias,
    const float* __restrict__ res, const float* __restrict__ g,
    const float* __restrict__ bb, float* __restrict__ outF,
    bf16* __restrict__ outB) {
  int row = blockIdx.x, t = threadIdx.x;
  size_t base = (size_t)row * E_ + t * 4;
  const size_t mn = (size_t)2048 * 1024;
  float u0 = 0.f, u1 = 0.f, u2 = 0.f, u3 = 0.f;
#pragma unroll
  for (int sk = 0; sk < SK; ++sk) {
    f16x4 v = *(const f16x4*)&P[(size_t)sk * mn + base];
    u0 += (float)v.x; u1 += (float)v.y; u2 += (float)v.z; u3 += (float)v.w;
  }
  float4 bv = *(const float4*)&bias[t * 4];
  float4 rv = *(const float4*)&res[base];
  u0 += bv.x + rv.x; u1 += bv.y + rv.y; u2 += bv.z + rv.z; u3 += bv.w + rv.w;
  float s = u0 + u1 + u2 + u3;
  float s2 = u0 * u0 + u1 * u1 + u2 * u2 + u3 * u3;
#pragma unroll
  for (int off = 32; off >= 1; off >>= 1) {
    s += __shfl_xor(s, off);
    s2 += __shfl_xor(s2, off);
  }
  __shared__ float rs[4], rs2[4];
  int wid = t >> 6;
  if ((t & 63) == 0) { rs[wid] = s; rs2[wid] = s2; }
  __syncthreads();
  float S1 = rs[0] + rs[1] + rs[2] + rs[3];
  float S2 = rs2[0] + rs2[1] + rs2[2] + rs2[3];
  float mu = S1 * (1.f / E_);
  float var = S2 * (1.f / E_) - mu * mu;
  float inv = rsqrtf(var + 1e-5f);
  float4 gv = *(const float4*)&g[t * 4];
  float4 bbv = *(const float4*)&bb[t * 4];
  float4 ov;
  ov.x = (u0 - mu) * inv * gv.x + bbv.x;
  ov.y = (u1 - mu) * inv * gv.y + bbv.y;
  ov.z = (u2 - mu) * inv * gv.z + bbv.z;
  ov.w = (u3 - mu) * inv * gv.w + bbv.w;
  *(float4*)&outF[base] = ov;
  if (OUTBF16) {
    bf16x4 obv;
    obv.x = (bf16)ov.x; obv.y = (bf16)ov.y; obv.z = (bf16)ov.z; obv.w = (bf16)ov.w;
    *(bf16x4*)&outB[base] = obv;
  }
}

// ---------------- MFMA flash attention (cont-based scores) ------------------
__global__ __launch_bounds__(256) void k_attn2(
    const float* __restrict__ qsT, const float* __restrict__ kmT,
    const bf16* __restrict__ cont, const float* __restrict__ swin,
    const bf16* __restrict__ vT,
    bf16* __restrict__ o, bf16* __restrict__ opart, float* __restrict__ mlpart) {
  int q = blockIdx.x & 3;
  int iwg = blockIdx.x >> 2;       // 0..15
  if (q > iwg) return;             // ntile = iwg+1; quarter q needs q < ntile
  int bh = blockIdx.y;
  int b = bh >> 3, h = bh & 7;
  int t = threadIdx.x;
  int wid = t >> 6, lane = t & 63;
  int iw = iwg * 4 + wid;          // 0..63
  int m = lane & 15, ko = lane >> 4;
  int ntile = iwg + 1;

  __shared__ float sw[S_];
  *(float4*)&sw[t * 4] = *(const float4*)&swin[(size_t)bh * S_ + t * 4];
  __syncthreads();

  int i_row = iw * 16 + m;
  float qs_i = qsT[(size_t)bh * S_ + i_row];
  const bf16* cr = cont + ((size_t)bh << 20) + (size_t)i_row * S_;

  f32x4 acc[8];
#pragma unroll
  for (int nf = 0; nf < 8; ++nf) acc[nf] = (f32x4){0.f, 0.f, 0.f, 0.f};
  float m_run = -INFINITY, l_run = 0.f;

  for (int jt = q; jt < ntile; jt += 4) {
    int j0 = jt * 64;
    float pv[2][8];
    float mx = -INFINITY;
    bf16x8 cv[2];
    cv[0] = *(const bf16x8*)&cr[j0 + ko * 8];
    cv[1] = *(const bf16x8*)&cr[j0 + 32 + ko * 8];
#pragma unroll
    for (int s = 0; s < 2; ++s) {
      int bj = j0 + s * 32 + ko * 8;
      float4 km0 = *(const float4*)&kmT[(size_t)bh * S_ + bj];
      float4 km1 = *(const float4*)&kmT[(size_t)bh * S_ + bj + 4];
      float kmv[8] = {km0.x, km0.y, km0.z, km0.w, km1.x, km1.y, km1.z, km1.w};
#pragma unroll
      for (int e = 0; e < 8; ++e) {
        int j = bj + e;
        int dd = i_row - j;
        float val = sw[dd >= 0 ? dd : 0] + qs_i + kmv[e] + 0.25f * (float)cv[s][e];
        val = (dd >= 0) ? val : -INFINITY;   // cndmask, branch-free
        pv[s][e] = val;
        mx = fmaxf(mx, val);
      }
    }
    mx = fmaxf(mx, __shfl_xor(mx, 16));
    mx = fmaxf(mx, __shfl_xor(mx, 32));
    float mnew = fmaxf(m_run, mx);
    float scale = __expf(m_run - mnew);
    float lsum = 0.f;
    bf16x8 pa[2];
#pragma unroll
    for (int s = 0; s < 2; ++s)
#pragma unroll
      for (int e = 0; e < 8; ++e) {
        float p = __expf(pv[s][e] - mnew);
        lsum += p;
        pa[s][e] = (bf16)p;
      }
    lsum += __shfl_xor(lsum, 16);
    lsum += __shfl_xor(lsum, 32);
    l_run = l_run * scale + lsum;
    m_run = mnew;
    float sc[4];
#pragma unroll
    for (int r = 0; r < 4; ++r) sc[r] = __shfl(scale, ko * 4 + r);
#pragma unroll
    for (int nf = 0; nf < 8; ++nf)
#pragma unroll
      for (int r = 0; r < 4; ++r) acc[nf][r] *= sc[r];
#pragma unroll
    for (int s = 0; s < 2; ++s) {
      int bj = j0 + s * 32 + ko * 8;
#pragma unroll
      for (int nf = 0; nf < 8; ++nf) {
        int d = nf * 16 + m;
        bf16x8 bv = *(const bf16x8*)&vT[((size_t)bh * HD_ + d) * S_ + bj];
        acc[nf] = __builtin_amdgcn_mfma_f32_16x16x32_bf16(pa[s], bv, acc[nf], 0, 0, 0);
      }
    }
  }

  if (ntile == 1) {                // iw<4 (only q==0): finalize directly
    float lr[4];
#pragma unroll
    for (int r = 0; r < 4; ++r) lr[r] = __shfl(l_run, ko * 4 + r);
#pragma unroll
    for (int nf = 0; nf < 8; ++nf) {
      int d = nf * 16 + m;
#pragma unroll
      for (int r = 0; r < 4; ++r) {
        int row = iw * 16 + ko * 4 + r;
        o[(((size_t)b * S_ + row) * H_ + h) * HD_ + d] = (bf16)(acc[nf][r] / lr[r]);
      }
    }
  } else {
    bf16* op = opart + ((size_t)(q * 16 + bh) * 64 + iw) * 2048;
#pragma unroll
    for (int nf = 0; nf < 8; ++nf) {
      int d = nf * 16 + m;
#pragma unroll
      for (int r = 0; r < 4; ++r) op[(ko * 4 + r) * 128 + d] = (bf16)acc[nf][r];
    }
    if (lane < 16) {
      float* mlp = mlpart + ((size_t)(q * 16 + bh) * 64 + iw) * 32;
      mlp[m * 2 + 0] = m_run;
      mlp[m * 2 + 1] = l_run;
    }
  }
}

// ---------------- combine up to 4 attention quarters (rows iw>=4) -----------
__global__ __launch_bounds__(256) void k_comb(const bf16* __restrict__ opart,
                                              const float* __restrict__ mlpart,
                                              bf16* __restrict__ o) {
  int blk = blockIdx.x;
  int bh = blk / 60, iw = blk % 60 + 4;
  int b = bh >> 3, h = bh & 7;
  int t = threadIdx.x;
  int r = t >> 4, d0 = (t & 15) * 8;
  int nq = iw / 4 + 1;
  if (nq > 4) nq = 4;
  float mq[4], lq[4];
  float mm = -INFINITY;
#pragma unroll
  for (int q = 0; q < 4; ++q) {
    if (q < nq) {
      size_t idx = (size_t)(q * 16 + bh) * 64 + iw;
      mq[q] = mlpart[idx * 32 + r * 2];
      lq[q] = mlpart[idx * 32 + r * 2 + 1];
      mm = fmaxf(mm, mq[q]);
    }
  }
  float L = 0.f;
  float acc[8] = {0.f, 0.f, 0.f, 0.f, 0.f, 0.f, 0.f, 0.f};
#pragma unroll
  for (int q = 0; q < 4; ++q) {
    if (q < nq) {
      float e = __expf(mq[q] - mm);
      L += lq[q] * e;
      size_t idx = (size_t)(q * 16 + bh) * 64 + iw;
      bf16x8 v = *(const bf16x8*)&opart[(idx * 16 + r) * 128 + d0];
#pragma unroll
      for (int k = 0; k < 8; ++k) acc[k] += (float)v[k] * e;
    }
  }
  float inv = 1.f / L;
  bf16x8 ov;
#pragma unroll
  for (int k = 0; k < 8; ++k) ov[k] = (bf16)(acc[k] * inv);
  int row = iw * 16 + r;
  *(bf16x8*)&o[(((size_t)b * S_ + row) * H_ + h) * HD_ + d0] = ov;
}

}  // namespace

extern "C" void kernel_launch(void* const* d_in, const int* in_sizes, int n_in,
                              void* d_out, int out_size, void* d_ws, size_t ws_size,
                              hipStream_t stream) {
  (void)in_sizes; (void)n_in; (void)out_size; (void)ws_size;
  const float* x       = (const float*)d_in[0];
  const float* v_w     = (const float*)d_in[1];
  const float* v_b     = (const float*)d_in[2];
  const float* out_w   = (const float*)d_in[3];
  const float* out_b   = (const float*)d_in[4];
  const float* qmod_w  = (const float*)d_in[5];
  const float* qmod_b  = (const float*)d_in[6];
  const float* kmod_w  = (const float*)d_in[7];
  const float* kmod_b  = (const float*)d_in[8];
  const float* gate_w1 = (const float*)d_in[9];
  const float* gate_b1 = (const float*)d_in[10];
  const float* gate_w2 = (const float*)d_in[11];
  const float* gate_b2 = (const float*)d_in[12];
  const float* mod_w1  = (const float*)d_in[13];
  const float* mod_b1  = (const float*)d_in[14];
  const float* mod_w2  = (const float*)d_in[15];
  const float* mod_b2  = (const float*)d_in[16];
  const float* mod_basis = (const float*)d_in[17];
  const float* freqs   = (const float*)d_in[18];
  const float* amps    = (const float*)d_in[19];
  const float* phases  = (const float*)d_in[20];
  const float* cwq     = (const float*)d_in[21];
  const float* cwk     = (const float*)d_in[22];
  const float* ffn_w1  = (const float*)d_in[23];
  const float* ffn_b1  = (const float*)d_in[24];
  const float* ffn_w2  = (const float*)d_in[25];
  const float* ffn_b2  = (const float*)d_in[26];
  const float* ln_ag   = (const float*)d_in[27];
  const float* ln_ab   = (const float*)d_in[28];
  const float* ln_fg   = (const float*)d_in[29];
  const float* ln_fb   = (const float*)d_in[30];

  char* wsc = (char*)d_ws;
  size_t off = 0;
  auto alloc = [&](size_t bytes) -> void* {
    void* p = wsc + off;
    off += (bytes + 255) & ~(size_t)255;
    return p;
  };
  float* pooled = (float*)alloc(2048 * 4);   // unused (layout stability)
  float* part   = (float*)alloc(65536 * 4);
  float2* gpart = (float2*)alloc((size_t)2 * H_ * 16 * 128 * 8);
  float* wmod   = (float*)alloc(2048 * 4);
  float* kerns  = (float*)alloc((size_t)H_ * M_ * S_ * 4);
  float* swin   = (float*)alloc((size_t)B_ * H_ * S_ * 4);
  float* qsT    = (float*)alloc((size_t)B_ * H_ * S_ * 4);
  float* kmT    = (float*)alloc((size_t)B_ * H_ * S_ * 4);
  float* qcb    = (float*)alloc((size_t)B_ * H_ * S_ * R_ * 4);
  float* kcb    = (float*)alloc((size_t)B_ * H_ * S_ * R_ * 4);
  float* ybuf   = (float*)alloc((size_t)B_ * S_ * E_ * 4);       // 8MB (post-LN y)
  bf16* xb      = (bf16*)alloc((size_t)B_ * S_ * E_ * 2);
  bf16* yb      = (bf16*)alloc((size_t)B_ * S_ * E_ * 2);
  bf16* vwT     = (bf16*)alloc((size_t)E_ * E_ * 2);
  bf16* outwT   = (bf16*)alloc((size_t)E_ * E_ * 2);
  bf16* ffn1T   = (bf16*)alloc((size_t)E_ * FFNH_ * 2);
  bf16* ffn2T   = (bf16*)alloc((size_t)FFNH_ * E_ * 2);
  bf16* wcatT   = (bf16*)alloc((size_t)256 * E_ * 2);            // 0.5MB
  bf16* vT      = (bf16*)alloc((size_t)B_ * S_ * E_ * 2);        // v [b,hd,s]
  bf16* ob      = (bf16*)alloc((size_t)B_ * S_ * E_ * 2);        // attn out
  float* mlpart = (float*)alloc((size_t)4 * 16 * 64 * 16 * 2 * 4);
  char* poolU2  = (char*)alloc((size_t)B_ * S_ * FFNH_ * 2);     // 16MB union
  bf16* opart = (bf16*)poolU2;     // 16MB (attn phase)
  bf16* hb    = (bf16*)poolU2;     // 16MB (FFN phase)
  // P1: 64MB union. fp16 partials: qk [0,8MB); out [0,16MB); ffn2 [0,16MB).
  // cont (32MB bf16) at [16MB,48MB) until attn2 completes.
  // v-partials (16MB fp16) at [48MB,64MB) -- lets v GEMM run alongside qk.
  char* P1c = (char*)alloc((size_t)64 * 1024 * 1024);
  f16*  P1  = (f16*)P1c;
  bf16* cont = (bf16*)(P1c + (size_t)16 * 1024 * 1024);
  f16*  P1v  = (f16*)(P1c + (size_t)48 * 1024 * 1024);
  (void)pooled;

  float* outp = (float*)d_out;
  const int BS = B_ * S_;

  // fused prep: cvt + 4x transpose + wcat + pool partials + wave synthesis
  k_prep<<<17472, 256, 0, stream>>>(x, xb, v_w, vwT, out_w, outwT,
                                    ffn_w1, ffn1T, ffn_w2, ffn2T,
                                    qmod_w, kmod_w, cwq, cwk, wcatT,
                                    part, freqs, amps, phases, kerns);

  // qk GEMM || gate1 || v GEMM
  k_qv<<<1024, 256, 0, stream>>>(xb, wcatT, P1, P1v, vwT,
                                 part, gate_w1, mod_w1, gpart);

  // fin_qk || gate2 || fin_vT
  k_fg2v<<<4112, 256, 0, stream>>>(P1, qmod_b, kmod_b, qsT, kmT, qcb, kcb,
                                   gpart, gate_b1, gate_w2, gate_b2,
                                   mod_b1, mod_w2, mod_b2, mod_basis, wmod,
                                   P1v, v_b, vT);

  // cont + swin
  k_cs<<<1088, 256, 0, stream>>>(qcb, kcb, cont, wmod, kerns, swin);

  k_attn2<<<dim3(64, 16), 256, 0, stream>>>(qsT, kmT, cont, swin, vT, ob, opart, mlpart);
  k_comb<<<16 * 60, 256, 0, stream>>>(opart, mlpart, ob);

  // y = LN(o @ out_w + out_b + x)  (split-K=4, fused fin+LN -> ybuf fp32 + yb bf16)
  k_gemm_sk<1><<<dim3(8, 16, 4), 256, 0, stream>>>(
      ob, outwT, P1, E_, E_, 256, 0, (size_t)2048 * 1024);
  k_fin_ln<4, true><<<2048, 256, 0, stream>>>(P1, out_b, x, ln_ag, ln_ab, ybuf, yb);

  // h = gelu(y @ ffn_w1 + b1)  (fused epilogue, no partial round-trip)
  k_gemm_mfma<true, false, false, true><<<dim3(FFNH_ / 128, BS / 128), 256, 0, stream>>>(
      yb, ffn1T, ffn_b1, nullptr, nullptr, hb, FFNH_, E_);

  // out = LN(h @ ffn_w2 + b2 + y)  (split-K=4, fused fin+LN -> outp)
  k_gemm_sk<1><<<dim3(8, 16, 4), 256, 0, stream>>>(
      hb, ffn2T, P1, E_, FFNH_, 1024, 0, (size_t)2048 * 1024);
  k_fin_ln<4, false><<<2048, 256, 0, stream>>>(P1, ffn_b2, ybuf, ln_fg, ln_fb, outp, nullptr);
}

// Round 20
// 222.949 us; speedup vs baseline: 1.5410x; 1.0001x over previous
//
#include <hip/hip_runtime.h>
#include <math.h>
#include <stdint.h>

namespace {

constexpr int B_ = 2, S_ = 1024, E_ = 1024, H_ = 8, HD_ = 128;
constexpr int M_ = 128, W_ = 32, GH_ = 128, R_ = 8, MR_ = 8, FFNH_ = 4096;
constexpr int SCH = 32;            // s-chunks for pooling
constexpr int SPC = S_ / SCH;      // 32 rows per chunk

typedef __bf16 bf16;
typedef _Float16 f16;
typedef __attribute__((ext_vector_type(8))) __bf16 bf16x8;
typedef __attribute__((ext_vector_type(4))) __bf16 bf16x4;
typedef __attribute__((ext_vector_type(4))) _Float16 f16x4;
typedef __attribute__((ext_vector_type(4))) float f32x4;

__device__ inline float gelu_tanh(float u) {
  float u3 = u * u * u;
  return 0.5f * u * (1.f + tanhf(0.7978845608028654f * (u + 0.044715f * u3)));
}

__device__ __forceinline__ void gl_lds16(const void* g, void* l) {
  __builtin_amdgcn_global_load_lds((const __attribute__((address_space(1))) void*)g,
                                   (__attribute__((address_space(3))) void*)l, 16, 0, 0);
}

// ---------------- shared split-K GEMM body (BK=64), lin pre-swizzled --------
template <int NB>
__device__ __forceinline__ void gemm_body(
    const bf16* __restrict__ A, const bf16* __restrict__ BT,
    f16* __restrict__ P, int N, int K, int Kslice, size_t strideB, size_t mn,
    int lin, int gx, int gy, bf16* Asb, bf16* Bsb) {
  int t = threadIdx.x;
  int by = lin % gy;
  int rem = lin / gy;
  int bx = rem % gx;
  int z = rem / gx;
  int bb = z % NB;
  int k0 = (z / NB) * Kslice;
  const bf16* Bbase = BT + (size_t)bb * strideB;
  int row0 = by * 128, col0 = bx * 128;
  int lane = t & 63, wid = t >> 6;
  int wr = wid >> 1, wc = wid & 1;

  const bf16* AgP[4];
  const bf16* BgP[4];
  int ldo[4];
#pragma unroll
  for (int j = 0; j < 4; ++j) {
    int p = t + j * 256;
    int sub = p >> 9;
    int pp = p & 511;
    int rt = ((pp >> 6) << 4) | (pp & 15);
    int kb = (pp >> 4) & 3;
    AgP[j] = A + (size_t)(row0 + rt) * K + k0 + sub * 32 + kb * 8;
    BgP[j] = Bbase + (size_t)(col0 + rt) * K + k0 + sub * 32 + kb * 8;
    ldo[j] = sub * 4096 + pp * 8;
  }

  f32x4 acc[4][4];
#pragma unroll
  for (int m = 0; m < 4; ++m)
#pragma unroll
    for (int n = 0; n < 4; ++n) acc[m][n] = (f32x4){0.f, 0.f, 0.f, 0.f};

#pragma unroll
  for (int j = 0; j < 4; ++j) {
    gl_lds16(AgP[j], &Asb[ldo[j]]);
    gl_lds16(BgP[j], &Bsb[ldo[j]]);
  }

  const int nt = Kslice >> 6;
  for (int kt = 0; kt < nt; ++kt) {
    int cur = kt & 1;
    __syncthreads();
    if (kt + 1 < nt) {
      size_t go = (size_t)(kt + 1) * 64;
      int nb = cur ^ 1;
#pragma unroll
      for (int j = 0; j < 4; ++j) {
        gl_lds16(AgP[j] + go, &Asb[nb * 8192 + ldo[j]]);
        gl_lds16(BgP[j] + go, &Bsb[nb * 8192 + ldo[j]]);
      }
    }
#pragma unroll
    for (int kk = 0; kk < 2; ++kk) {
      bf16x8 af[4], bfr[4];
#pragma unroll
      for (int m = 0; m < 4; ++m)
        af[m] = *(const bf16x8*)&Asb[cur * 8192 + kk * 4096 + ((wr * 4 + m) * 64 + lane) * 8];
#pragma unroll
      for (int n = 0; n < 4; ++n)
        bfr[n] = *(const bf16x8*)&Bsb[cur * 8192 + kk * 4096 + ((wc * 4 + n) * 64 + lane) * 8];
#pragma unroll
      for (int m = 0; m < 4; ++m)
#pragma unroll
        for (int n = 0; n < 4; ++n)
          acc[m][n] = __builtin_amdgcn_mfma_f32_16x16x32_bf16(af[m], bfr[n], acc[m][n], 0, 0, 0);
    }
  }

  f16* Pz = P + (size_t)z * mn;
  int r0 = row0 + wr * 64, c0 = col0 + wc * 64;
#pragma unroll
  for (int m = 0; m < 4; ++m)
#pragma unroll
    for (int n = 0; n < 4; ++n) {
      int col = c0 + n * 16 + (lane & 15);
#pragma unroll
      for (int reg = 0; reg < 4; ++reg) {
        int row = r0 + m * 16 + ((lane >> 4) << 2) + reg;
        Pz[(size_t)row * N + col] = (f16)acc[m][n][reg];
      }
    }
}

// ---- weight (K,N) fp32 -> (N,K) bf16 transpose tile helper -----------------
__device__ __forceinline__ void wt_tile(const float* __restrict__ w,
                                        bf16* __restrict__ wT, int K, int N,
                                        int bx, int by, float (*tile)[33]) {
  int t = threadIdx.x;
  int n0 = bx * 32, k0 = by * 32;
  int tx = t & 31, ty = t >> 5;
  for (int r = ty; r < 32; r += 8) tile[r][tx] = w[(size_t)(k0 + r) * N + n0 + tx];
  __syncthreads();
  for (int r = ty; r < 32; r += 8) wT[(size_t)(n0 + r) * K + k0 + tx] = (bf16)tile[tx][r];
}

// ---------------- fused prep (early-needed only): cvt + v_w^T + wcat +
// pool partials + waves.  blocks: [0,2048) cvt; [2048,3072) v_w^T;
// [3072,4096) wcat; [4096,4160) pool; [4160,8256) waves.
__global__ __launch_bounds__(256) void k_prep(
    const float* __restrict__ x, bf16* __restrict__ xb,
    const float* __restrict__ v_w, bf16* __restrict__ vwT,
    const float* __restrict__ qmw, const float* __restrict__ kmw,
    const float* __restrict__ cwq, const float* __restrict__ cwk,
    bf16* __restrict__ wcat, float* __restrict__ part,
    const float* __restrict__ freqs, const float* __restrict__ amps,
    const float* __restrict__ phases, float* __restrict__ kerns) {
  __shared__ float tile[32][33];
  __shared__ float f0[W_], f1[W_], am[W_], ph[W_];
  int b = blockIdx.x, t = threadIdx.x;
  if (b < 2048) {                  // fp32 -> bf16 elementwise (x)
    size_t i = ((size_t)b * 256 + t) * 4;
    float4 v = *(const float4*)(x + i);
    bf16x4 o;
    o.x = (bf16)v.x; o.y = (bf16)v.y; o.z = (bf16)v.z; o.w = (bf16)v.w;
    *(bf16x4*)(xb + i) = o;
    return;
  }
  if (b < 3072) {                  // v_w^T
    int l = b - 2048;
    wt_tile(v_w, vwT, 1024, 1024, l & 31, l >> 5, tile);
    return;
  }
  if (b < 4096) {                  // Wcat^T (256 x 1024)
    int idx = (b - 3072) * 256 + t;
    int n = idx >> 10, k = idx & 1023;
    float v = 0.f;
    if (n < 8) {
      v = qmw[k * 8 + n];
    } else if (n < 16) {
      v = kmw[k * 8 + (n - 8)];
    } else if (n < 80) {
      int u = n - 16, h = u >> 3, r = u & 7;
      int kk = k - h * 128;
      if (kk >= 0 && kk < 128) v = cwq[((size_t)h * 128 + kk) * 8 + r];
    } else if (n < 144) {
      int u = n - 80, h = u >> 3, r = u & 7;
      int kk = k - h * 128;
      if (kk >= 0 && kk < 128) v = cwk[((size_t)h * 128 + kk) * 8 + r];
    }
    wcat[idx] = (bf16)v;
    return;
  }
  if (b < 4160) {                  // pool partials
    int b0 = b - 4096;
    int bb = b0 / SCH, c = b0 % SCH;
    const float* xp = x + (size_t)bb * S_ * E_ + (size_t)c * SPC * E_;
    float acc[4] = {0.f, 0.f, 0.f, 0.f};
    for (int s = 0; s < SPC; ++s) {
      const float* row = xp + (size_t)s * E_;
#pragma unroll
      for (int q = 0; q < 4; ++q) acc[q] += row[t + q * 256];
    }
    float* pp = part + (size_t)b0 * E_;
#pragma unroll
    for (int q = 0; q < 4; ++q) pp[t + q * 256] = acc[q];
    return;
  }
  {                                // waves
    int blk = b - 4160;
    int lt = blk & 3;
    int hm = blk >> 2;
    if (t < W_) {
      f0[t] = freqs[((size_t)hm * W_ + t) * 2 + 0];
      f1[t] = freqs[((size_t)hm * W_ + t) * 2 + 1];
      am[t] = amps[(size_t)hm * W_ + t];
      ph[t] = phases[(size_t)hm * W_ + t];
    }
    __syncthreads();
    int l = lt * 256 + t;
    float rel = (float)(l - (S_ - 1));
    float p1 = rel * (1.0f / S_);
    float p2 = (rel < 0.f) ? (-sqrtf(-rel + 1e-6f) * (1.0f / 32.0f)) : 0.f;
    const float TWO_PI = 6.28318530717958647692f;
    float acc = 0.f;
#pragma unroll
    for (int w = 0; w < W_; ++w)
      acc += am[w] * __sinf(TWO_PI * (f0[w] * p1 + f1[w] * p2) + ph[w]);
    kerns[(size_t)hm * S_ + l] = acc;
  }
}

// -------- fused: qk GEMM (0..255) || gate1 (256..511) || v GEMM (512..1023) -
__global__ __launch_bounds__(256) void k_qv(
    const bf16* __restrict__ xb, const bf16* __restrict__ wcatT,
    f16* __restrict__ Pqk, f16* __restrict__ Pv,
    const bf16* __restrict__ vwT,
    const float* __restrict__ part,
    const float* __restrict__ gw1, const float* __restrict__ mw1,
    float2* __restrict__ gpart) {
  __shared__ bf16 Asb[2 * 8192];
  __shared__ bf16 Bsb[2 * 8192];
  __shared__ float spool[2][64];
  __shared__ float red[2][2][128];
  int b = blockIdx.x, t = threadIdx.x;
  if (b < 256) {                   // qk GEMM: grid(2,16,8), nwg=256, cpx=32
    int lin = (b & 7) * 32 + (b >> 3);
    gemm_body<1>(xb, wcatT, Pqk, 256, E_, 128, 0, (size_t)2048 * 256,
                 lin, 2, 16, Asb, Bsb);
    return;
  }
  if (b >= 512) {                  // v GEMM: grid(8,8,8) NB=2, nwg=512, cpx=64
    int l = b - 512;
    int lin = (l & 7) * 64 + (l >> 3);
    gemm_body<2>(vwT, xb, Pv, S_, E_, 256, (size_t)S_ * E_, (size_t)1024 * 1024,
                 lin, 8, 8, Asb, Bsb);
    return;
  }
  // gate1 (pooled computed in-kernel from part)
  int b0 = b - 256;
  int chunk = b0 & 15, h = (b0 >> 4) & 7, mat = b0 >> 7;
  const float* w = mat ? mw1 : gw1;
  if (t < 128) {
    int bb = t >> 6;
    int e = chunk * 64 + (t & 63);
    float s = 0.f;
    for (int c = 0; c < SCH; ++c) s += part[(size_t)(bb * SCH + c) * E_ + e];
    spool[bb][t & 63] = s * (1.0f / S_);
  }
  __syncthreads();
  int g = t & 127, half = t >> 7;
  int e0 = chunk * 64 + half * 32;
  const float* wp = w + (size_t)h * E_ * GH_ + (size_t)e0 * GH_ + g;
  float a0 = 0.f, a1 = 0.f;
#pragma unroll 8
  for (int r = 0; r < 32; ++r) {
    float wv = wp[(size_t)r * GH_];
    a0 += spool[0][half * 32 + r] * wv;
    a1 += spool[1][half * 32 + r] * wv;
  }
  red[half][0][g] = a0;
  red[half][1][g] = a1;
  __syncthreads();
  if (half == 0) {
    float2 o;
    o.x = red[0][0][g] + red[1][0][g];
    o.y = red[0][1][g] + red[1][1][g];
    gpart[(((size_t)mat * H_ + h) * 16 + chunk) * 128 + g] = o;
  }
}

// -- fused: fin_qk (0..2047) || gate2 (2048..2063) || fin_vT (2064..4111) ----
__global__ __launch_bounds__(256) void k_fg2v(
    const f16* __restrict__ Pqk, const float* __restrict__ qmb,
    const float* __restrict__ kmb, float* __restrict__ qsT,
    float* __restrict__ kmT, float* __restrict__ qc, float* __restrict__ kc,
    const float2* __restrict__ gpart,
    const float* __restrict__ gb1, const float* __restrict__ gw2, const float* __restrict__ gb2,
    const float* __restrict__ mb1, const float* __restrict__ mw2, const float* __restrict__ mb2,
    const float* __restrict__ mbasis, float* __restrict__ wmod,
    const f16* __restrict__ Pv, const float* __restrict__ v_b,
    bf16* __restrict__ vT) {
  __shared__ float ghs[GH_], mhs[GH_], glog[M_], mrs[MR_];
  __shared__ float red2[2][128];
  __shared__ float rbuf[128];
  int blk = blockIdx.x, t = threadIdx.x;
  if (blk < 2048) {                // fin_qk
    if (t >= 144) return;
    int row = blk;
    int b = row >> 10, s = row & 1023;
    const size_t mn = (size_t)2048 * 256;
    float sum = 0.f;
#pragma unroll
    for (int z = 0; z < 8; ++z) sum += (float)Pqk[(size_t)z * mn + (size_t)row * 256 + t];
    if (t < 8) {
      qsT[((size_t)(b * 8 + t)) * 1024 + s] = sum + qmb[t];
    } else if (t < 16) {
      kmT[((size_t)(b * 8 + t - 8)) * 1024 + s] = sum + kmb[t - 8];
    } else if (t < 80) {
      int u = t - 16, h = u >> 3, r = u & 7;
      qc[(((size_t)(b * 8 + h)) * 1024 + s) * 8 + r] = sum;
    } else {
      int u = t - 80, h = u >> 3, r = u & 7;
      kc[(((size_t)(b * 8 + h)) * 1024 + s) * 8 + r] = sum;
    }
    return;
  }
  if (blk >= 2064) {               // fin_vT
    size_t i = ((size_t)(blk - 2064) * 256 + t) * 4;
    const size_t mn = (size_t)1024 * 1024;
    float sx = 0.f, sy = 0.f, sz = 0.f, sw2 = 0.f;
#pragma unroll
    for (int sk = 0; sk < 4; ++sk) {
      f16x4 v = *(const f16x4*)&Pv[(size_t)sk * 2 * mn + i];
      sx += (float)v.x; sy += (float)v.y; sz += (float)v.z; sw2 += (float)v.w;
    }
    float bcol = v_b[(i >> 10) & 1023];
    bf16x4 o;
    o.x = (bf16)(sx + bcol); o.y = (bf16)(sy + bcol);
    o.z = (bf16)(sz + bcol); o.w = (bf16)(sw2 + bcol);
    *(bf16x4*)&vT[i] = o;
    return;
  }
  // gate2
  int bh = blk - 2048;
  int b = bh >> 3, h = bh & 7;
  {
    int g = t & 127, mat = t >> 7;
    const float2* pp = gpart + ((size_t)mat * H_ + h) * 16 * 128 + g;
    float acc = 0.f;
#pragma unroll
    for (int c = 0; c < 16; ++c) {
      float2 v = pp[(size_t)c * 128];
      acc += b ? v.y : v.x;
    }
    acc += (mat ? mb1 : gb1)[h * GH_ + g];
    acc = fmaxf(acc, 0.f);
    if (mat == 0) ghs[g] = acc; else mhs[g] = acc;
  }
  __syncthreads();
  {
    int m = t & 127, half = t >> 7;
    float acc = 0.f;
    const float* wp = gw2 + (size_t)h * GH_ * M_ + m;
#pragma unroll 4
    for (int g = half * 64; g < half * 64 + 64; ++g)
      acc += ghs[g] * wp[(size_t)g * M_];
    red2[half][m] = acc;
  }
  __syncthreads();
  if (t < 128) glog[t] = red2[0][t] + red2[1][t] + gb2[h * M_ + t];
  if (t < 64) {
    int r = t & 7, seg = t >> 3;
    float acc = 0.f;
    const float* wp = mw2 + (size_t)h * GH_ * MR_ + r;
    for (int g = seg * 16; g < seg * 16 + 16; ++g) acc += mhs[g] * wp[(size_t)g * MR_];
    acc += __shfl_xor(acc, 8);
    acc += __shfl_xor(acc, 16);
    acc += __shfl_xor(acc, 32);
    if (t < 8) mrs[t] = acc + mb2[h * MR_ + t];
  }
  __syncthreads();
  if (t < 128) rbuf[t] = glog[t];
  __syncthreads();
  for (int off = 64; off >= 1; off >>= 1) {
    if (t < off) rbuf[t] = fmaxf(rbuf[t], rbuf[t + off]);
    __syncthreads();
  }
  float mx = rbuf[0];
  __syncthreads();
  float ev = 0.f;
  if (t < 128) ev = expf(glog[t] - mx);
  __syncthreads();
  if (t < 128) rbuf[t] = ev;
  __syncthreads();
  for (int off = 64; off >= 1; off >>= 1) {
    if (t < off) rbuf[t] += rbuf[t + off];
    __syncthreads();
  }
  float inv = 1.f / rbuf[0];
  if (t < 128) {
    float wsel = ev * inv;
    float md = 0.f;
#pragma unroll
    for (int r = 0; r < MR_; ++r) md += mrs[r] * mbasis[((size_t)h * MR_ + r) * M_ + t];
    wmod[bh * M_ + t] = wsel * (1.f + md);
  }
}

// ---- cont (0..1023) + swin (1024..1087) + deferred weight transposes -------
// [1088,2112): out_w^T; [2112,6208): ffn_w1^T; [6208,10304): ffn_w2^T.
__global__ __launch_bounds__(256) void k_cs(
    const float* __restrict__ qc, const float* __restrict__ kc,
    bf16* __restrict__ cont,
    const float* __restrict__ wmod, const float* __restrict__ kerns,
    float* __restrict__ swin,
    const float* __restrict__ out_w, bf16* __restrict__ outwT,
    const float* __restrict__ ffn_w1, bf16* __restrict__ ffn1T,
    const float* __restrict__ ffn_w2, bf16* __restrict__ ffn2T) {
  __shared__ float wm[M_];
  __shared__ float tile[32][33];
  int b = blockIdx.x, t = threadIdx.x;
  if (b >= 1088) {                 // deferred weight transposes
    if (b < 2112) {
      int l = b - 1088;
      wt_tile(out_w, outwT, 1024, 1024, l & 31, l >> 5, tile);
    } else if (b < 6208) {
      int l = b - 2112;
      wt_tile(ffn_w1, ffn1T, 1024, 4096, l & 127, l >> 7, tile);
    } else {
      int l = b - 6208;
      wt_tile(ffn_w2, ffn2T, 4096, 1024, l & 31, l >> 5, tile);
    }
    return;
  }
  int jt = b & 7, it = (b >> 3) & 7, bh = b >> 6;   // bh 0..16
  if (bh == 16) {                  // swin
    int blk = it * 8 + jt;
    int dt = blk & 3;
    int sbh = blk >> 2;
    int h = sbh & 7;
    if (t < M_) wm[t] = wmod[sbh * M_ + t];
    __syncthreads();
    int d = dt * 256 + t;
    int l = (S_ - 1) - d;
    float acc = 0.f;
    for (int m = 0; m < M_; ++m) acc += wm[m] * kerns[((size_t)h * M_ + m) * S_ + l];
    float dd = (float)d;
    float win = expf(-dd * dd * (1.0f / 131072.0f));
    swin[(size_t)sbh * S_ + d] = 3.0f * win * acc;
    return;
  }
  if (jt > it) return;
  int w = t >> 6, lane = t & 63;
  int ln = lane & 15, ko = lane >> 4;
  int i0 = it * 128 + w * 32;
  int j0 = jt * 128;

  bf16x8 av[2];
#pragma unroll
  for (int mi = 0; mi < 2; ++mi) {
    bf16x8 a;
#pragma unroll
    for (int k = 0; k < 8; ++k) a[k] = (bf16)0.f;
    if (ko == 0) {
      const float* qp = &qc[((size_t)bh * S_ + i0 + mi * 16 + ln) * 8];
      float4 q0 = *(const float4*)qp;
      float4 q1 = *(const float4*)(qp + 4);
      a[0] = (bf16)q0.x; a[1] = (bf16)q0.y; a[2] = (bf16)q0.z; a[3] = (bf16)q0.w;
      a[4] = (bf16)q1.x; a[5] = (bf16)q1.y; a[6] = (bf16)q1.z; a[7] = (bf16)q1.w;
    }
    av[mi] = a;
  }
  bf16x8 bv[8];
#pragma unroll
  for (int nb = 0; nb < 8; ++nb) {
    bf16x8 bb;
#pragma unroll
    for (int k = 0; k < 8; ++k) bb[k] = (bf16)0.f;
    if (ko == 0) {
      const float* kp = &kc[((size_t)bh * S_ + j0 + nb * 16 + ln) * 8];
      float4 k0 = *(const float4*)kp;
      float4 k1 = *(const float4*)(kp + 4);
      bb[0] = (bf16)k0.x; bb[1] = (bf16)k0.y; bb[2] = (bf16)k0.z; bb[3] = (bf16)k0.w;
      bb[4] = (bf16)k1.x; bb[5] = (bf16)k1.y; bb[6] = (bf16)k1.z; bb[7] = (bf16)k1.w;
    }
    bv[nb] = bb;
  }
  f32x4 acc[2][8];
#pragma unroll
  for (int mi = 0; mi < 2; ++mi)
#pragma unroll
    for (int nb = 0; nb < 8; ++nb) {
      acc[mi][nb] = (f32x4){0.f, 0.f, 0.f, 0.f};
      acc[mi][nb] = __builtin_amdgcn_mfma_f32_16x16x32_bf16(av[mi], bv[nb], acc[mi][nb], 0, 0, 0);
    }
  bf16* cb = cont + ((size_t)bh << 20);
#pragma unroll
  for (int mi = 0; mi < 2; ++mi)
#pragma unroll
    for (int nb = 0; nb < 8; ++nb) {
      int col = j0 + nb * 16 + ln;
#pragma unroll
      for (int reg = 0; reg < 4; ++reg) {
        int row = i0 + mi * 16 + ko * 4 + reg;
        cb[(size_t)row * S_ + col] = (bf16)acc[mi][nb][reg];
      }
    }
}

// ---------------- bf16 MFMA GEMM, BK=64, fused epilogue (FFN1), swizzled ----
template <bool GELU, bool RES, bool OUTF32, bool OUTBF16>
__global__ __launch_bounds__(256) void k_gemm_mfma(
    const bf16* __restrict__ A, const bf16* __restrict__ BT,
    const float* __restrict__ bias, const float* __restrict__ res,
    float* __restrict__ C, bf16* __restrict__ Cb, int N, int K) {
  __shared__ bf16 Asb[2][8192];
  __shared__ bf16 Bsb[2][8192];
  int t = threadIdx.x;
  int gx = gridDim.x, gy = gridDim.y;
  int nwg = gx * gy;
  int lin = blockIdx.y * gx + blockIdx.x;
  if (!(nwg & 7)) {
    int cpx = nwg >> 3;
    lin = (lin & 7) * cpx + (lin >> 3);
  }
  int by = lin % gy;
  int bx = lin / gy;
  int row0 = by * 128, col0 = bx * 128;
  int lane = t & 63, wid = t >> 6;
  int wr = wid >> 1, wc = wid & 1;

  const bf16* AgP[4];
  const bf16* BgP[4];
  int ldo[4];
#pragma unroll
  for (int j = 0; j < 4; ++j) {
    int p = t + j * 256;
    int sub = p >> 9;
    int pp = p & 511;
    int rt = ((pp >> 6) << 4) | (pp & 15);
    int kb = (pp >> 4) & 3;
    AgP[j] = A + (size_t)(row0 + rt) * K + sub * 32 + kb * 8;
    BgP[j] = BT + (size_t)(col0 + rt) * K + sub * 32 + kb * 8;
    ldo[j] = sub * 4096 + pp * 8;
  }

  f32x4 acc[4][4];
#pragma unroll
  for (int m = 0; m < 4; ++m)
#pragma unroll
    for (int n = 0; n < 4; ++n) acc[m][n] = (f32x4){0.f, 0.f, 0.f, 0.f};

#pragma unroll
  for (int j = 0; j < 4; ++j) {
    gl_lds16(AgP[j], &Asb[0][ldo[j]]);
    gl_lds16(BgP[j], &Bsb[0][ldo[j]]);
  }

  const int nt = K >> 6;
  for (int kt = 0; kt < nt; ++kt) {
    int cur = kt & 1;
    __syncthreads();
    if (kt + 1 < nt) {
      size_t go = (size_t)(kt + 1) * 64;
      int nb = cur ^ 1;
#pragma unroll
      for (int j = 0; j < 4; ++j) {
        gl_lds16(AgP[j] + go, &Asb[nb][ldo[j]]);
        gl_lds16(BgP[j] + go, &Bsb[nb][ldo[j]]);
      }
    }
#pragma unroll
    for (int kk = 0; kk < 2; ++kk) {
      bf16x8 af[4], bfr[4];
#pragma unroll
      for (int m = 0; m < 4; ++m)
        af[m] = *(const bf16x8*)&Asb[cur][kk * 4096 + ((wr * 4 + m) * 64 + lane) * 8];
#pragma unroll
      for (int n = 0; n < 4; ++n)
        bfr[n] = *(const bf16x8*)&Bsb[cur][kk * 4096 + ((wc * 4 + n) * 64 + lane) * 8];
#pragma unroll
      for (int m = 0; m < 4; ++m)
#pragma unroll
        for (int n = 0; n < 4; ++n)
          acc[m][n] = __builtin_amdgcn_mfma_f32_16x16x32_bf16(af[m], bfr[n], acc[m][n], 0, 0, 0);
    }
  }

  int r0 = row0 + wr * 64, c0 = col0 + wc * 64;
#pragma unroll
  for (int m = 0; m < 4; ++m) {
#pragma unroll
    for (int n = 0; n < 4; ++n) {
      int col = c0 + n * 16 + (lane & 15);
      float bcol = bias[col];
#pragma unroll
      for (int reg = 0; reg < 4; ++reg) {
        int row = r0 + m * 16 + ((lane >> 4) << 2) + reg;
        float u = acc[m][n][reg] + bcol;
        if (GELU) u = gelu_tanh(u);
        if (RES) u += res[(size_t)row * N + col];
        if (OUTF32) C[(size_t)row * N + col] = u;
        if (OUTBF16) Cb[(size_t)row * N + col] = (bf16)u;
      }
    }
  }
}

// ---------------- split-K bf16 MFMA GEMM, BK=64, swizzled (by-fastest) ------
template <int NB>
__global__ __launch_bounds__(256) void k_gemm_sk(
    const bf16* __restrict__ A, const bf16* __restrict__ BT,
    f16* __restrict__ P, int N, int K, int Kslice, size_t strideB, size_t mn) {
  __shared__ bf16 Asb[2 * 8192];
  __shared__ bf16 Bsb[2 * 8192];
  int gx = gridDim.x, gy = gridDim.y;
  int nwg = gx * gy * gridDim.z;
  int lin = (blockIdx.z * gy + blockIdx.y) * gx + blockIdx.x;
  if (!(nwg & 7)) {
    int cpx = nwg >> 3;
    lin = (lin & 7) * cpx + (lin >> 3);
  }
  gemm_body<NB>(A, BT, P, N, K, Kslice, strideB, mn, lin, gx, gy, Asb, Bsb);
}

// ---------------- fused fin+LayerNorm: u = sumP + bias + res; LN(u) ---------
template <int SK, bool OUTBF16>
__global__ __launch_bounds__(256) void k_fin_ln(
    const f16* __restrict__ P, const float* __restrict__ bias,
    const float* __restrict__ res, const float* __restrict__ g,
    const float* __restrict__ bb, float* __restrict__ outF,
    bf16* __restrict__ outB) {
  int row = blockIdx.x, t = threadIdx.x;
  size_t base = (size_t)row * E_ + t * 4;
  const size_t mn = (size_t)2048 * 1024;
  float u0 = 0.f, u1 = 0.f, u2 = 0.f, u3 = 0.f;
#pragma unroll
  for (int sk = 0; sk < SK; ++sk) {
    f16x4 v = *(const f16x4*)&P[(size_t)sk * mn + base];
    u0 += (float)v.x; u1 += (float)v.y; u2 += (float)v.z; u3 += (float)v.w;
  }
  float4 bv = *(const float4*)&bias[t * 4];
  float4 rv = *(const float4*)&res[base];
  u0 += bv.x + rv.x; u1 += bv.y + rv.y; u2 += bv.z + rv.z; u3 += bv.w + rv.w;
  float s = u0 + u1 + u2 + u3;
  float s2 = u0 * u0 + u1 * u1 + u2 * u2 + u3 * u3;
#pragma unroll
  for (int off = 32; off >= 1; off >>= 1) {
    s += __shfl_xor(s, off);
    s2 += __shfl_xor(s2, off);
  }
  __shared__ float rs[4], rs2[4];
  int wid = t >> 6;
  if ((t & 63) == 0) { rs[wid] = s; rs2[wid] = s2; }
  __syncthreads();
  float S1 = rs[0] + rs[1] + rs[2] + rs[3];
  float S2 = rs2[0] + rs2[1] + rs2[2] + rs2[3];
  float mu = S1 * (1.f / E_);
  float var = S2 * (1.f / E_) - mu * mu;
  float inv = rsqrtf(var + 1e-5f);
  float4 gv = *(const float4*)&g[t * 4];
  float4 bbv = *(const float4*)&bb[t * 4];
  float4 ov;
  ov.x = (u0 - mu) * inv * gv.x + bbv.x;
  ov.y = (u1 - mu) * inv * gv.y + bbv.y;
  ov.z = (u2 - mu) * inv * gv.z + bbv.z;
  ov.w = (u3 - mu) * inv * gv.w + bbv.w;
  *(float4*)&outF[base] = ov;
  if (OUTBF16) {
    bf16x4 obv;
    obv.x = (bf16)ov.x; obv.y = (bf16)ov.y; obv.z = (bf16)ov.z; obv.w = (bf16)ov.w;
    *(bf16x4*)&outB[base] = obv;
  }
}

// ---------------- MFMA flash attention (cont-based scores) ------------------
__global__ __launch_bounds__(256) void k_attn2(
    const float* __restrict__ qsT, const float* __restrict__ kmT,
    const bf16* __restrict__ cont, const float* __restrict__ swin,
    const bf16* __restrict__ vT,
    bf16* __restrict__ o, bf16* __restrict__ opart, float* __restrict__ mlpart) {
  int q = blockIdx.x & 3;
  int iwg = blockIdx.x >> 2;       // 0..15
  if (q > iwg) return;             // ntile = iwg+1; quarter q needs q < ntile
  int bh = blockIdx.y;
  int b = bh >> 3, h = bh & 7;
  int t = threadIdx.x;
  int wid = t >> 6, lane = t & 63;
  int iw = iwg * 4 + wid;          // 0..63
  int m = lane & 15, ko = lane >> 4;
  int ntile = iwg + 1;

  __shared__ float sw[S_];
  *(float4*)&sw[t * 4] = *(const float4*)&swin[(size_t)bh * S_ + t * 4];
  __syncthreads();

  int i_row = iw * 16 + m;
  float qs_i = qsT[(size_t)bh * S_ + i_row];
  const bf16* cr = cont + ((size_t)bh << 20) + (size_t)i_row * S_;

  f32x4 acc[8];
#pragma unroll
  for (int nf = 0; nf < 8; ++nf) acc[nf] = (f32x4){0.f, 0.f, 0.f, 0.f};
  float m_run = -INFINITY, l_run = 0.f;

  for (int jt = q; jt < ntile; jt += 4) {
    int j0 = jt * 64;
    float pv[2][8];
    float mx = -INFINITY;
    bf16x8 cv[2];
    cv[0] = *(const bf16x8*)&cr[j0 + ko * 8];
    cv[1] = *(const bf16x8*)&cr[j0 + 32 + ko * 8];
#pragma unroll
    for (int s = 0; s < 2; ++s) {
      int bj = j0 + s * 32 + ko * 8;
      float4 km0 = *(const float4*)&kmT[(size_t)bh * S_ + bj];
      float4 km1 = *(const float4*)&kmT[(size_t)bh * S_ + bj + 4];
      float kmv[8] = {km0.x, km0.y, km0.z, km0.w, km1.x, km1.y, km1.z, km1.w};
#pragma unroll
      for (int e = 0; e < 8; ++e) {
        int j = bj + e;
        int dd = i_row - j;
        float val = sw[dd >= 0 ? dd : 0] + qs_i + kmv[e] + 0.25f * (float)cv[s][e];
        val = (dd >= 0) ? val : -INFINITY;   // cndmask, branch-free
        pv[s][e] = val;
        mx = fmaxf(mx, val);
      }
    }
    mx = fmaxf(mx, __shfl_xor(mx, 16));
    mx = fmaxf(mx, __shfl_xor(mx, 32));
    float mnew = fmaxf(m_run, mx);
    float scale = __expf(m_run - mnew);
    float lsum = 0.f;
    bf16x8 pa[2];
#pragma unroll
    for (int s = 0; s < 2; ++s)
#pragma unroll
      for (int e = 0; e < 8; ++e) {
        float p = __expf(pv[s][e] - mnew);
        lsum += p;
        pa[s][e] = (bf16)p;
      }
    lsum += __shfl_xor(lsum, 16);
    lsum += __shfl_xor(lsum, 32);
    l_run = l_run * scale + lsum;
    m_run = mnew;
    float sc[4];
#pragma unroll
    for (int r = 0; r < 4; ++r) sc[r] = __shfl(scale, ko * 4 + r);
#pragma unroll
    for (int nf = 0; nf < 8; ++nf)
#pragma unroll
      for (int r = 0; r < 4; ++r) acc[nf][r] *= sc[r];
#pragma unroll
    for (int s = 0; s < 2; ++s) {
      int bj = j0 + s * 32 + ko * 8;
#pragma unroll
      for (int nf = 0; nf < 8; ++nf) {
        int d = nf * 16 + m;
        bf16x8 bv = *(const bf16x8*)&vT[((size_t)bh * HD_ + d) * S_ + bj];
        acc[nf] = __builtin_amdgcn_mfma_f32_16x16x32_bf16(pa[s], bv, acc[nf], 0, 0, 0);
      }
    }
  }

  if (ntile == 1) {                // iw<4 (only q==0): finalize directly
    float lr[4];
#pragma unroll
    for (int r = 0; r < 4; ++r) lr[r] = __shfl(l_run, ko * 4 + r);
#pragma unroll
    for (int nf = 0; nf < 8; ++nf) {
      int d = nf * 16 + m;
#pragma unroll
      for (int r = 0; r < 4; ++r) {
        int row = iw * 16 + ko * 4 + r;
        o[(((size_t)b * S_ + row) * H_ + h) * HD_ + d] = (bf16)(acc[nf][r] / lr[r]);
      }
    }
  } else {
    bf16* op = opart + ((size_t)(q * 16 + bh) * 64 + iw) * 2048;
#pragma unroll
    for (int nf = 0; nf < 8; ++nf) {
      int d = nf * 16 + m;
#pragma unroll
      for (int r = 0; r < 4; ++r) op[(ko * 4 + r) * 128 + d] = (bf16)acc[nf][r];
    }
    if (lane < 16) {
      float* mlp = mlpart + ((size_t)(q * 16 + bh) * 64 + iw) * 32;
      mlp[m * 2 + 0] = m_run;
      mlp[m * 2 + 1] = l_run;
    }
  }
}

// ---------------- combine up to 4 attention quarters (rows iw>=4) -----------
__global__ __launch_bounds__(256) void k_comb(const bf16* __restrict__ opart,
                                              const float* __restrict__ mlpart,
                                              bf16* __restrict__ o) {
  int blk = blockIdx.x;
  int bh = blk / 60, iw = blk % 60 + 4;
  int b = bh >> 3, h = bh & 7;
  int t = threadIdx.x;
  int r = t >> 4, d0 = (t & 15) * 8;
  int nq = iw / 4 + 1;
  if (nq > 4) nq = 4;
  float mq[4], lq[4];
  float mm = -INFINITY;
#pragma unroll
  for (int q = 0; q < 4; ++q) {
    if (q < nq) {
      size_t idx = (size_t)(q * 16 + bh) * 64 + iw;
      mq[q] = mlpart[idx * 32 + r * 2];
      lq[q] = mlpart[idx * 32 + r * 2 + 1];
      mm = fmaxf(mm, mq[q]);
    }
  }
  float L = 0.f;
  float acc[8] = {0.f, 0.f, 0.f, 0.f, 0.f, 0.f, 0.f, 0.f};
#pragma unroll
  for (int q = 0; q < 4; ++q) {
    if (q < nq) {
      float e = __expf(mq[q] - mm);
      L += lq[q] * e;
      size_t idx = (size_t)(q * 16 + bh) * 64 + iw;
      bf16x8 v = *(const bf16x8*)&opart[(idx * 16 + r) * 128 + d0];
#pragma unroll
      for (int k = 0; k < 8; ++k) acc[k] += (float)v[k] * e;
    }
  }
  float inv = 1.f / L;
  bf16x8 ov;
#pragma unroll
  for (int k = 0; k < 8; ++k) ov[k] = (bf16)(acc[k] * inv);
  int row = iw * 16 + r;
  *(bf16x8*)&o[(((size_t)b * S_ + row) * H_ + h) * HD_ + d0] = ov;
}

}  // namespace

extern "C" void kernel_launch(void* const* d_in, const int* in_sizes, int n_in,
                              void* d_out, int out_size, void* d_ws, size_t ws_size,
                              hipStream_t stream) {
  (void)in_sizes; (void)n_in; (void)out_size; (void)ws_size;
  const float* x       = (const float*)d_in[0];
  const float* v_w     = (const float*)d_in[1];
  const float* v_b     = (const float*)d_in[2];
  const float* out_w   = (const float*)d_in[3];
  const float* out_b   = (const float*)d_in[4];
  const float* qmod_w  = (const float*)d_in[5];
  const float* qmod_b  = (const float*)d_in[6];
  const float* kmod_w  = (const float*)d_in[7];
  const float* kmod_b  = (const float*)d_in[8];
  const float* gate_w1 = (const float*)d_in[9];
  const float* gate_b1 = (const float*)d_in[10];
  const float* gate_w2 = (const float*)d_in[11];
  const float* gate_b2 = (const float*)d_in[12];
  const float* mod_w1  = (const float*)d_in[13];
  const float* mod_b1  = (const float*)d_in[14];
  const float* mod_w2  = (const float*)d_in[15];
  const float* mod_b2  = (const float*)d_in[16];
  const float* mod_basis = (const float*)d_in[17];
  const float* freqs   = (const float*)d_in[18];
  const float* amps    = (const float*)d_in[19];
  const float* phases  = (const float*)d_in[20];
  const float* cwq     = (const float*)d_in[21];
  const float* cwk     = (const float*)d_in[22];
  const float* ffn_w1  = (const float*)d_in[23];
  const float* ffn_b1  = (const float*)d_in[24];
  const float* ffn_w2  = (const float*)d_in[25];
  const float* ffn_b2  = (const float*)d_in[26];
  const float* ln_ag   = (const float*)d_in[27];
  const float* ln_ab   = (const float*)d_in[28];
  const float* ln_fg   = (const float*)d_in[29];
  const float* ln_fb   = (const float*)d_in[30];

  char* wsc = (char*)d_ws;
  size_t off = 0;
  auto alloc = [&](size_t bytes) -> void* {
    void* p = wsc + off;
    off += (bytes + 255) & ~(size_t)255;
    return p;
  };
  float* pooled = (float*)alloc(2048 * 4);   // unused (layout stability)
  float* part   = (float*)alloc(65536 * 4);
  float2* gpart = (float2*)alloc((size_t)2 * H_ * 16 * 128 * 8);
  float* wmod   = (float*)alloc(2048 * 4);
  float* kerns  = (float*)alloc((size_t)H_ * M_ * S_ * 4);
  float* swin   = (float*)alloc((size_t)B_ * H_ * S_ * 4);
  float* qsT    = (float*)alloc((size_t)B_ * H_ * S_ * 4);
  float* kmT    = (float*)alloc((size_t)B_ * H_ * S_ * 4);
  float* qcb    = (float*)alloc((size_t)B_ * H_ * S_ * R_ * 4);
  float* kcb    = (float*)alloc((size_t)B_ * H_ * S_ * R_ * 4);
  float* ybuf   = (float*)alloc((size_t)B_ * S_ * E_ * 4);       // 8MB (post-LN y)
  bf16* xb      = (bf16*)alloc((size_t)B_ * S_ * E_ * 2);
  bf16* yb      = (bf16*)alloc((size_t)B_ * S_ * E_ * 2);
  bf16* vwT     = (bf16*)alloc((size_t)E_ * E_ * 2);
  bf16* outwT   = (bf16*)alloc((size_t)E_ * E_ * 2);
  bf16* ffn1T   = (bf16*)alloc((size_t)E_ * FFNH_ * 2);
  bf16* ffn2T   = (bf16*)alloc((size_t)FFNH_ * E_ * 2);
  bf16* wcatT   = (bf16*)alloc((size_t)256 * E_ * 2);            // 0.5MB
  bf16* vT      = (bf16*)alloc((size_t)B_ * S_ * E_ * 2);        // v [b,hd,s]
  bf16* ob      = (bf16*)alloc((size_t)B_ * S_ * E_ * 2);        // attn out
  float* mlpart = (float*)alloc((size_t)4 * 16 * 64 * 16 * 2 * 4);
  char* poolU2  = (char*)alloc((size_t)B_ * S_ * FFNH_ * 2);     // 16MB union
  bf16* opart = (bf16*)poolU2;     // 16MB (attn phase)
  bf16* hb    = (bf16*)poolU2;     // 16MB (FFN phase)
  // P1: 64MB union. fp16 partials: qk [0,8MB); out [0,16MB); ffn2 [0,16MB).
  // cont (32MB bf16) at [16MB,48MB) until attn2 completes.
  // v-partials (16MB fp16) at [48MB,64MB).
  char* P1c = (char*)alloc((size_t)64 * 1024 * 1024);
  f16*  P1  = (f16*)P1c;
  bf16* cont = (bf16*)(P1c + (size_t)16 * 1024 * 1024);
  f16*  P1v  = (f16*)(P1c + (size_t)48 * 1024 * 1024);
  (void)pooled;

  float* outp = (float*)d_out;
  const int BS = B_ * S_;

  // prep (early-needed): cvt + v_w^T + wcat + pool partials + waves
  k_prep<<<8256, 256, 0, stream>>>(x, xb, v_w, vwT,
                                   qmod_w, kmod_w, cwq, cwk, wcatT,
                                   part, freqs, amps, phases, kerns);

  // qk GEMM || gate1 || v GEMM
  k_qv<<<1024, 256, 0, stream>>>(xb, wcatT, P1, P1v, vwT,
                                 part, gate_w1, mod_w1, gpart);

  // fin_qk || gate2 || fin_vT
  k_fg2v<<<4112, 256, 0, stream>>>(P1, qmod_b, kmod_b, qsT, kmT, qcb, kcb,
                                   gpart, gate_b1, gate_w2, gate_b2,
                                   mod_b1, mod_w2, mod_b2, mod_basis, wmod,
                                   P1v, v_b, vT);

  // cont + swin || deferred weight transposes (out_w, ffn_w1, ffn_w2)
  k_cs<<<10304, 256, 0, stream>>>(qcb, kcb, cont, wmod, kerns, swin,
                                  out_w, outwT, ffn_w1, ffn1T, ffn_w2, ffn2T);

  k_attn2<<<dim3(64, 16), 256, 0, stream>>>(qsT, kmT, cont, swin, vT, ob, opart, mlpart);
  k_comb<<<16 * 60, 256, 0, stream>>>(opart, mlpart, ob);

  // y = LN(o @ out_w + out_b + x)  (split-K=4, fused fin+LN -> ybuf fp32 + yb bf16)
  k_gemm_sk<1><<<dim3(8, 16, 4), 256, 0, stream>>>(
      ob, outwT, P1, E_, E_, 256, 0, (size_t)2048 * 1024);
  k_fin_ln<4, true><<<2048, 256, 0, stream>>>(P1, out_b, x, ln_ag, ln_ab, ybuf, yb);

  // h = gelu(y @ ffn_w1 + b1)  (fused epilogue, no partial round-trip)
  k_gemm_mfma<true, false, false, true><<<dim3(FFNH_ / 128, BS / 128), 256, 0, stream>>>(
      yb, ffn1T, ffn_b1, nullptr, nullptr, hb, FFNH_, E_);

  // out = LN(h @ ffn_w2 + b2 + y)  (split-K=4, fused fin+LN -> outp)
  k_gemm_sk<1><<<dim3(8, 16, 4), 256, 0, stream>>>(
      hb, ffn2T, P1, E_, FFNH_, 1024, 0, (size_t)2048 * 1024);
  k_fin_ln<4, false><<<2048, 256, 0, stream>>>(P1, ffn_b2, ybuf, ln_fg, ln_fb, outp, nullptr);
}